// Round 1
// baseline (1839.297 us; speedup 1.0000x reference)
//
#include <hip/hip_runtime.h>
#include <hip/hip_bf16.h>
#include <math.h>

// Problem constants
constexpr int BATCH   = 4096;
constexpr int NCLS    = 10;
constexpr int NHID    = 4096;   // OUT_HIDDEN
constexpr int PREV    = 512;    // NHID / ARG_IN
constexpr int NTYPES  = 16;
constexpr int CG      = 32;     // cells per type per row: 4096/(16*8)
constexpr float LN_EPS = 1e-5f;

// ---------------------------------------------------------------------------
// GEMM: C[M,N] = A[M,K] @ W[K,N] + bias[N]    (fp32, 64x64 tile, BK=16)
// ---------------------------------------------------------------------------
__global__ __launch_bounds__(256)
void gemm_bias_kernel(const float* __restrict__ A, const float* __restrict__ W,
                      const float* __restrict__ bias, float* __restrict__ C,
                      int N, int K) {
  constexpr int BK = 16;
  __shared__ float As[BK][64 + 1];   // +1 pad: breaks store conflicts
  __shared__ float Bs[BK][64];
  const int tid = threadIdx.x;
  const int tx = tid & 15;           // micro-tile col group
  const int ty = tid >> 4;           // micro-tile row group
  const int row0 = blockIdx.y * 64;
  const int col0 = blockIdx.x * 64;

  float acc[4][4] = {};

  for (int k0 = 0; k0 < K; k0 += BK) {
    // A tile: 64 rows x 16 k, one float4 per thread
    {
      const int r = tid >> 2;
      const int c = (tid & 3) * 4;
      const float4 v = *reinterpret_cast<const float4*>(&A[(size_t)(row0 + r) * K + k0 + c]);
      As[c + 0][r] = v.x; As[c + 1][r] = v.y; As[c + 2][r] = v.z; As[c + 3][r] = v.w;
    }
    // B tile: 16 k x 64 cols, one float4 per thread
    {
      const int r = tid >> 4;
      const int c = (tid & 15) * 4;
      *reinterpret_cast<float4*>(&Bs[r][c]) =
          *reinterpret_cast<const float4*>(&W[(size_t)(k0 + r) * N + col0 + c]);
    }
    __syncthreads();
    #pragma unroll
    for (int kk = 0; kk < BK; ++kk) {
      float a[4], b[4];
      #pragma unroll
      for (int i = 0; i < 4; ++i) a[i] = As[kk][ty * 4 + i];
      #pragma unroll
      for (int j = 0; j < 4; ++j) b[j] = Bs[kk][tx * 4 + j];
      #pragma unroll
      for (int i = 0; i < 4; ++i)
        #pragma unroll
        for (int j = 0; j < 4; ++j)
          acc[i][j] = fmaf(a[i], b[j], acc[i][j]);
    }
    __syncthreads();
  }

  #pragma unroll
  for (int i = 0; i < 4; ++i) {
    const int row = row0 + ty * 4 + i;
    float4 o;
    o.x = acc[i][0] + bias[col0 + tx * 4 + 0];
    o.y = acc[i][1] + bias[col0 + tx * 4 + 1];
    o.z = acc[i][2] + bias[col0 + tx * 4 + 2];
    o.w = acc[i][3] + bias[col0 + tx * 4 + 3];
    *reinterpret_cast<float4*>(&C[(size_t)row * N + col0 + tx * 4]) = o;
  }
}

// ---------------------------------------------------------------------------
// LayerNorm in place over rows of length N=4096 (no affine params)
// ---------------------------------------------------------------------------
__global__ __launch_bounds__(256)
void layernorm_kernel(float* __restrict__ X, int N) {
  float* p = X + (size_t)blockIdx.x * N;
  const int tid = threadIdx.x;
  float s = 0.f, ss = 0.f;
  for (int i = tid * 4; i < N; i += 256 * 4) {
    const float4 v = *reinterpret_cast<const float4*>(&p[i]);
    s  += v.x + v.y + v.z + v.w;
    ss += v.x * v.x + v.y * v.y + v.z * v.z + v.w * v.w;
  }
  #pragma unroll
  for (int off = 32; off; off >>= 1) {
    s  += __shfl_down(s, off);
    ss += __shfl_down(ss, off);
  }
  __shared__ float sb[4], ssb[4];
  __shared__ float mu_s, rs_s;
  if ((tid & 63) == 0) { sb[tid >> 6] = s; ssb[tid >> 6] = ss; }
  __syncthreads();
  if (tid == 0) {
    const float S  = sb[0] + sb[1] + sb[2] + sb[3];
    const float SS = ssb[0] + ssb[1] + ssb[2] + ssb[3];
    const float mu = S / N;
    const float var = SS / N - mu * mu;
    mu_s = mu;
    rs_s = rsqrtf(var + LN_EPS);
  }
  __syncthreads();
  const float mu = mu_s, rs = rs_s;
  for (int i = tid * 4; i < N; i += 256 * 4) {
    float4 v = *reinterpret_cast<const float4*>(&p[i]);
    v.x = (v.x - mu) * rs; v.y = (v.y - mu) * rs;
    v.z = (v.z - mu) * rs; v.w = (v.w - mu) * rs;
    *reinterpret_cast<float4*>(&p[i]) = v;
  }
}

// ---------------------------------------------------------------------------
// W2 transpose:  W2[t][j][k] -> W2T[t][k][j]  so the inner k-row is contiguous
// ---------------------------------------------------------------------------
__global__ __launch_bounds__(256)
void transpose_w2_kernel(const float* __restrict__ W2, float* __restrict__ W2T) {
  const int t = blockIdx.x;
  for (int idx = threadIdx.x; idx < 64 * 64; idx += 256) {
    const int k = idx >> 6, j = idx & 63;
    W2T[t * 4096 + k * 64 + j] = W2[t * 4096 + j * 64 + k];
  }
}

// ---------------------------------------------------------------------------
// Inner grouped MLPs: in (B,4096) viewed as (B,T=16,Cg=32,A=8) -> out (B,512)
// One thread per (b,t,c). h1[64] fully in registers (forced unroll,
// compile-time indices only). Weight reads are wave-uniform -> scalar path.
// ---------------------------------------------------------------------------
__global__ __launch_bounds__(256)
void inner_mlp_kernel(const float* __restrict__ in, float* __restrict__ out,
                      const float* __restrict__ W1, const float* __restrict__ b1,
                      const float* __restrict__ W2T, const float* __restrict__ b2,
                      const float* __restrict__ W3, const float* __restrict__ b3) {
  const int t    = blockIdx.y;
  const int cell = blockIdx.x * 256 + threadIdx.x;   // 0 .. B*CG-1
  const int b    = cell >> 5;                        // / CG
  const int c    = cell & 31;

  const float* zp = in + (size_t)b * NHID + t * (CG * 8) + c * 8;
  float z[8];
  {
    const float4 z0 = *reinterpret_cast<const float4*>(zp);
    const float4 z1 = *reinterpret_cast<const float4*>(zp + 4);
    z[0] = z0.x; z[1] = z0.y; z[2] = z0.z; z[3] = z0.w;
    z[4] = z1.x; z[5] = z1.y; z[6] = z1.z; z[7] = z1.w;
  }

  const float* w1t = W1 + t * (8 * 64);
  const float* b1t = b1 + t * 64;
  float h[64];
  #pragma unroll
  for (int j = 0; j < 64; ++j) {
    float a = b1t[j];
    #pragma unroll
    for (int q = 0; q < 8; ++q) a = fmaf(z[q], w1t[q * 64 + j], a);
    h[j] = fmaxf(a, 0.f);
  }

  const float* w2t = W2T + t * 4096;
  const float* b2t = b2 + t * 64;
  const float* w3t = W3 + t * 64;
  float y = b3[t];
  for (int k = 0; k < 64; ++k) {          // runtime loop; inner j unrolled
    float a = b2t[k];
    const float* wr = w2t + k * 64;       // contiguous 256B row, uniform addr
    #pragma unroll
    for (int j = 0; j < 64; ++j) a = fmaf(h[j], wr[j], a);
    y = fmaf(fmaxf(a, 0.f), w3t[k], y);
  }
  out[(size_t)b * PREV + t * CG + c] = y;
}

// ---------------------------------------------------------------------------
// Head: logits = Y @ Wfc + bfc ; per-row NLL into rowloss (one wave per row)
// ---------------------------------------------------------------------------
__global__ __launch_bounds__(64)
void head_kernel(const float* __restrict__ Y, const float* __restrict__ Wfc,
                 const float* __restrict__ bfc, const int* __restrict__ labels,
                 float* __restrict__ logits, float* __restrict__ rowloss) {
  const int b = blockIdx.x;
  const int lane = threadIdx.x;
  const float* yr = Y + (size_t)b * PREV;
  float acc[NCLS] = {};
  for (int k = lane; k < PREV; k += 64) {
    const float yv = yr[k];
    #pragma unroll
    for (int cI = 0; cI < NCLS; ++cI) acc[cI] = fmaf(yv, Wfc[k * NCLS + cI], acc[cI]);
  }
  #pragma unroll
  for (int cI = 0; cI < NCLS; ++cI) {
    #pragma unroll
    for (int off = 32; off; off >>= 1) acc[cI] += __shfl_down(acc[cI], off);
  }
  if (lane == 0) {
    float l[NCLS];
    float m = -1e30f;
    #pragma unroll
    for (int cI = 0; cI < NCLS; ++cI) { l[cI] = acc[cI] + bfc[cI]; m = fmaxf(m, l[cI]); }
    float se = 0.f;
    #pragma unroll
    for (int cI = 0; cI < NCLS; ++cI) se += __expf(l[cI] - m);
    const float lse = m + __logf(se);
    #pragma unroll
    for (int cI = 0; cI < NCLS; ++cI) logits[(size_t)b * NCLS + cI] = l[cI];
    const int lab = labels[b];
    float picked = 0.f;
    #pragma unroll
    for (int cI = 0; cI < NCLS; ++cI) picked += (cI == lab) ? l[cI] : 0.f;  // no runtime idx
    rowloss[b] = lse - picked;
  }
}

// ---------------------------------------------------------------------------
// Deterministic loss reduction (single block) -> d_out[B*NCLS]
// ---------------------------------------------------------------------------
__global__ __launch_bounds__(256)
void loss_reduce_kernel(const float* __restrict__ rowloss, float* __restrict__ loss_out) {
  float s = 0.f;
  for (int i = threadIdx.x; i < BATCH; i += 256) s += rowloss[i];
  #pragma unroll
  for (int off = 32; off; off >>= 1) s += __shfl_down(s, off);
  __shared__ float sb[4];
  if ((threadIdx.x & 63) == 0) sb[threadIdx.x >> 6] = s;
  __syncthreads();
  if (threadIdx.x == 0) loss_out[0] = (sb[0] + sb[1] + sb[2] + sb[3]) * (1.f / BATCH);
}

// ---------------------------------------------------------------------------
extern "C" void kernel_launch(void* const* d_in, const int* in_sizes, int n_in,
                              void* d_out, int out_size, void* d_ws, size_t ws_size,
                              hipStream_t stream) {
  const float* x      = (const float*)d_in[0];
  const int*   labels = (const int*)  d_in[1];
  const float* Wout0  = (const float*)d_in[2];
  const float* bout0  = (const float*)d_in[3];
  const float* Wout1  = (const float*)d_in[4];
  const float* bout1  = (const float*)d_in[5];
  const float* Wout2  = (const float*)d_in[6];
  const float* bout2  = (const float*)d_in[7];
  const float* W1     = (const float*)d_in[8];
  const float* b1     = (const float*)d_in[9];
  const float* W2     = (const float*)d_in[10];
  const float* b2     = (const float*)d_in[11];
  const float* W3     = (const float*)d_in[12];
  const float* b3     = (const float*)d_in[13];
  const float* Wfc    = (const float*)d_in[14];
  const float* bfc    = (const float*)d_in[15];

  char* ws = (char*)d_ws;
  float* Abuf    = (float*)(ws);                                  // 4096*4096 f32 = 64 MB
  float* Ybuf    = (float*)(ws + ((size_t)64 << 20));             // 4096*512  f32 =  8 MB
  float* W2T     = (float*)(ws + ((size_t)72 << 20));             // 16*64*64  f32 = 256 KB
  float* rowloss = (float*)(ws + ((size_t)73 << 20));             // 4096 f32

  float* logits  = (float*)d_out;
  float* loss    = logits + (size_t)BATCH * NCLS;

  transpose_w2_kernel<<<dim3(NTYPES), dim3(256), 0, stream>>>(W2, W2T);

  const dim3 ggrid(NHID / 64, BATCH / 64), gblk(256);
  const dim3 igrid(BATCH * CG / 256, NTYPES), iblk(256);

  // layer 0
  gemm_bias_kernel<<<ggrid, gblk, 0, stream>>>(x, Wout0, bout0, Abuf, NHID, 1024);
  layernorm_kernel<<<dim3(BATCH), dim3(256), 0, stream>>>(Abuf, NHID);
  inner_mlp_kernel<<<igrid, iblk, 0, stream>>>(Abuf, Ybuf, W1, b1, W2T, b2, W3, b3);
  // layer 1
  gemm_bias_kernel<<<ggrid, gblk, 0, stream>>>(Ybuf, Wout1, bout1, Abuf, NHID, PREV);
  layernorm_kernel<<<dim3(BATCH), dim3(256), 0, stream>>>(Abuf, NHID);
  inner_mlp_kernel<<<igrid, iblk, 0, stream>>>(Abuf, Ybuf, W1, b1, W2T, b2, W3, b3);
  // layer 2
  gemm_bias_kernel<<<ggrid, gblk, 0, stream>>>(Ybuf, Wout2, bout2, Abuf, NHID, PREV);
  layernorm_kernel<<<dim3(BATCH), dim3(256), 0, stream>>>(Abuf, NHID);
  inner_mlp_kernel<<<igrid, iblk, 0, stream>>>(Abuf, Ybuf, W1, b1, W2T, b2, W3, b3);

  // head + loss
  head_kernel<<<dim3(BATCH), dim3(64), 0, stream>>>(Ybuf, Wfc, bfc, labels, logits, rowloss);
  loss_reduce_kernel<<<dim3(1), dim3(256), 0, stream>>>(rowloss, loss);
}

// Round 2
// 1081.122 us; speedup vs baseline: 1.7013x; 1.7013x over previous
//
#include <hip/hip_runtime.h>
#include <hip/hip_bf16.h>
#include <math.h>

// Problem constants
constexpr int BATCH   = 4096;
constexpr int NCLS    = 10;
constexpr int NHID    = 4096;   // OUT_HIDDEN
constexpr int PREV    = 512;    // NHID / ARG_IN
constexpr int NTYPES  = 16;
constexpr int CG      = 32;     // cells per type per row: 4096/(16*8)
constexpr float LN_EPS = 1e-5f;

typedef __attribute__((ext_vector_type(8))) short short8;   // 8 bf16 (4 VGPRs)
typedef __attribute__((ext_vector_type(4))) float f32x4;    // MFMA accumulator

// ---------------------------------------------------------------------------
// bf16 MFMA GEMM (m97 structure): C[M,N] = A[M,K] @ BT[N,K]^T + bias
// 128x128 tile, BK=32, 4 waves (2x2), each wave 64x64 = 4x4 16x16 fragments.
// global_load_lds width=16 into linear LDS [row][32] bf16 (64B rows).
// ---------------------------------------------------------------------------
__global__ __launch_bounds__(256)
void gemm_mfma_kernel(const __hip_bfloat16* __restrict__ A,   // M x K
                      const __hip_bfloat16* __restrict__ BT,  // N x K
                      const float* __restrict__ bias,
                      float* __restrict__ C,                  // M x N
                      int N, int K) {
  __shared__ __hip_bfloat16 As[128 * 32];
  __shared__ __hip_bfloat16 Bs[128 * 32];
  const int tid  = threadIdx.x;
  const int wid  = tid >> 6;
  const int lane = tid & 63;
  const int row0 = blockIdx.y * 128;
  const int col0 = blockIdx.x * 128;
  const int wrow = (wid >> 1) * 64;
  const int wcol = (wid & 1) * 64;

  f32x4 acc[4][4] = {};

  // staging geometry: each wave stages 32 rows of A and 32 rows of BT
  const int sr = wid * 32;            // wave's row base within the 128-row tile
  const int lr = lane >> 2;           // row within a 16-row chunk
  const int lc = (lane & 3) * 8;      // element offset within row (8 bf16 = 16B)

  const int fr = lane & 15;           // fragment row/col
  const int fo = (lane >> 4) * 8;     // fragment k-offset (8 contiguous k)

  for (int k0 = 0; k0 < K; k0 += 32) {
    const __hip_bfloat16* ga0 = A  + (size_t)(row0 + sr +      lr) * K + k0 + lc;
    const __hip_bfloat16* ga1 = A  + (size_t)(row0 + sr + 16 + lr) * K + k0 + lc;
    const __hip_bfloat16* gb0 = BT + (size_t)(col0 + sr +      lr) * K + k0 + lc;
    const __hip_bfloat16* gb1 = BT + (size_t)(col0 + sr + 16 + lr) * K + k0 + lc;
    __builtin_amdgcn_global_load_lds((const __attribute__((address_space(1))) void*)ga0,
                                     (__attribute__((address_space(3))) void*)&As[(sr     ) * 32], 16, 0, 0);
    __builtin_amdgcn_global_load_lds((const __attribute__((address_space(1))) void*)ga1,
                                     (__attribute__((address_space(3))) void*)&As[(sr + 16) * 32], 16, 0, 0);
    __builtin_amdgcn_global_load_lds((const __attribute__((address_space(1))) void*)gb0,
                                     (__attribute__((address_space(3))) void*)&Bs[(sr     ) * 32], 16, 0, 0);
    __builtin_amdgcn_global_load_lds((const __attribute__((address_space(1))) void*)gb1,
                                     (__attribute__((address_space(3))) void*)&Bs[(sr + 16) * 32], 16, 0, 0);
    __syncthreads();

    short8 af[4], bfr[4];
    #pragma unroll
    for (int i = 0; i < 4; ++i)
      af[i] = *reinterpret_cast<const short8*>(&As[(wrow + i * 16 + fr) * 32 + fo]);
    #pragma unroll
    for (int j = 0; j < 4; ++j)
      bfr[j] = *reinterpret_cast<const short8*>(&Bs[(wcol + j * 16 + fr) * 32 + fo]);

    #pragma unroll
    for (int i = 0; i < 4; ++i)
      #pragma unroll
      for (int j = 0; j < 4; ++j)
        acc[i][j] = __builtin_amdgcn_mfma_f32_16x16x32_bf16(af[i], bfr[j], acc[i][j], 0, 0, 0);
    __syncthreads();
  }

  // epilogue: C/D layout row=(lane>>4)*4+r, col=lane&15  [m89/m91]
  #pragma unroll
  for (int j = 0; j < 4; ++j) {
    const int cc = col0 + wcol + j * 16 + (lane & 15);
    const float bv = bias[cc];
    #pragma unroll
    for (int i = 0; i < 4; ++i) {
      const int rr = row0 + wrow + i * 16 + (lane >> 4) * 4;
      #pragma unroll
      for (int r = 0; r < 4; ++r)
        C[(size_t)(rr + r) * N + cc] = acc[i][j][r] + bv;
    }
  }
}

// ---------------------------------------------------------------------------
// fp32 -> bf16 conversion (vectorized)
// ---------------------------------------------------------------------------
__global__ __launch_bounds__(256)
void cvt_bf16_kernel(const float* __restrict__ in, __hip_bfloat16* __restrict__ out, int n) {
  const int i = (blockIdx.x * 256 + threadIdx.x) * 4;
  if (i >= n) return;
  const float4 v = *reinterpret_cast<const float4*>(&in[i]);
  __hip_bfloat16 t[4];
  t[0] = __float2bfloat16(v.x); t[1] = __float2bfloat16(v.y);
  t[2] = __float2bfloat16(v.z); t[3] = __float2bfloat16(v.w);
  *reinterpret_cast<ushort4*>(&out[i]) = *reinterpret_cast<const ushort4*>(t);
}

// ---------------------------------------------------------------------------
// W (K x N fp32) -> WT (N x K bf16) transpose+convert, 64x64 LDS tiles
// ---------------------------------------------------------------------------
__global__ __launch_bounds__(256)
void transpose_cvt_kernel(const float* __restrict__ W, __hip_bfloat16* __restrict__ WT,
                          int K, int N) {
  __shared__ __hip_bfloat16 tile[64][65];
  const int tid = threadIdx.x;
  const int kt = blockIdx.y * 64, nt = blockIdx.x * 64;
  const int cn = tid & 63;
  for (int r = tid >> 6; r < 64; r += 4)
    tile[cn][r] = __float2bfloat16(W[(size_t)(kt + r) * N + nt + cn]);
  __syncthreads();
  for (int r = tid >> 6; r < 64; r += 4)
    WT[(size_t)(nt + r) * K + kt + cn] = tile[r][cn];
}

// ---------------------------------------------------------------------------
// LayerNorm in place over rows of length N=4096 (no affine params)
// ---------------------------------------------------------------------------
__global__ __launch_bounds__(256)
void layernorm_kernel(float* __restrict__ X, int N) {
  float* p = X + (size_t)blockIdx.x * N;
  const int tid = threadIdx.x;
  float s = 0.f, ss = 0.f;
  for (int i = tid * 4; i < N; i += 256 * 4) {
    const float4 v = *reinterpret_cast<const float4*>(&p[i]);
    s  += v.x + v.y + v.z + v.w;
    ss += v.x * v.x + v.y * v.y + v.z * v.z + v.w * v.w;
  }
  #pragma unroll
  for (int off = 32; off; off >>= 1) {
    s  += __shfl_down(s, off);
    ss += __shfl_down(ss, off);
  }
  __shared__ float sb[4], ssb[4];
  __shared__ float mu_s, rs_s;
  if ((tid & 63) == 0) { sb[tid >> 6] = s; ssb[tid >> 6] = ss; }
  __syncthreads();
  if (tid == 0) {
    const float S  = sb[0] + sb[1] + sb[2] + sb[3];
    const float SS = ssb[0] + ssb[1] + ssb[2] + ssb[3];
    const float mu = S / N;
    const float var = SS / N - mu * mu;
    mu_s = mu;
    rs_s = rsqrtf(var + LN_EPS);
  }
  __syncthreads();
  const float mu = mu_s, rs = rs_s;
  for (int i = tid * 4; i < N; i += 256 * 4) {
    float4 v = *reinterpret_cast<const float4*>(&p[i]);
    v.x = (v.x - mu) * rs; v.y = (v.y - mu) * rs;
    v.z = (v.z - mu) * rs; v.w = (v.w - mu) * rs;
    *reinterpret_cast<float4*>(&p[i]) = v;
  }
}

// ---------------------------------------------------------------------------
// W2 transpose (fp32): W2[t][j][k] -> W2T[t][k][j]
// ---------------------------------------------------------------------------
__global__ __launch_bounds__(256)
void transpose_w2_kernel(const float* __restrict__ W2, float* __restrict__ W2T) {
  const int t = blockIdx.x;
  for (int idx = threadIdx.x; idx < 64 * 64; idx += 256) {
    const int k = idx >> 6, j = idx & 63;
    W2T[t * 4096 + k * 64 + j] = W2[t * 4096 + j * 64 + k];
  }
}

// ---------------------------------------------------------------------------
// Inner grouped MLPs: in (B,4096) -> out fp32 (B,512) + bf16 copy for next GEMM
// ---------------------------------------------------------------------------
__global__ __launch_bounds__(256)
void inner_mlp_kernel(const float* __restrict__ in, float* __restrict__ out,
                      __hip_bfloat16* __restrict__ outb,
                      const float* __restrict__ W1, const float* __restrict__ b1,
                      const float* __restrict__ W2T, const float* __restrict__ b2,
                      const float* __restrict__ W3, const float* __restrict__ b3) {
  const int t    = blockIdx.y;
  const int cell = blockIdx.x * 256 + threadIdx.x;   // 0 .. B*CG-1
  const int b    = cell >> 5;                        // / CG
  const int c    = cell & 31;

  const float* zp = in + (size_t)b * NHID + t * (CG * 8) + c * 8;
  float z[8];
  {
    const float4 z0 = *reinterpret_cast<const float4*>(zp);
    const float4 z1 = *reinterpret_cast<const float4*>(zp + 4);
    z[0] = z0.x; z[1] = z0.y; z[2] = z0.z; z[3] = z0.w;
    z[4] = z1.x; z[5] = z1.y; z[6] = z1.z; z[7] = z1.w;
  }

  const float* w1t = W1 + t * (8 * 64);
  const float* b1t = b1 + t * 64;
  float h[64];
  #pragma unroll
  for (int j = 0; j < 64; ++j) {
    float a = b1t[j];
    #pragma unroll
    for (int q = 0; q < 8; ++q) a = fmaf(z[q], w1t[q * 64 + j], a);
    h[j] = fmaxf(a, 0.f);
  }

  const float* w2t = W2T + t * 4096;
  const float* b2t = b2 + t * 64;
  const float* w3t = W3 + t * 64;
  float y = b3[t];
  for (int k = 0; k < 64; ++k) {          // runtime loop; inner j unrolled
    float a = b2t[k];
    const float* wr = w2t + k * 64;       // contiguous 256B row, uniform addr
    #pragma unroll
    for (int j = 0; j < 64; ++j) a = fmaf(h[j], wr[j], a);
    y = fmaf(fmaxf(a, 0.f), w3t[k], y);
  }
  const size_t oidx = (size_t)b * PREV + t * CG + c;
  out[oidx]  = y;
  outb[oidx] = __float2bfloat16(y);
}

// ---------------------------------------------------------------------------
// Head: logits = Y @ Wfc + bfc ; per-row NLL into rowloss (one wave per row)
// ---------------------------------------------------------------------------
__global__ __launch_bounds__(64)
void head_kernel(const float* __restrict__ Y, const float* __restrict__ Wfc,
                 const float* __restrict__ bfc, const int* __restrict__ labels,
                 float* __restrict__ logits, float* __restrict__ rowloss) {
  const int b = blockIdx.x;
  const int lane = threadIdx.x;
  const float* yr = Y + (size_t)b * PREV;
  float acc[NCLS] = {};
  for (int k = lane; k < PREV; k += 64) {
    const float yv = yr[k];
    #pragma unroll
    for (int cI = 0; cI < NCLS; ++cI) acc[cI] = fmaf(yv, Wfc[k * NCLS + cI], acc[cI]);
  }
  #pragma unroll
  for (int cI = 0; cI < NCLS; ++cI) {
    #pragma unroll
    for (int off = 32; off; off >>= 1) acc[cI] += __shfl_down(acc[cI], off);
  }
  if (lane == 0) {
    float l[NCLS];
    float m = -1e30f;
    #pragma unroll
    for (int cI = 0; cI < NCLS; ++cI) { l[cI] = acc[cI] + bfc[cI]; m = fmaxf(m, l[cI]); }
    float se = 0.f;
    #pragma unroll
    for (int cI = 0; cI < NCLS; ++cI) se += __expf(l[cI] - m);
    const float lse = m + __logf(se);
    #pragma unroll
    for (int cI = 0; cI < NCLS; ++cI) logits[(size_t)b * NCLS + cI] = l[cI];
    const int lab = labels[b];
    float picked = 0.f;
    #pragma unroll
    for (int cI = 0; cI < NCLS; ++cI) picked += (cI == lab) ? l[cI] : 0.f;
    rowloss[b] = lse - picked;
  }
}

// ---------------------------------------------------------------------------
// Deterministic loss reduction (single block)
// ---------------------------------------------------------------------------
__global__ __launch_bounds__(256)
void loss_reduce_kernel(const float* __restrict__ rowloss, float* __restrict__ loss_out) {
  float s = 0.f;
  for (int i = threadIdx.x; i < BATCH; i += 256) s += rowloss[i];
  #pragma unroll
  for (int off = 32; off; off >>= 1) s += __shfl_down(s, off);
  __shared__ float sb[4];
  if ((threadIdx.x & 63) == 0) sb[threadIdx.x >> 6] = s;
  __syncthreads();
  if (threadIdx.x == 0) loss_out[0] = (sb[0] + sb[1] + sb[2] + sb[3]) * (1.f / BATCH);
}

// ---------------------------------------------------------------------------
extern "C" void kernel_launch(void* const* d_in, const int* in_sizes, int n_in,
                              void* d_out, int out_size, void* d_ws, size_t ws_size,
                              hipStream_t stream) {
  const float* x      = (const float*)d_in[0];
  const int*   labels = (const int*)  d_in[1];
  const float* Wout0  = (const float*)d_in[2];
  const float* bout0  = (const float*)d_in[3];
  const float* Wout1  = (const float*)d_in[4];
  const float* bout1  = (const float*)d_in[5];
  const float* Wout2  = (const float*)d_in[6];
  const float* bout2  = (const float*)d_in[7];
  const float* W1     = (const float*)d_in[8];
  const float* b1     = (const float*)d_in[9];
  const float* W2     = (const float*)d_in[10];
  const float* b2     = (const float*)d_in[11];
  const float* W3     = (const float*)d_in[12];
  const float* b3     = (const float*)d_in[13];
  const float* Wfc    = (const float*)d_in[14];
  const float* bfc    = (const float*)d_in[15];

  char* ws = (char*)d_ws;
  float*          Abuf    = (float*)(ws);                               // 64 MB fp32 4096x4096
  float*          Ybuf    = (float*)(ws + ((size_t)64 << 20));          //  8 MB fp32 4096x512
  __hip_bfloat16* Ybf     = (__hip_bfloat16*)(ws + ((size_t)72 << 20)); //  4 MB bf16 4096x512
  __hip_bfloat16* xbf     = (__hip_bfloat16*)(ws + ((size_t)76 << 20)); //  8 MB bf16 4096x1024
  __hip_bfloat16* WT0     = (__hip_bfloat16*)(ws + ((size_t)84 << 20)); //  8 MB bf16 4096x1024
  __hip_bfloat16* WT1     = (__hip_bfloat16*)(ws + ((size_t)92 << 20)); //  4 MB bf16 4096x512
  __hip_bfloat16* WT2     = (__hip_bfloat16*)(ws + ((size_t)96 << 20)); //  4 MB bf16 4096x512
  float*          W2T     = (float*)(ws + ((size_t)100 << 20));         // 256 KB
  float*          rowloss = (float*)(ws + ((size_t)101 << 20));         // 16 KB

  float* logits = (float*)d_out;
  float* loss   = logits + (size_t)BATCH * NCLS;

  // per-launch weight/input conversions (deterministic, cheap)
  cvt_bf16_kernel<<<dim3(BATCH * 1024 / 4 / 256), dim3(256), 0, stream>>>(x, xbf, BATCH * 1024);
  transpose_cvt_kernel<<<dim3(NHID / 64, 1024 / 64), dim3(256), 0, stream>>>(Wout0, WT0, 1024, NHID);
  transpose_cvt_kernel<<<dim3(NHID / 64, PREV / 64), dim3(256), 0, stream>>>(Wout1, WT1, PREV, NHID);
  transpose_cvt_kernel<<<dim3(NHID / 64, PREV / 64), dim3(256), 0, stream>>>(Wout2, WT2, PREV, NHID);
  transpose_w2_kernel<<<dim3(NTYPES), dim3(256), 0, stream>>>(W2, W2T);

  const dim3 ggrid(NHID / 128, BATCH / 128), gblk(256);
  const dim3 igrid(BATCH * CG / 256, NTYPES), iblk(256);

  // layer 0
  gemm_mfma_kernel<<<ggrid, gblk, 0, stream>>>(xbf, WT0, bout0, Abuf, NHID, 1024);
  layernorm_kernel<<<dim3(BATCH), dim3(256), 0, stream>>>(Abuf, NHID);
  inner_mlp_kernel<<<igrid, iblk, 0, stream>>>(Abuf, Ybuf, Ybf, W1, b1, W2T, b2, W3, b3);
  // layer 1
  gemm_mfma_kernel<<<ggrid, gblk, 0, stream>>>(Ybf, WT1, bout1, Abuf, NHID, PREV);
  layernorm_kernel<<<dim3(BATCH), dim3(256), 0, stream>>>(Abuf, NHID);
  inner_mlp_kernel<<<igrid, iblk, 0, stream>>>(Abuf, Ybuf, Ybf, W1, b1, W2T, b2, W3, b3);
  // layer 2
  gemm_mfma_kernel<<<ggrid, gblk, 0, stream>>>(Ybf, WT2, bout2, Abuf, NHID, PREV);
  layernorm_kernel<<<dim3(BATCH), dim3(256), 0, stream>>>(Abuf, NHID);
  inner_mlp_kernel<<<igrid, iblk, 0, stream>>>(Abuf, Ybuf, Ybf, W1, b1, W2T, b2, W3, b3);

  // head + loss
  head_kernel<<<dim3(BATCH), dim3(64), 0, stream>>>(Ybuf, Wfc, bfc, labels, logits, rowloss);
  loss_reduce_kernel<<<dim3(1), dim3(256), 0, stream>>>(rowloss, loss);
}

// Round 3
// 617.612 us; speedup vs baseline: 2.9781x; 1.7505x over previous
//
#include <hip/hip_runtime.h>
#include <hip/hip_bf16.h>
#include <math.h>

// Problem constants
constexpr int BATCH   = 4096;
constexpr int NCLS    = 10;
constexpr int NHID    = 4096;   // OUT_HIDDEN
constexpr int PREV    = 512;    // NHID / ARG_IN
constexpr int NTYPES  = 16;
constexpr int CG      = 32;     // cells per type per row: 4096/(16*8)
constexpr float LN_EPS = 1e-5f;

typedef __attribute__((ext_vector_type(8))) short short8;   // 8 bf16 (4 VGPRs)
typedef __attribute__((ext_vector_type(4))) float f32x4;    // MFMA accumulator

// ---------------------------------------------------------------------------
// bf16 MFMA GEMM (m97 structure): C[M,N] = A[M,K] @ BT[N,K]^T + bias
// ---------------------------------------------------------------------------
__global__ __launch_bounds__(256)
void gemm_mfma_kernel(const __hip_bfloat16* __restrict__ A,   // M x K
                      const __hip_bfloat16* __restrict__ BT,  // N x K
                      const float* __restrict__ bias,
                      float* __restrict__ C,                  // M x N
                      int N, int K) {
  __shared__ __hip_bfloat16 As[128 * 32];
  __shared__ __hip_bfloat16 Bs[128 * 32];
  const int tid  = threadIdx.x;
  const int wid  = tid >> 6;
  const int lane = tid & 63;
  const int row0 = blockIdx.y * 128;
  const int col0 = blockIdx.x * 128;
  const int wrow = (wid >> 1) * 64;
  const int wcol = (wid & 1) * 64;

  f32x4 acc[4][4] = {};

  const int sr = wid * 32;
  const int lr = lane >> 2;
  const int lc = (lane & 3) * 8;

  const int fr = lane & 15;
  const int fo = (lane >> 4) * 8;

  for (int k0 = 0; k0 < K; k0 += 32) {
    const __hip_bfloat16* ga0 = A  + (size_t)(row0 + sr +      lr) * K + k0 + lc;
    const __hip_bfloat16* ga1 = A  + (size_t)(row0 + sr + 16 + lr) * K + k0 + lc;
    const __hip_bfloat16* gb0 = BT + (size_t)(col0 + sr +      lr) * K + k0 + lc;
    const __hip_bfloat16* gb1 = BT + (size_t)(col0 + sr + 16 + lr) * K + k0 + lc;
    __builtin_amdgcn_global_load_lds((const __attribute__((address_space(1))) void*)ga0,
                                     (__attribute__((address_space(3))) void*)&As[(sr     ) * 32], 16, 0, 0);
    __builtin_amdgcn_global_load_lds((const __attribute__((address_space(1))) void*)ga1,
                                     (__attribute__((address_space(3))) void*)&As[(sr + 16) * 32], 16, 0, 0);
    __builtin_amdgcn_global_load_lds((const __attribute__((address_space(1))) void*)gb0,
                                     (__attribute__((address_space(3))) void*)&Bs[(sr     ) * 32], 16, 0, 0);
    __builtin_amdgcn_global_load_lds((const __attribute__((address_space(1))) void*)gb1,
                                     (__attribute__((address_space(3))) void*)&Bs[(sr + 16) * 32], 16, 0, 0);
    __syncthreads();

    short8 af[4], bfr[4];
    #pragma unroll
    for (int i = 0; i < 4; ++i)
      af[i] = *reinterpret_cast<const short8*>(&As[(wrow + i * 16 + fr) * 32 + fo]);
    #pragma unroll
    for (int j = 0; j < 4; ++j)
      bfr[j] = *reinterpret_cast<const short8*>(&Bs[(wcol + j * 16 + fr) * 32 + fo]);

    #pragma unroll
    for (int i = 0; i < 4; ++i)
      #pragma unroll
      for (int j = 0; j < 4; ++j)
        acc[i][j] = __builtin_amdgcn_mfma_f32_16x16x32_bf16(af[i], bfr[j], acc[i][j], 0, 0, 0);
    __syncthreads();
  }

  #pragma unroll
  for (int j = 0; j < 4; ++j) {
    const int cc = col0 + wcol + j * 16 + (lane & 15);
    const float bv = bias[cc];
    #pragma unroll
    for (int i = 0; i < 4; ++i) {
      const int rr = row0 + wrow + i * 16 + (lane >> 4) * 4;
      #pragma unroll
      for (int r = 0; r < 4; ++r)
        C[(size_t)(rr + r) * N + cc] = acc[i][j][r] + bv;
    }
  }
}

// ---------------------------------------------------------------------------
// fp32 -> bf16 conversion (vectorized)
// ---------------------------------------------------------------------------
__global__ __launch_bounds__(256)
void cvt_bf16_kernel(const float* __restrict__ in, __hip_bfloat16* __restrict__ out, int n) {
  const int i = (blockIdx.x * 256 + threadIdx.x) * 4;
  if (i >= n) return;
  const float4 v = *reinterpret_cast<const float4*>(&in[i]);
  __hip_bfloat16 t[4];
  t[0] = __float2bfloat16(v.x); t[1] = __float2bfloat16(v.y);
  t[2] = __float2bfloat16(v.z); t[3] = __float2bfloat16(v.w);
  *reinterpret_cast<ushort4*>(&out[i]) = *reinterpret_cast<const ushort4*>(t);
}

// ---------------------------------------------------------------------------
// W (K x N fp32) -> WT (N x K bf16) transpose+convert, 64x64 LDS tiles
// ---------------------------------------------------------------------------
__global__ __launch_bounds__(256)
void transpose_cvt_kernel(const float* __restrict__ W, __hip_bfloat16* __restrict__ WT,
                          int K, int N) {
  __shared__ __hip_bfloat16 tile[64][65];
  const int tid = threadIdx.x;
  const int kt = blockIdx.y * 64, nt = blockIdx.x * 64;
  const int cn = tid & 63;
  for (int r = tid >> 6; r < 64; r += 4)
    tile[cn][r] = __float2bfloat16(W[(size_t)(kt + r) * N + nt + cn]);
  __syncthreads();
  for (int r = tid >> 6; r < 64; r += 4)
    WT[(size_t)(nt + r) * K + kt + cn] = tile[r][cn];
}

// ---------------------------------------------------------------------------
// W2 (T,h,n) fp32 -> W2Tb (T,n,h) bf16
// ---------------------------------------------------------------------------
__global__ __launch_bounds__(256)
void transpose_w2_bf16_kernel(const float* __restrict__ W2, __hip_bfloat16* __restrict__ W2Tb) {
  const int t = blockIdx.x;
  for (int idx = threadIdx.x; idx < 64 * 64; idx += 256) {
    const int n = idx >> 6, h = idx & 63;
    W2Tb[t * 4096 + n * 64 + h] = __float2bfloat16(W2[t * 4096 + h * 64 + n]);
  }
}

// ---------------------------------------------------------------------------
// LayerNorm in place over rows of length N=4096
// ---------------------------------------------------------------------------
__global__ __launch_bounds__(256)
void layernorm_kernel(float* __restrict__ X, int N) {
  float* p = X + (size_t)blockIdx.x * N;
  const int tid = threadIdx.x;
  float s = 0.f, ss = 0.f;
  for (int i = tid * 4; i < N; i += 256 * 4) {
    const float4 v = *reinterpret_cast<const float4*>(&p[i]);
    s  += v.x + v.y + v.z + v.w;
    ss += v.x * v.x + v.y * v.y + v.z * v.z + v.w * v.w;
  }
  #pragma unroll
  for (int off = 32; off; off >>= 1) {
    s  += __shfl_down(s, off);
    ss += __shfl_down(ss, off);
  }
  __shared__ float sb[4], ssb[4];
  __shared__ float mu_s, rs_s;
  if ((tid & 63) == 0) { sb[tid >> 6] = s; ssb[tid >> 6] = ss; }
  __syncthreads();
  if (tid == 0) {
    const float S  = sb[0] + sb[1] + sb[2] + sb[3];
    const float SS = ssb[0] + ssb[1] + ssb[2] + ssb[3];
    const float mu = S / N;
    const float var = SS / N - mu * mu;
    mu_s = mu;
    rs_s = rsqrtf(var + LN_EPS);
  }
  __syncthreads();
  const float mu = mu_s, rs = rs_s;
  for (int i = tid * 4; i < N; i += 256 * 4) {
    float4 v = *reinterpret_cast<const float4*>(&p[i]);
    v.x = (v.x - mu) * rs; v.y = (v.y - mu) * rs;
    v.z = (v.z - mu) * rs; v.w = (v.w - mu) * rs;
    *reinterpret_cast<float4*>(&p[i]) = v;
  }
}

// ---------------------------------------------------------------------------
// Fused inner grouped MLPs with MFMA middle layer.
// Block: 256 thr (4 waves), one cell type, 128 rows (row = b*32+c).
// L1 (K=8) fp32 VALU -> H1 bf16 in LDS (XOR-swizzled).
// L2 (64x64) mfma_f32_16x16x32_bf16, 16 MFMA/wave.
// L3 in-register on C-fragments + shfl_xor reduce.
// ---------------------------------------------------------------------------
__global__ __launch_bounds__(256)
void inner_mlp_mfma_kernel(const float* __restrict__ in, float* __restrict__ out,
                           __hip_bfloat16* __restrict__ outb,
                           const __hip_bfloat16* __restrict__ W2Tb,
                           const float* __restrict__ W1, const float* __restrict__ b1,
                           const float* __restrict__ b2,
                           const float* __restrict__ W3, const float* __restrict__ b3) {
  __shared__ __hip_bfloat16 H1s[128 * 64];   // row-major, elem ^= (row&7)<<3 swizzle
  const int tid  = threadIdx.x;
  const int lane = tid & 63;
  const int w    = tid >> 6;
  const int t    = blockIdx.y;
  const int rowbase = blockIdx.x * 128;

  const int fc = lane & 15;      // fragment col / row index
  const int fq = lane >> 4;      // fragment quad

  // --- early: preload W2 B-fragments (bf16 NxK) — hides under phase A
  short8 bfrag[4][2];
  #pragma unroll
  for (int cf = 0; cf < 4; ++cf)
    #pragma unroll
    for (int ks = 0; ks < 2; ++ks)
      bfrag[cf][ks] = *reinterpret_cast<const short8*>(
          &W2Tb[(size_t)t * 4096 + (cf * 16 + fc) * 64 + ks * 32 + fq * 8]);

  // --- phase A: layer1 (fp32) for 4 rows x 8 cols per thread
  const int rg = tid >> 3;       // row group (x4 rows)
  const int cg = tid & 7;        // col group (x8 cols)

  float z[4][8];
  #pragma unroll
  for (int rr = 0; rr < 4; ++rr) {
    const int g = rowbase + rg * 4 + rr;
    const float* zp = in + (size_t)(g >> 5) * NHID + t * 256 + (g & 31) * 8;
    const float4 z0 = *reinterpret_cast<const float4*>(zp);
    const float4 z1 = *reinterpret_cast<const float4*>(zp + 4);
    z[rr][0] = z0.x; z[rr][1] = z0.y; z[rr][2] = z0.z; z[rr][3] = z0.w;
    z[rr][4] = z1.x; z[rr][5] = z1.y; z[rr][6] = z1.z; z[rr][7] = z1.w;
  }

  float h[4][8];
  {
    const float4 bv0 = *reinterpret_cast<const float4*>(&b1[t * 64 + cg * 8]);
    const float4 bv1 = *reinterpret_cast<const float4*>(&b1[t * 64 + cg * 8 + 4]);
    #pragma unroll
    for (int rr = 0; rr < 4; ++rr) {
      h[rr][0] = bv0.x; h[rr][1] = bv0.y; h[rr][2] = bv0.z; h[rr][3] = bv0.w;
      h[rr][4] = bv1.x; h[rr][5] = bv1.y; h[rr][6] = bv1.z; h[rr][7] = bv1.w;
    }
  }
  {
    const float* w1t = W1 + t * 512 + cg * 8;
    #pragma unroll
    for (int q = 0; q < 8; ++q) {
      const float4 wa = *reinterpret_cast<const float4*>(&w1t[q * 64]);
      const float4 wb = *reinterpret_cast<const float4*>(&w1t[q * 64 + 4]);
      float wv[8] = { wa.x, wa.y, wa.z, wa.w, wb.x, wb.y, wb.z, wb.w };
      #pragma unroll
      for (int rr = 0; rr < 4; ++rr)
        #pragma unroll
        for (int jj = 0; jj < 8; ++jj)
          h[rr][jj] = fmaf(z[rr][q], wv[jj], h[rr][jj]);
    }
  }
  #pragma unroll
  for (int rr = 0; rr < 4; ++rr) {
    const int row = rg * 4 + rr;
    union { short8 v; __hip_bfloat16 e[8]; } pk;
    #pragma unroll
    for (int jj = 0; jj < 8; ++jj)
      pk.e[jj] = __float2bfloat16(fmaxf(h[rr][jj], 0.f));
    const int eo = row * 64 + ((cg * 8) ^ ((row & 7) << 3));
    *reinterpret_cast<short8*>(&H1s[eo]) = pk.v;
  }

  __syncthreads();

  // --- phase B: layer2 MFMA. Wave w owns rows w*32 .. w*32+31.
  f32x4 acc[2][4] = {};
  #pragma unroll
  for (int ks = 0; ks < 2; ++ks) {
    short8 a0, a1;
    {
      const int row = w * 32 + 0 * 16 + fc;
      const int k0 = ks * 32 + fq * 8;
      a0 = *reinterpret_cast<const short8*>(&H1s[row * 64 + (k0 ^ ((row & 7) << 3))]);
    }
    {
      const int row = w * 32 + 1 * 16 + fc;
      const int k0 = ks * 32 + fq * 8;
      a1 = *reinterpret_cast<const short8*>(&H1s[row * 64 + (k0 ^ ((row & 7) << 3))]);
    }
    #pragma unroll
    for (int cf = 0; cf < 4; ++cf) {
      acc[0][cf] = __builtin_amdgcn_mfma_f32_16x16x32_bf16(a0, bfrag[cf][ks], acc[0][cf], 0, 0, 0);
      acc[1][cf] = __builtin_amdgcn_mfma_f32_16x16x32_bf16(a1, bfrag[cf][ks], acc[1][cf], 0, 0, 0);
    }
  }

  // --- phase C: layer3. acc[rf][cf][r] = H2[w*32 + rf*16 + fq*4 + r][cf*16 + fc]
  float b2v[4], w3v[4];
  #pragma unroll
  for (int cf = 0; cf < 4; ++cf) {
    b2v[cf] = b2[t * 64 + cf * 16 + fc];
    w3v[cf] = W3[t * 64 + cf * 16 + fc];
  }
  float p[2][4];
  #pragma unroll
  for (int rf = 0; rf < 2; ++rf)
    #pragma unroll
    for (int r = 0; r < 4; ++r) {
      float s = 0.f;
      #pragma unroll
      for (int cf = 0; cf < 4; ++cf)
        s = fmaf(fmaxf(acc[rf][cf][r] + b2v[cf], 0.f), w3v[cf], s);
      s += __shfl_xor(s, 1);
      s += __shfl_xor(s, 2);
      s += __shfl_xor(s, 4);
      s += __shfl_xor(s, 8);
      p[rf][r] = s;
    }

  if (fc == 0) {
    const float yb = b3[t];
    #pragma unroll
    for (int rf = 0; rf < 2; ++rf)
      #pragma unroll
      for (int r = 0; r < 4; ++r) {
        const int g = rowbase + w * 32 + rf * 16 + fq * 4 + r;
        const float y = p[rf][r] + yb;
        const size_t oidx = (size_t)(g >> 5) * PREV + t * CG + (g & 31);
        out[oidx]  = y;
        outb[oidx] = __float2bfloat16(y);
      }
  }
}

// ---------------------------------------------------------------------------
// Head: logits = Y @ Wfc + bfc ; per-row NLL into rowloss (one wave per row)
// ---------------------------------------------------------------------------
__global__ __launch_bounds__(64)
void head_kernel(const float* __restrict__ Y, const float* __restrict__ Wfc,
                 const float* __restrict__ bfc, const int* __restrict__ labels,
                 float* __restrict__ logits, float* __restrict__ rowloss) {
  const int b = blockIdx.x;
  const int lane = threadIdx.x;
  const float* yr = Y + (size_t)b * PREV;
  float acc[NCLS] = {};
  for (int k = lane; k < PREV; k += 64) {
    const float yv = yr[k];
    #pragma unroll
    for (int cI = 0; cI < NCLS; ++cI) acc[cI] = fmaf(yv, Wfc[k * NCLS + cI], acc[cI]);
  }
  #pragma unroll
  for (int cI = 0; cI < NCLS; ++cI) {
    #pragma unroll
    for (int off = 32; off; off >>= 1) acc[cI] += __shfl_down(acc[cI], off);
  }
  if (lane == 0) {
    float l[NCLS];
    float m = -1e30f;
    #pragma unroll
    for (int cI = 0; cI < NCLS; ++cI) { l[cI] = acc[cI] + bfc[cI]; m = fmaxf(m, l[cI]); }
    float se = 0.f;
    #pragma unroll
    for (int cI = 0; cI < NCLS; ++cI) se += __expf(l[cI] - m);
    const float lse = m + __logf(se);
    #pragma unroll
    for (int cI = 0; cI < NCLS; ++cI) logits[(size_t)b * NCLS + cI] = l[cI];
    const int lab = labels[b];
    float picked = 0.f;
    #pragma unroll
    for (int cI = 0; cI < NCLS; ++cI) picked += (cI == lab) ? l[cI] : 0.f;
    rowloss[b] = lse - picked;
  }
}

// ---------------------------------------------------------------------------
// Deterministic loss reduction (single block)
// ---------------------------------------------------------------------------
__global__ __launch_bounds__(256)
void loss_reduce_kernel(const float* __restrict__ rowloss, float* __restrict__ loss_out) {
  float s = 0.f;
  for (int i = threadIdx.x; i < BATCH; i += 256) s += rowloss[i];
  #pragma unroll
  for (int off = 32; off; off >>= 1) s += __shfl_down(s, off);
  __shared__ float sb[4];
  if ((threadIdx.x & 63) == 0) sb[threadIdx.x >> 6] = s;
  __syncthreads();
  if (threadIdx.x == 0) loss_out[0] = (sb[0] + sb[1] + sb[2] + sb[3]) * (1.f / BATCH);
}

// ---------------------------------------------------------------------------
extern "C" void kernel_launch(void* const* d_in, const int* in_sizes, int n_in,
                              void* d_out, int out_size, void* d_ws, size_t ws_size,
                              hipStream_t stream) {
  const float* x      = (const float*)d_in[0];
  const int*   labels = (const int*)  d_in[1];
  const float* Wout0  = (const float*)d_in[2];
  const float* bout0  = (const float*)d_in[3];
  const float* Wout1  = (const float*)d_in[4];
  const float* bout1  = (const float*)d_in[5];
  const float* Wout2  = (const float*)d_in[6];
  const float* bout2  = (const float*)d_in[7];
  const float* W1     = (const float*)d_in[8];
  const float* b1     = (const float*)d_in[9];
  const float* W2     = (const float*)d_in[10];
  const float* b2     = (const float*)d_in[11];
  const float* W3     = (const float*)d_in[12];
  const float* b3     = (const float*)d_in[13];
  const float* Wfc    = (const float*)d_in[14];
  const float* bfc    = (const float*)d_in[15];

  char* ws = (char*)d_ws;
  float*          Abuf    = (float*)(ws);                               // 64 MB fp32 4096x4096
  float*          Ybuf    = (float*)(ws + ((size_t)64 << 20));          //  8 MB fp32 4096x512
  __hip_bfloat16* Ybf     = (__hip_bfloat16*)(ws + ((size_t)72 << 20)); //  4 MB bf16 4096x512
  __hip_bfloat16* xbf     = (__hip_bfloat16*)(ws + ((size_t)76 << 20)); //  8 MB bf16 4096x1024
  __hip_bfloat16* WT0     = (__hip_bfloat16*)(ws + ((size_t)84 << 20)); //  8 MB bf16 4096x1024
  __hip_bfloat16* WT1     = (__hip_bfloat16*)(ws + ((size_t)92 << 20)); //  4 MB bf16 4096x512
  __hip_bfloat16* WT2     = (__hip_bfloat16*)(ws + ((size_t)96 << 20)); //  4 MB bf16 4096x512
  __hip_bfloat16* W2Tb    = (__hip_bfloat16*)(ws + ((size_t)100 << 20));// 128 KB bf16 16x64x64
  float*          rowloss = (float*)(ws + ((size_t)101 << 20));         // 16 KB

  float* logits = (float*)d_out;
  float* loss   = logits + (size_t)BATCH * NCLS;

  // per-launch weight/input conversions (deterministic, cheap)
  cvt_bf16_kernel<<<dim3(BATCH * 1024 / 4 / 256), dim3(256), 0, stream>>>(x, xbf, BATCH * 1024);
  transpose_cvt_kernel<<<dim3(NHID / 64, 1024 / 64), dim3(256), 0, stream>>>(Wout0, WT0, 1024, NHID);
  transpose_cvt_kernel<<<dim3(NHID / 64, PREV / 64), dim3(256), 0, stream>>>(Wout1, WT1, PREV, NHID);
  transpose_cvt_kernel<<<dim3(NHID / 64, PREV / 64), dim3(256), 0, stream>>>(Wout2, WT2, PREV, NHID);
  transpose_w2_bf16_kernel<<<dim3(NTYPES), dim3(256), 0, stream>>>(W2, W2Tb);

  const dim3 ggrid(NHID / 128, BATCH / 128), gblk(256);
  const dim3 igrid(BATCH * CG / 128, NTYPES), iblk(256);

  // layer 0
  gemm_mfma_kernel<<<ggrid, gblk, 0, stream>>>(xbf, WT0, bout0, Abuf, NHID, 1024);
  layernorm_kernel<<<dim3(BATCH), dim3(256), 0, stream>>>(Abuf, NHID);
  inner_mlp_mfma_kernel<<<igrid, iblk, 0, stream>>>(Abuf, Ybuf, Ybf, W2Tb, W1, b1, b2, W3, b3);
  // layer 1
  gemm_mfma_kernel<<<ggrid, gblk, 0, stream>>>(Ybf, WT1, bout1, Abuf, NHID, PREV);
  layernorm_kernel<<<dim3(BATCH), dim3(256), 0, stream>>>(Abuf, NHID);
  inner_mlp_mfma_kernel<<<igrid, iblk, 0, stream>>>(Abuf, Ybuf, Ybf, W2Tb, W1, b1, b2, W3, b3);
  // layer 2
  gemm_mfma_kernel<<<ggrid, gblk, 0, stream>>>(Ybf, WT2, bout2, Abuf, NHID, PREV);
  layernorm_kernel<<<dim3(BATCH), dim3(256), 0, stream>>>(Abuf, NHID);
  inner_mlp_mfma_kernel<<<igrid, iblk, 0, stream>>>(Abuf, Ybuf, Ybf, W2Tb, W1, b1, b2, W3, b3);

  // head + loss
  head_kernel<<<dim3(BATCH), dim3(64), 0, stream>>>(Ybuf, Wfc, bfc, labels, logits, rowloss);
  loss_reduce_kernel<<<dim3(1), dim3(256), 0, stream>>>(rowloss, loss);
}

// Round 4
// 540.812 us; speedup vs baseline: 3.4010x; 1.1420x over previous
//
#include <hip/hip_runtime.h>
#include <hip/hip_bf16.h>
#include <math.h>

// Problem constants
constexpr int BATCH   = 4096;
constexpr int NCLS    = 10;
constexpr int NHID    = 4096;   // OUT_HIDDEN
constexpr int PREV    = 512;    // NHID / ARG_IN
constexpr int NTYPES  = 16;
constexpr int CG      = 32;     // cells per type per row: 4096/(16*8)
constexpr float LN_EPS = 1e-5f;

typedef __attribute__((ext_vector_type(8))) short short8;   // 8 bf16 (4 VGPRs)
typedef __attribute__((ext_vector_type(4))) float f32x4;    // MFMA accumulator

// ---------------------------------------------------------------------------
// bf16 MFMA GEMM (m97 structure): C[M,N] = A[M,K] @ BT[N,K]^T + bias
// ---------------------------------------------------------------------------
__global__ __launch_bounds__(256)
void gemm_mfma_kernel(const __hip_bfloat16* __restrict__ A,   // M x K
                      const __hip_bfloat16* __restrict__ BT,  // N x K
                      const float* __restrict__ bias,
                      float* __restrict__ C,                  // M x N
                      int N, int K) {
  __shared__ __hip_bfloat16 As[128 * 32];
  __shared__ __hip_bfloat16 Bs[128 * 32];
  const int tid  = threadIdx.x;
  const int wid  = tid >> 6;
  const int lane = tid & 63;
  const int row0 = blockIdx.y * 128;
  const int col0 = blockIdx.x * 128;
  const int wrow = (wid >> 1) * 64;
  const int wcol = (wid & 1) * 64;

  f32x4 acc[4][4] = {};

  const int sr = wid * 32;
  const int lr = lane >> 2;
  const int lc = (lane & 3) * 8;

  const int fr = lane & 15;
  const int fo = (lane >> 4) * 8;

  for (int k0 = 0; k0 < K; k0 += 32) {
    const __hip_bfloat16* ga0 = A  + (size_t)(row0 + sr +      lr) * K + k0 + lc;
    const __hip_bfloat16* ga1 = A  + (size_t)(row0 + sr + 16 + lr) * K + k0 + lc;
    const __hip_bfloat16* gb0 = BT + (size_t)(col0 + sr +      lr) * K + k0 + lc;
    const __hip_bfloat16* gb1 = BT + (size_t)(col0 + sr + 16 + lr) * K + k0 + lc;
    __builtin_amdgcn_global_load_lds((const __attribute__((address_space(1))) void*)ga0,
                                     (__attribute__((address_space(3))) void*)&As[(sr     ) * 32], 16, 0, 0);
    __builtin_amdgcn_global_load_lds((const __attribute__((address_space(1))) void*)ga1,
                                     (__attribute__((address_space(3))) void*)&As[(sr + 16) * 32], 16, 0, 0);
    __builtin_amdgcn_global_load_lds((const __attribute__((address_space(1))) void*)gb0,
                                     (__attribute__((address_space(3))) void*)&Bs[(sr     ) * 32], 16, 0, 0);
    __builtin_amdgcn_global_load_lds((const __attribute__((address_space(1))) void*)gb1,
                                     (__attribute__((address_space(3))) void*)&Bs[(sr + 16) * 32], 16, 0, 0);
    __syncthreads();

    short8 af[4], bfr[4];
    #pragma unroll
    for (int i = 0; i < 4; ++i)
      af[i] = *reinterpret_cast<const short8*>(&As[(wrow + i * 16 + fr) * 32 + fo]);
    #pragma unroll
    for (int j = 0; j < 4; ++j)
      bfr[j] = *reinterpret_cast<const short8*>(&Bs[(wcol + j * 16 + fr) * 32 + fo]);

    #pragma unroll
    for (int i = 0; i < 4; ++i)
      #pragma unroll
      for (int j = 0; j < 4; ++j)
        acc[i][j] = __builtin_amdgcn_mfma_f32_16x16x32_bf16(af[i], bfr[j], acc[i][j], 0, 0, 0);
    __syncthreads();
  }

  #pragma unroll
  for (int j = 0; j < 4; ++j) {
    const int cc = col0 + wcol + j * 16 + (lane & 15);
    const float bv = bias[cc];
    #pragma unroll
    for (int i = 0; i < 4; ++i) {
      const int rr = row0 + wrow + i * 16 + (lane >> 4) * 4;
      #pragma unroll
      for (int r = 0; r < 4; ++r)
        C[(size_t)(rr + r) * N + cc] = acc[i][j][r] + bv;
    }
  }
}

// ---------------------------------------------------------------------------
// fp32 -> bf16 conversion (vectorized)
// ---------------------------------------------------------------------------
__global__ __launch_bounds__(256)
void cvt_bf16_kernel(const float* __restrict__ in, __hip_bfloat16* __restrict__ out, int n) {
  const int i = (blockIdx.x * 256 + threadIdx.x) * 4;
  if (i >= n) return;
  const float4 v = *reinterpret_cast<const float4*>(&in[i]);
  __hip_bfloat16 t[4];
  t[0] = __float2bfloat16(v.x); t[1] = __float2bfloat16(v.y);
  t[2] = __float2bfloat16(v.z); t[3] = __float2bfloat16(v.w);
  *reinterpret_cast<ushort4*>(&out[i]) = *reinterpret_cast<const ushort4*>(t);
}

// ---------------------------------------------------------------------------
// W (K x N fp32) -> WT (N x K bf16) transpose+convert, 64x64 LDS tiles
// ---------------------------------------------------------------------------
__global__ __launch_bounds__(256)
void transpose_cvt_kernel(const float* __restrict__ W, __hip_bfloat16* __restrict__ WT,
                          int K, int N) {
  __shared__ __hip_bfloat16 tile[64][65];
  const int tid = threadIdx.x;
  const int kt = blockIdx.y * 64, nt = blockIdx.x * 64;
  const int cn = tid & 63;
  for (int r = tid >> 6; r < 64; r += 4)
    tile[cn][r] = __float2bfloat16(W[(size_t)(kt + r) * N + nt + cn]);
  __syncthreads();
  for (int r = tid >> 6; r < 64; r += 4)
    WT[(size_t)(nt + r) * K + kt + cn] = tile[r][cn];
}

// ---------------------------------------------------------------------------
// W2 (T,h,n) fp32 -> W2Tb (T,n,h) bf16
// ---------------------------------------------------------------------------
__global__ __launch_bounds__(256)
void transpose_w2_bf16_kernel(const float* __restrict__ W2, __hip_bfloat16* __restrict__ W2Tb) {
  const int t = blockIdx.x;
  for (int idx = threadIdx.x; idx < 64 * 64; idx += 256) {
    const int n = idx >> 6, h = idx & 63;
    W2Tb[t * 4096 + n * 64 + h] = __float2bfloat16(W2[t * 4096 + h * 64 + n]);
  }
}

// ---------------------------------------------------------------------------
// Fused LayerNorm + inner grouped MLPs.
// Block: 256 thr (4 waves), 4 batch rows, ALL 16 cell types (looped).
// Phase 0: wave w computes LN stats for batch row (row0+w).
// Per type t: L1 (K=8) fp32 VALU with on-the-fly (x-mu)*rs -> H1 bf16 LDS
// (XOR swizzle, 0-conflict pattern verified in round 3); 16 MFMA/wave; L3
// epilogue in-register + shfl_xor reduce.
// ---------------------------------------------------------------------------
__global__ __launch_bounds__(256)
void fused_ln_inner_kernel(const float* __restrict__ X,      // (B, 4096) pre-LN
                           float* __restrict__ out,          // (B, 512)
                           __hip_bfloat16* __restrict__ outb,
                           const __hip_bfloat16* __restrict__ W2Tb,
                           const float* __restrict__ W1, const float* __restrict__ b1,
                           const float* __restrict__ b2,
                           const float* __restrict__ W3, const float* __restrict__ b3) {
  __shared__ __hip_bfloat16 H1s[128 * 64];   // 16 KB, elem ^= (row&7)<<3 swizzle
  __shared__ float muS[4], rsS[4];
  const int tid  = threadIdx.x;
  const int lane = tid & 63;
  const int wvid = tid >> 6;
  const int row0 = blockIdx.x * 4;           // 4 batch rows per block

  // --- phase 0: LN stats, wave wvid handles batch row row0+wvid
  {
    const float* p = X + (size_t)(row0 + wvid) * NHID;
    float s = 0.f, ss = 0.f;
    #pragma unroll
    for (int i = 0; i < 16; ++i) {
      const float4 v = *reinterpret_cast<const float4*>(&p[i * 256 + lane * 4]);
      s  += v.x + v.y + v.z + v.w;
      ss += v.x * v.x + v.y * v.y + v.z * v.z + v.w * v.w;
    }
    #pragma unroll
    for (int off = 32; off; off >>= 1) { s += __shfl_xor(s, off); ss += __shfl_xor(ss, off); }
    if (lane == 0) {
      const float mu = s * (1.f / 4096.f);
      muS[wvid] = mu;
      rsS[wvid] = rsqrtf(ss * (1.f / 4096.f) - mu * mu + LN_EPS);
    }
  }
  __syncthreads();

  const int fc = lane & 15;      // fragment col / row index
  const int fq = lane >> 4;      // fragment quad
  const int rg = tid >> 3;       // cell group: cells rg*4 .. rg*4+3 (same batch row)
  const int cg = tid & 7;        // neuron group: neurons cg*8 .. +8

  const int bl = rg >> 3;        // local batch row of this thread's cells
  const float mu = muS[bl], rs = rsS[bl];
  const float* xrow = X + (size_t)(row0 + bl) * NHID;

  for (int t = 0; t < NTYPES; ++t) {
    // --- L1: 4 cells x 8 neurons per thread, LN applied on the fly
    float z[4][8];
    {
      const float* zp = xrow + t * 256 + (rg & 7) * 32;
      #pragma unroll
      for (int rr = 0; rr < 4; ++rr) {
        const float4 a = *reinterpret_cast<const float4*>(&zp[rr * 8]);
        const float4 b = *reinterpret_cast<const float4*>(&zp[rr * 8 + 4]);
        z[rr][0] = (a.x - mu) * rs; z[rr][1] = (a.y - mu) * rs;
        z[rr][2] = (a.z - mu) * rs; z[rr][3] = (a.w - mu) * rs;
        z[rr][4] = (b.x - mu) * rs; z[rr][5] = (b.y - mu) * rs;
        z[rr][6] = (b.z - mu) * rs; z[rr][7] = (b.w - mu) * rs;
      }
    }
    float h[4][8];
    {
      const float4 bv0 = *reinterpret_cast<const float4*>(&b1[t * 64 + cg * 8]);
      const float4 bv1 = *reinterpret_cast<const float4*>(&b1[t * 64 + cg * 8 + 4]);
      #pragma unroll
      for (int rr = 0; rr < 4; ++rr) {
        h[rr][0] = bv0.x; h[rr][1] = bv0.y; h[rr][2] = bv0.z; h[rr][3] = bv0.w;
        h[rr][4] = bv1.x; h[rr][5] = bv1.y; h[rr][6] = bv1.z; h[rr][7] = bv1.w;
      }
    }
    {
      const float* w1t = W1 + t * 512 + cg * 8;
      #pragma unroll
      for (int q = 0; q < 8; ++q) {
        const float4 wa = *reinterpret_cast<const float4*>(&w1t[q * 64]);
        const float4 wb = *reinterpret_cast<const float4*>(&w1t[q * 64 + 4]);
        float wv[8] = { wa.x, wa.y, wa.z, wa.w, wb.x, wb.y, wb.z, wb.w };
        #pragma unroll
        for (int rr = 0; rr < 4; ++rr)
          #pragma unroll
          for (int jj = 0; jj < 8; ++jj)
            h[rr][jj] = fmaf(z[rr][q], wv[jj], h[rr][jj]);
      }
    }
    #pragma unroll
    for (int rr = 0; rr < 4; ++rr) {
      const int row = rg * 4 + rr;
      union { short8 v; __hip_bfloat16 e[8]; } pk;
      #pragma unroll
      for (int jj = 0; jj < 8; ++jj)
        pk.e[jj] = __float2bfloat16(fmaxf(h[rr][jj], 0.f));
      const int eo = row * 64 + ((cg * 8) ^ ((row & 7) << 3));
      *reinterpret_cast<short8*>(&H1s[eo]) = pk.v;
    }
    __syncthreads();

    // --- L2 MFMA: wave wvid owns cells wvid*32 .. +31
    short8 bfrag[4][2];
    #pragma unroll
    for (int cf = 0; cf < 4; ++cf)
      #pragma unroll
      for (int ks = 0; ks < 2; ++ks)
        bfrag[cf][ks] = *reinterpret_cast<const short8*>(
            &W2Tb[(size_t)t * 4096 + (cf * 16 + fc) * 64 + ks * 32 + fq * 8]);

    f32x4 acc[2][4] = {};
    #pragma unroll
    for (int ks = 0; ks < 2; ++ks) {
      short8 a0, a1;
      {
        const int row = wvid * 32 + fc;
        a0 = *reinterpret_cast<const short8*>(
            &H1s[row * 64 + ((ks * 32 + fq * 8) ^ ((row & 7) << 3))]);
      }
      {
        const int row = wvid * 32 + 16 + fc;
        a1 = *reinterpret_cast<const short8*>(
            &H1s[row * 64 + ((ks * 32 + fq * 8) ^ ((row & 7) << 3))]);
      }
      #pragma unroll
      for (int cf = 0; cf < 4; ++cf) {
        acc[0][cf] = __builtin_amdgcn_mfma_f32_16x16x32_bf16(a0, bfrag[cf][ks], acc[0][cf], 0, 0, 0);
        acc[1][cf] = __builtin_amdgcn_mfma_f32_16x16x32_bf16(a1, bfrag[cf][ks], acc[1][cf], 0, 0, 0);
      }
    }

    // --- L3 epilogue
    float b2v[4], w3v[4];
    #pragma unroll
    for (int cf = 0; cf < 4; ++cf) {
      b2v[cf] = b2[t * 64 + cf * 16 + fc];
      w3v[cf] = W3[t * 64 + cf * 16 + fc];
    }
    float p[2][4];
    #pragma unroll
    for (int rf = 0; rf < 2; ++rf)
      #pragma unroll
      for (int r = 0; r < 4; ++r) {
        float s = 0.f;
        #pragma unroll
        for (int cf = 0; cf < 4; ++cf)
          s = fmaf(fmaxf(acc[rf][cf][r] + b2v[cf], 0.f), w3v[cf], s);
        s += __shfl_xor(s, 1);
        s += __shfl_xor(s, 2);
        s += __shfl_xor(s, 4);
        s += __shfl_xor(s, 8);
        p[rf][r] = s;
      }

    if (fc == 0) {
      const float yb = b3[t];
      #pragma unroll
      for (int rf = 0; rf < 2; ++rf)
        #pragma unroll
        for (int r = 0; r < 4; ++r) {
          const int m = wvid * 32 + rf * 16 + fq * 4 + r;     // cell in block
          const float y = p[rf][r] + yb;
          const size_t oidx = (size_t)(row0 + (m >> 5)) * PREV + t * CG + (m & 31);
          out[oidx]  = y;
          outb[oidx] = __float2bfloat16(y);
        }
    }
    __syncthreads();   // protect H1s before next type overwrites
  }
}

// ---------------------------------------------------------------------------
// Head: logits = Y @ Wfc + bfc ; per-row NLL into rowloss (one wave per row)
// ---------------------------------------------------------------------------
__global__ __launch_bounds__(64)
void head_kernel(const float* __restrict__ Y, const float* __restrict__ Wfc,
                 const float* __restrict__ bfc, const int* __restrict__ labels,
                 float* __restrict__ logits, float* __restrict__ rowloss) {
  const int b = blockIdx.x;
  const int lane = threadIdx.x;
  const float* yr = Y + (size_t)b * PREV;
  float acc[NCLS] = {};
  for (int k = lane; k < PREV; k += 64) {
    const float yv = yr[k];
    #pragma unroll
    for (int cI = 0; cI < NCLS; ++cI) acc[cI] = fmaf(yv, Wfc[k * NCLS + cI], acc[cI]);
  }
  #pragma unroll
  for (int cI = 0; cI < NCLS; ++cI) {
    #pragma unroll
    for (int off = 32; off; off >>= 1) acc[cI] += __shfl_down(acc[cI], off);
  }
  if (lane == 0) {
    float l[NCLS];
    float m = -1e30f;
    #pragma unroll
    for (int cI = 0; cI < NCLS; ++cI) { l[cI] = acc[cI] + bfc[cI]; m = fmaxf(m, l[cI]); }
    float se = 0.f;
    #pragma unroll
    for (int cI = 0; cI < NCLS; ++cI) se += __expf(l[cI] - m);
    const float lse = m + __logf(se);
    #pragma unroll
    for (int cI = 0; cI < NCLS; ++cI) logits[(size_t)b * NCLS + cI] = l[cI];
    const int lab = labels[b];
    float picked = 0.f;
    #pragma unroll
    for (int cI = 0; cI < NCLS; ++cI) picked += (cI == lab) ? l[cI] : 0.f;
    rowloss[b] = lse - picked;
  }
}

// ---------------------------------------------------------------------------
// Deterministic loss reduction (single block)
// ---------------------------------------------------------------------------
__global__ __launch_bounds__(256)
void loss_reduce_kernel(const float* __restrict__ rowloss, float* __restrict__ loss_out) {
  float s = 0.f;
  for (int i = threadIdx.x; i < BATCH; i += 256) s += rowloss[i];
  #pragma unroll
  for (int off = 32; off; off >>= 1) s += __shfl_down(s, off);
  __shared__ float sb[4];
  if ((threadIdx.x & 63) == 0) sb[threadIdx.x >> 6] = s;
  __syncthreads();
  if (threadIdx.x == 0) loss_out[0] = (sb[0] + sb[1] + sb[2] + sb[3]) * (1.f / BATCH);
}

// ---------------------------------------------------------------------------
extern "C" void kernel_launch(void* const* d_in, const int* in_sizes, int n_in,
                              void* d_out, int out_size, void* d_ws, size_t ws_size,
                              hipStream_t stream) {
  const float* x      = (const float*)d_in[0];
  const int*   labels = (const int*)  d_in[1];
  const float* Wout0  = (const float*)d_in[2];
  const float* bout0  = (const float*)d_in[3];
  const float* Wout1  = (const float*)d_in[4];
  const float* bout1  = (const float*)d_in[5];
  const float* Wout2  = (const float*)d_in[6];
  const float* bout2  = (const float*)d_in[7];
  const float* W1     = (const float*)d_in[8];
  const float* b1     = (const float*)d_in[9];
  const float* W2     = (const float*)d_in[10];
  const float* b2     = (const float*)d_in[11];
  const float* W3     = (const float*)d_in[12];
  const float* b3     = (const float*)d_in[13];
  const float* Wfc    = (const float*)d_in[14];
  const float* bfc    = (const float*)d_in[15];

  char* ws = (char*)d_ws;
  float*          Abuf    = (float*)(ws);                               // 64 MB fp32 4096x4096
  float*          Ybuf    = (float*)(ws + ((size_t)64 << 20));          //  8 MB fp32 4096x512
  __hip_bfloat16* Ybf     = (__hip_bfloat16*)(ws + ((size_t)72 << 20)); //  4 MB bf16 4096x512
  __hip_bfloat16* xbf     = (__hip_bfloat16*)(ws + ((size_t)76 << 20)); //  8 MB bf16 4096x1024
  __hip_bfloat16* WT0     = (__hip_bfloat16*)(ws + ((size_t)84 << 20)); //  8 MB bf16 4096x1024
  __hip_bfloat16* WT1     = (__hip_bfloat16*)(ws + ((size_t)92 << 20)); //  4 MB bf16 4096x512
  __hip_bfloat16* WT2     = (__hip_bfloat16*)(ws + ((size_t)96 << 20)); //  4 MB bf16 4096x512
  __hip_bfloat16* W2Tb    = (__hip_bfloat16*)(ws + ((size_t)100 << 20));// 128 KB bf16 16x64x64
  float*          rowloss = (float*)(ws + ((size_t)101 << 20));         // 16 KB

  float* logits = (float*)d_out;
  float* loss   = logits + (size_t)BATCH * NCLS;

  // per-launch weight/input conversions (deterministic, cheap)
  cvt_bf16_kernel<<<dim3(BATCH * 1024 / 4 / 256), dim3(256), 0, stream>>>(x, xbf, BATCH * 1024);
  transpose_cvt_kernel<<<dim3(NHID / 64, 1024 / 64), dim3(256), 0, stream>>>(Wout0, WT0, 1024, NHID);
  transpose_cvt_kernel<<<dim3(NHID / 64, PREV / 64), dim3(256), 0, stream>>>(Wout1, WT1, PREV, NHID);
  transpose_cvt_kernel<<<dim3(NHID / 64, PREV / 64), dim3(256), 0, stream>>>(Wout2, WT2, PREV, NHID);
  transpose_w2_bf16_kernel<<<dim3(NTYPES), dim3(256), 0, stream>>>(W2, W2Tb);

  const dim3 ggrid(NHID / 128, BATCH / 128), gblk(256);
  const dim3 fgrid(BATCH / 4), fblk(256);

  // layer 0
  gemm_mfma_kernel<<<ggrid, gblk, 0, stream>>>(xbf, WT0, bout0, Abuf, NHID, 1024);
  fused_ln_inner_kernel<<<fgrid, fblk, 0, stream>>>(Abuf, Ybuf, Ybf, W2Tb, W1, b1, b2, W3, b3);
  // layer 1
  gemm_mfma_kernel<<<ggrid, gblk, 0, stream>>>(Ybf, WT1, bout1, Abuf, NHID, PREV);
  fused_ln_inner_kernel<<<fgrid, fblk, 0, stream>>>(Abuf, Ybuf, Ybf, W2Tb, W1, b1, b2, W3, b3);
  // layer 2
  gemm_mfma_kernel<<<ggrid, gblk, 0, stream>>>(Ybf, WT2, bout2, Abuf, NHID, PREV);
  fused_ln_inner_kernel<<<fgrid, fblk, 0, stream>>>(Abuf, Ybuf, Ybf, W2Tb, W1, b1, b2, W3, b3);

  // head + loss
  head_kernel<<<dim3(BATCH), dim3(64), 0, stream>>>(Ybuf, Wfc, bfc, labels, logits, rowloss);
  loss_reduce_kernel<<<dim3(1), dim3(256), 0, stream>>>(rowloss, loss);
}

// Round 5
// 513.947 us; speedup vs baseline: 3.5788x; 1.0523x over previous
//
#include <hip/hip_runtime.h>
#include <hip/hip_bf16.h>
#include <math.h>

// Problem constants
constexpr int BATCH   = 4096;
constexpr int NCLS    = 10;
constexpr int NHID    = 4096;   // OUT_HIDDEN
constexpr int PREV    = 512;    // NHID / ARG_IN
constexpr int NTYPES  = 16;
constexpr int CG      = 32;     // cells per type per row: 4096/(16*8)
constexpr float LN_EPS = 1e-5f;

typedef __attribute__((ext_vector_type(8))) short short8;   // 8 bf16 (4 VGPRs)
typedef __attribute__((ext_vector_type(4))) float f32x4;    // MFMA accumulator

// ---------------------------------------------------------------------------
// bf16 MFMA GEMM (m97 structure): C[M,N] = A[M,K] @ BT[N,K]^T + bias
// ---------------------------------------------------------------------------
__global__ __launch_bounds__(256)
void gemm_mfma_kernel(const __hip_bfloat16* __restrict__ A,   // M x K
                      const __hip_bfloat16* __restrict__ BT,  // N x K
                      const float* __restrict__ bias,
                      float* __restrict__ C,                  // M x N
                      int N, int K) {
  __shared__ __hip_bfloat16 As[128 * 32];
  __shared__ __hip_bfloat16 Bs[128 * 32];
  const int tid  = threadIdx.x;
  const int wid  = tid >> 6;
  const int lane = tid & 63;
  const int row0 = blockIdx.y * 128;
  const int col0 = blockIdx.x * 128;
  const int wrow = (wid >> 1) * 64;
  const int wcol = (wid & 1) * 64;

  f32x4 acc[4][4] = {};

  const int sr = wid * 32;
  const int lr = lane >> 2;
  const int lc = (lane & 3) * 8;

  const int fr = lane & 15;
  const int fo = (lane >> 4) * 8;

  for (int k0 = 0; k0 < K; k0 += 32) {
    const __hip_bfloat16* ga0 = A  + (size_t)(row0 + sr +      lr) * K + k0 + lc;
    const __hip_bfloat16* ga1 = A  + (size_t)(row0 + sr + 16 + lr) * K + k0 + lc;
    const __hip_bfloat16* gb0 = BT + (size_t)(col0 + sr +      lr) * K + k0 + lc;
    const __hip_bfloat16* gb1 = BT + (size_t)(col0 + sr + 16 + lr) * K + k0 + lc;
    __builtin_amdgcn_global_load_lds((const __attribute__((address_space(1))) void*)ga0,
                                     (__attribute__((address_space(3))) void*)&As[(sr     ) * 32], 16, 0, 0);
    __builtin_amdgcn_global_load_lds((const __attribute__((address_space(1))) void*)ga1,
                                     (__attribute__((address_space(3))) void*)&As[(sr + 16) * 32], 16, 0, 0);
    __builtin_amdgcn_global_load_lds((const __attribute__((address_space(1))) void*)gb0,
                                     (__attribute__((address_space(3))) void*)&Bs[(sr     ) * 32], 16, 0, 0);
    __builtin_amdgcn_global_load_lds((const __attribute__((address_space(1))) void*)gb1,
                                     (__attribute__((address_space(3))) void*)&Bs[(sr + 16) * 32], 16, 0, 0);
    __syncthreads();

    short8 af[4], bfr[4];
    #pragma unroll
    for (int i = 0; i < 4; ++i)
      af[i] = *reinterpret_cast<const short8*>(&As[(wrow + i * 16 + fr) * 32 + fo]);
    #pragma unroll
    for (int j = 0; j < 4; ++j)
      bfr[j] = *reinterpret_cast<const short8*>(&Bs[(wcol + j * 16 + fr) * 32 + fo]);

    #pragma unroll
    for (int i = 0; i < 4; ++i)
      #pragma unroll
      for (int j = 0; j < 4; ++j)
        acc[i][j] = __builtin_amdgcn_mfma_f32_16x16x32_bf16(af[i], bfr[j], acc[i][j], 0, 0, 0);
    __syncthreads();
  }

  #pragma unroll
  for (int j = 0; j < 4; ++j) {
    const int cc = col0 + wcol + j * 16 + (lane & 15);
    const float bv = bias[cc];
    #pragma unroll
    for (int i = 0; i < 4; ++i) {
      const int rr = row0 + wrow + i * 16 + (lane >> 4) * 4;
      #pragma unroll
      for (int r = 0; r < 4; ++r)
        C[(size_t)(rr + r) * N + cc] = acc[i][j][r] + bv;
    }
  }
}

// ---------------------------------------------------------------------------
// fp32 -> bf16 conversion (vectorized)
// ---------------------------------------------------------------------------
__global__ __launch_bounds__(256)
void cvt_bf16_kernel(const float* __restrict__ in, __hip_bfloat16* __restrict__ out, int n) {
  const int i = (blockIdx.x * 256 + threadIdx.x) * 4;
  if (i >= n) return;
  const float4 v = *reinterpret_cast<const float4*>(&in[i]);
  __hip_bfloat16 t[4];
  t[0] = __float2bfloat16(v.x); t[1] = __float2bfloat16(v.y);
  t[2] = __float2bfloat16(v.z); t[3] = __float2bfloat16(v.w);
  *reinterpret_cast<ushort4*>(&out[i]) = *reinterpret_cast<const ushort4*>(t);
}

// ---------------------------------------------------------------------------
// W (K x N fp32) -> WT (N x K bf16) transpose+convert, 64x64 LDS tiles
// ---------------------------------------------------------------------------
__global__ __launch_bounds__(256)
void transpose_cvt_kernel(const float* __restrict__ W, __hip_bfloat16* __restrict__ WT,
                          int K, int N) {
  __shared__ __hip_bfloat16 tile[64][65];
  const int tid = threadIdx.x;
  const int kt = blockIdx.y * 64, nt = blockIdx.x * 64;
  const int cn = tid & 63;
  for (int r = tid >> 6; r < 64; r += 4)
    tile[cn][r] = __float2bfloat16(W[(size_t)(kt + r) * N + nt + cn]);
  __syncthreads();
  for (int r = tid >> 6; r < 64; r += 4)
    WT[(size_t)(nt + r) * K + kt + cn] = tile[r][cn];
}

// ---------------------------------------------------------------------------
// W2 (T,h,n) fp32 -> W2Tb (T,n,h) bf16
// ---------------------------------------------------------------------------
__global__ __launch_bounds__(256)
void transpose_w2_bf16_kernel(const float* __restrict__ W2, __hip_bfloat16* __restrict__ W2Tb) {
  const int t = blockIdx.x;
  for (int idx = threadIdx.x; idx < 64 * 64; idx += 256) {
    const int n = idx >> 6, h = idx & 63;
    W2Tb[t * 4096 + n * 64 + h] = __float2bfloat16(W2[t * 4096 + h * 64 + n]);
  }
}

// ---------------------------------------------------------------------------
// Fused LayerNorm + inner grouped MLPs, barrier-free.
// Block: 256 thr (4 waves), 4 batch rows. All LDS traffic is WAVE-PRIVATE:
// wave w owns batch row (row0+w) == cells [32w, 32w+32) -> no __syncthreads
// anywhere; intra-wave lgkmcnt ordering suffices.
// Phase 0: per wave, LN stats in-register (shfl), then normalized bf16 row
// written ONCE to LDS (swizzle rb ^= ((rb>>6)&7)<<4 per 16B granule).
// Per type: W2 frags + epilogue consts issued at TOP (latency hidden under
// L1 compute); L1 fp32 VALU from LDS z; H1 bf16 to LDS (swizzled); 16 MFMA;
// L3 epilogue in-register + shfl_xor reduce.
// ---------------------------------------------------------------------------
__global__ __launch_bounds__(256, 3)
void fused_ln_inner_kernel(const float* __restrict__ X,      // (B, 4096) pre-LN
                           float* __restrict__ out,          // (B, 512)
                           __hip_bfloat16* __restrict__ outb,
                           const __hip_bfloat16* __restrict__ W2Tb,
                           const float* __restrict__ W1, const float* __restrict__ b1,
                           const float* __restrict__ b2,
                           const float* __restrict__ W3, const float* __restrict__ b3) {
  __shared__ __hip_bfloat16 H0s[4 * 4096];   // 32 KB normalized input (swizzled)
  __shared__ __hip_bfloat16 H1s[128 * 64];   // 16 KB, elem ^= (row&7)<<3 swizzle
  const int tid  = threadIdx.x;
  const int lane = tid & 63;
  const int wvid = tid >> 6;
  const int row0 = blockIdx.x * 4;

  // --- phase 0: LN stats + normalize, wave-private
  {
    const float* p = X + (size_t)(row0 + wvid) * NHID;
    float s = 0.f, ss = 0.f;
    #pragma unroll
    for (int i = 0; i < 16; ++i) {
      const float4 v = *reinterpret_cast<const float4*>(&p[i * 256 + lane * 4]);
      s  += v.x + v.y + v.z + v.w;
      ss += v.x * v.x + v.y * v.y + v.z * v.z + v.w * v.w;
    }
    #pragma unroll
    for (int off = 32; off; off >>= 1) { s += __shfl_xor(s, off); ss += __shfl_xor(ss, off); }
    const float mu = s * (1.f / 4096.f);
    const float rs = rsqrtf(ss * (1.f / 4096.f) - mu * mu + LN_EPS);
    char* rowb = (char*)&H0s[wvid * 4096];
    #pragma unroll
    for (int i = 0; i < 16; ++i) {
      const float4 v = *reinterpret_cast<const float4*>(&p[i * 256 + lane * 4]);
      __hip_bfloat16 e[4];
      e[0] = __float2bfloat16((v.x - mu) * rs);
      e[1] = __float2bfloat16((v.y - mu) * rs);
      e[2] = __float2bfloat16((v.z - mu) * rs);
      e[3] = __float2bfloat16((v.w - mu) * rs);
      const int rb = i * 512 + lane * 8;                 // byte offset in row
      *reinterpret_cast<uint2*>(rowb + (rb ^ (((rb >> 6) & 7) << 4))) =
          *reinterpret_cast<const uint2*>(e);
    }
  }
  // no barrier: each wave reads only its own row below

  const int fc = lane & 15;      // fragment col / row index
  const int fq = lane >> 4;      // fragment quad
  const int rg = tid >> 3;       // cell group (x4 cells), bl = rg>>3 == wvid
  const int cg = tid & 7;        // neuron group (x8 neurons)

  const char* zrow = (const char*)&H0s[wvid * 4096];

  for (int t = 0; t < NTYPES; ++t) {
    // --- issue W2 fragments + epilogue constants EARLY (hide under L1)
    short8 bfrag[4][2];
    #pragma unroll
    for (int cf = 0; cf < 4; ++cf)
      #pragma unroll
      for (int ks = 0; ks < 2; ++ks)
        bfrag[cf][ks] = *reinterpret_cast<const short8*>(
            &W2Tb[(size_t)t * 4096 + (cf * 16 + fc) * 64 + ks * 32 + fq * 8]);
    float b2v[4], w3v[4];
    #pragma unroll
    for (int cf = 0; cf < 4; ++cf) {
      b2v[cf] = b2[t * 64 + cf * 16 + fc];
      w3v[cf] = W3[t * 64 + cf * 16 + fc];
    }
    const float yb = b3[t];

    // --- L1: z from LDS (4 cells x 8 k per thread)
    float z[4][8];
    #pragma unroll
    for (int rr = 0; rr < 4; ++rr) {
      const int c  = (rg & 7) * 4 + rr;
      const int rb = t * 512 + c * 16;
      union { short8 v; unsigned short u[8]; } zb;
      zb.v = *reinterpret_cast<const short8*>(zrow + (rb ^ (((rb >> 6) & 7) << 4)));
      #pragma unroll
      for (int j = 0; j < 8; ++j)
        z[rr][j] = __uint_as_float(((unsigned)zb.u[j]) << 16);
    }
    float h[4][8];
    {
      const float4 bv0 = *reinterpret_cast<const float4*>(&b1[t * 64 + cg * 8]);
      const float4 bv1 = *reinterpret_cast<const float4*>(&b1[t * 64 + cg * 8 + 4]);
      #pragma unroll
      for (int rr = 0; rr < 4; ++rr) {
        h[rr][0] = bv0.x; h[rr][1] = bv0.y; h[rr][2] = bv0.z; h[rr][3] = bv0.w;
        h[rr][4] = bv1.x; h[rr][5] = bv1.y; h[rr][6] = bv1.z; h[rr][7] = bv1.w;
      }
    }
    {
      const float* w1t = W1 + t * 512 + cg * 8;
      #pragma unroll
      for (int q = 0; q < 8; ++q) {
        const float4 wa = *reinterpret_cast<const float4*>(&w1t[q * 64]);
        const float4 wb = *reinterpret_cast<const float4*>(&w1t[q * 64 + 4]);
        float wv[8] = { wa.x, wa.y, wa.z, wa.w, wb.x, wb.y, wb.z, wb.w };
        #pragma unroll
        for (int rr = 0; rr < 4; ++rr)
          #pragma unroll
          for (int jj = 0; jj < 8; ++jj)
            h[rr][jj] = fmaf(z[rr][q], wv[jj], h[rr][jj]);
      }
    }
    #pragma unroll
    for (int rr = 0; rr < 4; ++rr) {
      const int row = rg * 4 + rr;
      union { short8 v; __hip_bfloat16 e[8]; } pk;
      #pragma unroll
      for (int jj = 0; jj < 8; ++jj)
        pk.e[jj] = __float2bfloat16(fmaxf(h[rr][jj], 0.f));
      const int eo = row * 64 + ((cg * 8) ^ ((row & 7) << 3));
      *reinterpret_cast<short8*>(&H1s[eo]) = pk.v;
    }
    // no barrier: wave w MFMA-reads exactly the H1 rows it just wrote

    // --- L2 MFMA: wave wvid owns cells [32*wvid, 32*wvid+32)
    f32x4 acc[2][4] = {};
    #pragma unroll
    for (int ks = 0; ks < 2; ++ks) {
      short8 a0, a1;
      {
        const int row = wvid * 32 + fc;
        a0 = *reinterpret_cast<const short8*>(
            &H1s[row * 64 + ((ks * 32 + fq * 8) ^ ((row & 7) << 3))]);
      }
      {
        const int row = wvid * 32 + 16 + fc;
        a1 = *reinterpret_cast<const short8*>(
            &H1s[row * 64 + ((ks * 32 + fq * 8) ^ ((row & 7) << 3))]);
      }
      #pragma unroll
      for (int cf = 0; cf < 4; ++cf) {
        acc[0][cf] = __builtin_amdgcn_mfma_f32_16x16x32_bf16(a0, bfrag[cf][ks], acc[0][cf], 0, 0, 0);
        acc[1][cf] = __builtin_amdgcn_mfma_f32_16x16x32_bf16(a1, bfrag[cf][ks], acc[1][cf], 0, 0, 0);
      }
    }

    // --- L3 epilogue
    float p[2][4];
    #pragma unroll
    for (int rf = 0; rf < 2; ++rf)
      #pragma unroll
      for (int r = 0; r < 4; ++r) {
        float s = 0.f;
        #pragma unroll
        for (int cf = 0; cf < 4; ++cf)
          s = fmaf(fmaxf(acc[rf][cf][r] + b2v[cf], 0.f), w3v[cf], s);
        s += __shfl_xor(s, 1);
        s += __shfl_xor(s, 2);
        s += __shfl_xor(s, 4);
        s += __shfl_xor(s, 8);
        p[rf][r] = s;
      }

    if (fc == 0) {
      #pragma unroll
      for (int rf = 0; rf < 2; ++rf)
        #pragma unroll
        for (int r = 0; r < 4; ++r) {
          const int m = wvid * 32 + rf * 16 + fq * 4 + r;     // cell in block
          const float y = p[rf][r] + yb;
          const size_t oidx = (size_t)(row0 + (m >> 5)) * PREV + t * CG + (m & 31);
          out[oidx]  = y;
          outb[oidx] = __float2bfloat16(y);
        }
    }
    // no barrier: next type's H1 writes are by the same wave that read
  }
}

// ---------------------------------------------------------------------------
// Head: logits = Y @ Wfc + bfc ; per-row NLL into rowloss (one wave per row)
// ---------------------------------------------------------------------------
__global__ __launch_bounds__(64)
void head_kernel(const float* __restrict__ Y, const float* __restrict__ Wfc,
                 const float* __restrict__ bfc, const int* __restrict__ labels,
                 float* __restrict__ logits, float* __restrict__ rowloss) {
  const int b = blockIdx.x;
  const int lane = threadIdx.x;
  const float* yr = Y + (size_t)b * PREV;
  float acc[NCLS] = {};
  for (int k = lane; k < PREV; k += 64) {
    const float yv = yr[k];
    #pragma unroll
    for (int cI = 0; cI < NCLS; ++cI) acc[cI] = fmaf(yv, Wfc[k * NCLS + cI], acc[cI]);
  }
  #pragma unroll
  for (int cI = 0; cI < NCLS; ++cI) {
    #pragma unroll
    for (int off = 32; off; off >>= 1) acc[cI] += __shfl_down(acc[cI], off);
  }
  if (lane == 0) {
    float l[NCLS];
    float m = -1e30f;
    #pragma unroll
    for (int cI = 0; cI < NCLS; ++cI) { l[cI] = acc[cI] + bfc[cI]; m = fmaxf(m, l[cI]); }
    float se = 0.f;
    #pragma unroll
    for (int cI = 0; cI < NCLS; ++cI) se += __expf(l[cI] - m);
    const float lse = m + __logf(se);
    #pragma unroll
    for (int cI = 0; cI < NCLS; ++cI) logits[(size_t)b * NCLS + cI] = l[cI];
    const int lab = labels[b];
    float picked = 0.f;
    #pragma unroll
    for (int cI = 0; cI < NCLS; ++cI) picked += (cI == lab) ? l[cI] : 0.f;
    rowloss[b] = lse - picked;
  }
}

// ---------------------------------------------------------------------------
// Deterministic loss reduction (single block)
// ---------------------------------------------------------------------------
__global__ __launch_bounds__(256)
void loss_reduce_kernel(const float* __restrict__ rowloss, float* __restrict__ loss_out) {
  float s = 0.f;
  for (int i = threadIdx.x; i < BATCH; i += 256) s += rowloss[i];
  #pragma unroll
  for (int off = 32; off; off >>= 1) s += __shfl_down(s, off);
  __shared__ float sb[4];
  if ((threadIdx.x & 63) == 0) sb[threadIdx.x >> 6] = s;
  __syncthreads();
  if (threadIdx.x == 0) loss_out[0] = (sb[0] + sb[1] + sb[2] + sb[3]) * (1.f / BATCH);
}

// ---------------------------------------------------------------------------
extern "C" void kernel_launch(void* const* d_in, const int* in_sizes, int n_in,
                              void* d_out, int out_size, void* d_ws, size_t ws_size,
                              hipStream_t stream) {
  const float* x      = (const float*)d_in[0];
  const int*   labels = (const int*)  d_in[1];
  const float* Wout0  = (const float*)d_in[2];
  const float* bout0  = (const float*)d_in[3];
  const float* Wout1  = (const float*)d_in[4];
  const float* bout1  = (const float*)d_in[5];
  const float* Wout2  = (const float*)d_in[6];
  const float* bout2  = (const float*)d_in[7];
  const float* W1     = (const float*)d_in[8];
  const float* b1     = (const float*)d_in[9];
  const float* W2     = (const float*)d_in[10];
  const float* b2     = (const float*)d_in[11];
  const float* W3     = (const float*)d_in[12];
  const float* b3     = (const float*)d_in[13];
  const float* Wfc    = (const float*)d_in[14];
  const float* bfc    = (const float*)d_in[15];

  char* ws = (char*)d_ws;
  float*          Abuf    = (float*)(ws);                               // 64 MB fp32 4096x4096
  float*          Ybuf    = (float*)(ws + ((size_t)64 << 20));          //  8 MB fp32 4096x512
  __hip_bfloat16* Ybf     = (__hip_bfloat16*)(ws + ((size_t)72 << 20)); //  4 MB bf16 4096x512
  __hip_bfloat16* xbf     = (__hip_bfloat16*)(ws + ((size_t)76 << 20)); //  8 MB bf16 4096x1024
  __hip_bfloat16* WT0     = (__hip_bfloat16*)(ws + ((size_t)84 << 20)); //  8 MB bf16 4096x1024
  __hip_bfloat16* WT1     = (__hip_bfloat16*)(ws + ((size_t)92 << 20)); //  4 MB bf16 4096x512
  __hip_bfloat16* WT2     = (__hip_bfloat16*)(ws + ((size_t)96 << 20)); //  4 MB bf16 4096x512
  __hip_bfloat16* W2Tb    = (__hip_bfloat16*)(ws + ((size_t)100 << 20));// 128 KB bf16 16x64x64
  float*          rowloss = (float*)(ws + ((size_t)101 << 20));         // 16 KB

  float* logits = (float*)d_out;
  float* loss   = logits + (size_t)BATCH * NCLS;

  // per-launch weight/input conversions (deterministic, cheap)
  cvt_bf16_kernel<<<dim3(BATCH * 1024 / 4 / 256), dim3(256), 0, stream>>>(x, xbf, BATCH * 1024);
  transpose_cvt_kernel<<<dim3(NHID / 64, 1024 / 64), dim3(256), 0, stream>>>(Wout0, WT0, 1024, NHID);
  transpose_cvt_kernel<<<dim3(NHID / 64, PREV / 64), dim3(256), 0, stream>>>(Wout1, WT1, PREV, NHID);
  transpose_cvt_kernel<<<dim3(NHID / 64, PREV / 64), dim3(256), 0, stream>>>(Wout2, WT2, PREV, NHID);
  transpose_w2_bf16_kernel<<<dim3(NTYPES), dim3(256), 0, stream>>>(W2, W2Tb);

  const dim3 ggrid(NHID / 128, BATCH / 128), gblk(256);
  const dim3 fgrid(BATCH / 4), fblk(256);

  // layer 0
  gemm_mfma_kernel<<<ggrid, gblk, 0, stream>>>(xbf, WT0, bout0, Abuf, NHID, 1024);
  fused_ln_inner_kernel<<<fgrid, fblk, 0, stream>>>(Abuf, Ybuf, Ybf, W2Tb, W1, b1, b2, W3, b3);
  // layer 1
  gemm_mfma_kernel<<<ggrid, gblk, 0, stream>>>(Ybf, WT1, bout1, Abuf, NHID, PREV);
  fused_ln_inner_kernel<<<fgrid, fblk, 0, stream>>>(Abuf, Ybuf, Ybf, W2Tb, W1, b1, b2, W3, b3);
  // layer 2
  gemm_mfma_kernel<<<ggrid, gblk, 0, stream>>>(Ybf, WT2, bout2, Abuf, NHID, PREV);
  fused_ln_inner_kernel<<<fgrid, fblk, 0, stream>>>(Abuf, Ybuf, Ybf, W2Tb, W1, b1, b2, W3, b3);

  // head + loss
  head_kernel<<<dim3(BATCH), dim3(64), 0, stream>>>(Ybuf, Wfc, bfc, labels, logits, rowloss);
  loss_reduce_kernel<<<dim3(1), dim3(256), 0, stream>>>(rowloss, loss);
}

// Round 6
// 473.602 us; speedup vs baseline: 3.8836x; 1.0852x over previous
//
#include <hip/hip_runtime.h>
#include <hip/hip_bf16.h>
#include <math.h>

// Problem constants
constexpr int BATCH   = 4096;
constexpr int NCLS    = 10;
constexpr int NHID    = 4096;   // OUT_HIDDEN
constexpr int PREV    = 512;    // NHID / ARG_IN
constexpr int NTYPES  = 16;
constexpr int CG      = 32;     // cells per type per row: 4096/(16*8)
constexpr float LN_EPS = 1e-5f;

typedef __attribute__((ext_vector_type(8))) short short8;   // 8 bf16 (4 VGPRs)
typedef __attribute__((ext_vector_type(4))) float f32x4;    // MFMA accumulator

// ---------------------------------------------------------------------------
// bf16 MFMA GEMM (m97 structure): C[M,N] = A[M,K] @ BT[N,K]^T + bias
// ---------------------------------------------------------------------------
__global__ __launch_bounds__(256)
void gemm_mfma_kernel(const __hip_bfloat16* __restrict__ A,   // M x K
                      const __hip_bfloat16* __restrict__ BT,  // N x K
                      const float* __restrict__ bias,
                      float* __restrict__ C,                  // M x N
                      int N, int K) {
  __shared__ __hip_bfloat16 As[128 * 32];
  __shared__ __hip_bfloat16 Bs[128 * 32];
  const int tid  = threadIdx.x;
  const int wid  = tid >> 6;
  const int lane = tid & 63;
  const int row0 = blockIdx.y * 128;
  const int col0 = blockIdx.x * 128;
  const int wrow = (wid >> 1) * 64;
  const int wcol = (wid & 1) * 64;

  f32x4 acc[4][4] = {};

  const int sr = wid * 32;
  const int lr = lane >> 2;
  const int lc = (lane & 3) * 8;

  const int fr = lane & 15;
  const int fo = (lane >> 4) * 8;

  for (int k0 = 0; k0 < K; k0 += 32) {
    const __hip_bfloat16* ga0 = A  + (size_t)(row0 + sr +      lr) * K + k0 + lc;
    const __hip_bfloat16* ga1 = A  + (size_t)(row0 + sr + 16 + lr) * K + k0 + lc;
    const __hip_bfloat16* gb0 = BT + (size_t)(col0 + sr +      lr) * K + k0 + lc;
    const __hip_bfloat16* gb1 = BT + (size_t)(col0 + sr + 16 + lr) * K + k0 + lc;
    __builtin_amdgcn_global_load_lds((const __attribute__((address_space(1))) void*)ga0,
                                     (__attribute__((address_space(3))) void*)&As[(sr     ) * 32], 16, 0, 0);
    __builtin_amdgcn_global_load_lds((const __attribute__((address_space(1))) void*)ga1,
                                     (__attribute__((address_space(3))) void*)&As[(sr + 16) * 32], 16, 0, 0);
    __builtin_amdgcn_global_load_lds((const __attribute__((address_space(1))) void*)gb0,
                                     (__attribute__((address_space(3))) void*)&Bs[(sr     ) * 32], 16, 0, 0);
    __builtin_amdgcn_global_load_lds((const __attribute__((address_space(1))) void*)gb1,
                                     (__attribute__((address_space(3))) void*)&Bs[(sr + 16) * 32], 16, 0, 0);
    __syncthreads();

    short8 af[4], bfr[4];
    #pragma unroll
    for (int i = 0; i < 4; ++i)
      af[i] = *reinterpret_cast<const short8*>(&As[(wrow + i * 16 + fr) * 32 + fo]);
    #pragma unroll
    for (int j = 0; j < 4; ++j)
      bfr[j] = *reinterpret_cast<const short8*>(&Bs[(wcol + j * 16 + fr) * 32 + fo]);

    #pragma unroll
    for (int i = 0; i < 4; ++i)
      #pragma unroll
      for (int j = 0; j < 4; ++j)
        acc[i][j] = __builtin_amdgcn_mfma_f32_16x16x32_bf16(af[i], bfr[j], acc[i][j], 0, 0, 0);
    __syncthreads();
  }

  #pragma unroll
  for (int j = 0; j < 4; ++j) {
    const int cc = col0 + wcol + j * 16 + (lane & 15);
    const float bv = bias[cc];
    #pragma unroll
    for (int i = 0; i < 4; ++i) {
      const int rr = row0 + wrow + i * 16 + (lane >> 4) * 4;
      #pragma unroll
      for (int r = 0; r < 4; ++r)
        C[(size_t)(rr + r) * N + cc] = acc[i][j][r] + bv;
    }
  }
}

// ---------------------------------------------------------------------------
// fp32 -> bf16 conversion (vectorized)
// ---------------------------------------------------------------------------
__global__ __launch_bounds__(256)
void cvt_bf16_kernel(const float* __restrict__ in, __hip_bfloat16* __restrict__ out, int n) {
  const int i = (blockIdx.x * 256 + threadIdx.x) * 4;
  if (i >= n) return;
  const float4 v = *reinterpret_cast<const float4*>(&in[i]);
  __hip_bfloat16 t[4];
  t[0] = __float2bfloat16(v.x); t[1] = __float2bfloat16(v.y);
  t[2] = __float2bfloat16(v.z); t[3] = __float2bfloat16(v.w);
  *reinterpret_cast<ushort4*>(&out[i]) = *reinterpret_cast<const ushort4*>(t);
}

// ---------------------------------------------------------------------------
// W (K x N fp32) -> WT (N x K bf16) transpose+convert, 64x64 LDS tiles
// ---------------------------------------------------------------------------
__global__ __launch_bounds__(256)
void transpose_cvt_kernel(const float* __restrict__ W, __hip_bfloat16* __restrict__ WT,
                          int K, int N) {
  __shared__ __hip_bfloat16 tile[64][65];
  const int tid = threadIdx.x;
  const int kt = blockIdx.y * 64, nt = blockIdx.x * 64;
  const int cn = tid & 63;
  for (int r = tid >> 6; r < 64; r += 4)
    tile[cn][r] = __float2bfloat16(W[(size_t)(kt + r) * N + nt + cn]);
  __syncthreads();
  for (int r = tid >> 6; r < 64; r += 4)
    WT[(size_t)(nt + r) * K + kt + cn] = tile[r][cn];
}

// ---------------------------------------------------------------------------
// W2 (T,h,n) fp32 -> W2Tb (T,n,h) bf16
// ---------------------------------------------------------------------------
__global__ __launch_bounds__(256)
void transpose_w2_bf16_kernel(const float* __restrict__ W2, __hip_bfloat16* __restrict__ W2Tb) {
  const int t = blockIdx.x;
  for (int idx = threadIdx.x; idx < 64 * 64; idx += 256) {
    const int n = idx >> 6, h = idx & 63;
    W2Tb[t * 4096 + n * 64 + h] = __float2bfloat16(W2[t * 4096 + h * 64 + n]);
  }
}

// ---------------------------------------------------------------------------
// LN stats: one wave per row, no barriers. stats[row] = (mu, rsqrt(var+eps))
// ---------------------------------------------------------------------------
__global__ __launch_bounds__(256)
void ln_stats_kernel(const float* __restrict__ X, float2* __restrict__ stats) {
  const int lane = threadIdx.x & 63;
  const int row  = blockIdx.x * 4 + (threadIdx.x >> 6);
  const float* p = X + (size_t)row * NHID;
  float s = 0.f, ss = 0.f;
  #pragma unroll
  for (int i = 0; i < 16; ++i) {
    const float4 v = *reinterpret_cast<const float4*>(&p[i * 256 + lane * 4]);
    s  += v.x + v.y + v.z + v.w;
    ss += v.x * v.x + v.y * v.y + v.z * v.z + v.w * v.w;
  }
  #pragma unroll
  for (int off = 32; off; off >>= 1) { s += __shfl_xor(s, off); ss += __shfl_xor(ss, off); }
  if (lane == 0) {
    const float mu = s * (1.f / 4096.f);
    float2 st;
    st.x = mu;
    st.y = rsqrtf(ss * (1.f / 4096.f) - mu * mu + LN_EPS);
    stats[row] = st;
  }
}

// ---------------------------------------------------------------------------
// Inner grouped MLPs, one TYPE per block, weights hoisted out of the loop.
// Block: 256 thr (4 waves), type t = blockIdx.y, rows [r0, r0+64) in 16
// iterations of 4 rows (wave w handles row r0+it*4+w; all LDS wave-private
// after the one startup barrier).
// Startup (once): W2 frags -> VGPR (8 x short8), b1/b2/W3/b3 slices -> regs,
// W1 -> LDS (2 KB).  Loop: z from global (on-the-fly LN via stats[]), L1
// fp32 VALU, H1 bf16 -> LDS (XOR swizzle), 16 MFMA/wave, L3 epilogue.
// ---------------------------------------------------------------------------
__global__ __launch_bounds__(256, 3)
void inner_type_kernel(const float* __restrict__ X,          // (B, 4096) pre-LN
                       const float2* __restrict__ stats,     // (B,) mu, rs
                       float* __restrict__ out,              // (B, 512)
                       __hip_bfloat16* __restrict__ outb,
                       const __hip_bfloat16* __restrict__ W2Tb,
                       const float* __restrict__ W1, const float* __restrict__ b1,
                       const float* __restrict__ b2,
                       const float* __restrict__ W3, const float* __restrict__ b3) {
  __shared__ __hip_bfloat16 H1s[128 * 64];   // 16 KB, elem ^= (row&7)<<3 swizzle
  __shared__ float W1s[512];                 // 2 KB: W1[t] (8 x 64)
  const int tid  = threadIdx.x;
  const int lane = tid & 63;
  const int wvid = tid >> 6;
  const int t    = blockIdx.y;
  const int r0   = blockIdx.x * 64;

  const int fc = lane & 15;      // fragment col / row index
  const int fq = lane >> 4;      // fragment quad
  const int rg = tid >> 3;       // cell group (x4 cells); rg>>3 == wvid
  const int cg = tid & 7;        // neuron group (x8 neurons)

  // ---- startup: all weight state loaded ONCE ----
  W1s[tid]       = W1[t * 512 + tid];
  W1s[256 + tid] = W1[t * 512 + 256 + tid];

  short8 bfrag[4][2];
  #pragma unroll
  for (int cf = 0; cf < 4; ++cf)
    #pragma unroll
    for (int ks = 0; ks < 2; ++ks)
      bfrag[cf][ks] = *reinterpret_cast<const short8*>(
          &W2Tb[(size_t)t * 4096 + (cf * 16 + fc) * 64 + ks * 32 + fq * 8]);

  float b2v[4], w3v[4];
  #pragma unroll
  for (int cf = 0; cf < 4; ++cf) {
    b2v[cf] = b2[t * 64 + cf * 16 + fc];
    w3v[cf] = W3[t * 64 + cf * 16 + fc];
  }
  const float yb = b3[t];

  float b1v[8];
  {
    const float4 bv0 = *reinterpret_cast<const float4*>(&b1[t * 64 + cg * 8]);
    const float4 bv1 = *reinterpret_cast<const float4*>(&b1[t * 64 + cg * 8 + 4]);
    b1v[0] = bv0.x; b1v[1] = bv0.y; b1v[2] = bv0.z; b1v[3] = bv0.w;
    b1v[4] = bv1.x; b1v[5] = bv1.y; b1v[6] = bv1.z; b1v[7] = bv1.w;
  }

  __syncthreads();   // W1s visible to all waves; the ONLY barrier

  for (int it = 0; it < 16; ++it) {
    const int row = r0 + it * 4 + wvid;            // wave-uniform
    const float2 st = stats[row];                  // wave-uniform -> scalar path
    const float mu = st.x, rs = st.y;

    // --- L1: 4 cells x 8 neurons per thread; z from global, LN on the fly
    const float* zbase = X + (size_t)row * NHID + t * 256 + (rg & 7) * 32;
    float z[4][8];
    #pragma unroll
    for (int rr = 0; rr < 4; ++rr) {
      const float4 a = *reinterpret_cast<const float4*>(&zbase[rr * 8]);
      const float4 b = *reinterpret_cast<const float4*>(&zbase[rr * 8 + 4]);
      z[rr][0] = (a.x - mu) * rs; z[rr][1] = (a.y - mu) * rs;
      z[rr][2] = (a.z - mu) * rs; z[rr][3] = (a.w - mu) * rs;
      z[rr][4] = (b.x - mu) * rs; z[rr][5] = (b.y - mu) * rs;
      z[rr][6] = (b.z - mu) * rs; z[rr][7] = (b.w - mu) * rs;
    }

    float h[4][8];
    #pragma unroll
    for (int rr = 0; rr < 4; ++rr)
      #pragma unroll
      for (int jj = 0; jj < 8; ++jj)
        h[rr][jj] = b1v[jj];
    #pragma unroll
    for (int q = 0; q < 8; ++q) {
      const float4 wa = *reinterpret_cast<const float4*>(&W1s[q * 64 + cg * 8]);
      const float4 wb = *reinterpret_cast<const float4*>(&W1s[q * 64 + cg * 8 + 4]);
      float wv[8] = { wa.x, wa.y, wa.z, wa.w, wb.x, wb.y, wb.z, wb.w };
      #pragma unroll
      for (int rr = 0; rr < 4; ++rr)
        #pragma unroll
        for (int jj = 0; jj < 8; ++jj)
          h[rr][jj] = fmaf(z[rr][q], wv[jj], h[rr][jj]);
    }
    #pragma unroll
    for (int rr = 0; rr < 4; ++rr) {
      const int hrow = rg * 4 + rr;
      union { short8 v; __hip_bfloat16 e[8]; } pk;
      #pragma unroll
      for (int jj = 0; jj < 8; ++jj)
        pk.e[jj] = __float2bfloat16(fmaxf(h[rr][jj], 0.f));
      const int eo = hrow * 64 + ((cg * 8) ^ ((hrow & 7) << 3));
      *reinterpret_cast<short8*>(&H1s[eo]) = pk.v;
    }
    // no barrier: wave w MFMA-reads exactly the H1 rows it just wrote

    // --- L2 MFMA: wave wvid owns H1 rows [32*wvid, 32*wvid+32)
    f32x4 acc[2][4] = {};
    #pragma unroll
    for (int ks = 0; ks < 2; ++ks) {
      short8 a0, a1;
      {
        const int hrow = wvid * 32 + fc;
        a0 = *reinterpret_cast<const short8*>(
            &H1s[hrow * 64 + ((ks * 32 + fq * 8) ^ ((hrow & 7) << 3))]);
      }
      {
        const int hrow = wvid * 32 + 16 + fc;
        a1 = *reinterpret_cast<const short8*>(
            &H1s[hrow * 64 + ((ks * 32 + fq * 8) ^ ((hrow & 7) << 3))]);
      }
      #pragma unroll
      for (int cf = 0; cf < 4; ++cf) {
        acc[0][cf] = __builtin_amdgcn_mfma_f32_16x16x32_bf16(a0, bfrag[cf][ks], acc[0][cf], 0, 0, 0);
        acc[1][cf] = __builtin_amdgcn_mfma_f32_16x16x32_bf16(a1, bfrag[cf][ks], acc[1][cf], 0, 0, 0);
      }
    }

    // --- L3 epilogue
    float p[2][4];
    #pragma unroll
    for (int rf = 0; rf < 2; ++rf)
      #pragma unroll
      for (int r = 0; r < 4; ++r) {
        float s = 0.f;
        #pragma unroll
        for (int cf = 0; cf < 4; ++cf)
          s = fmaf(fmaxf(acc[rf][cf][r] + b2v[cf], 0.f), w3v[cf], s);
        s += __shfl_xor(s, 1);
        s += __shfl_xor(s, 2);
        s += __shfl_xor(s, 4);
        s += __shfl_xor(s, 8);
        p[rf][r] = s;
      }

    if (fc == 0) {
      #pragma unroll
      for (int rf = 0; rf < 2; ++rf)
        #pragma unroll
        for (int r = 0; r < 4; ++r) {
          const int c = rf * 16 + fq * 4 + r;          // cell within the row
          const float y = p[rf][r] + yb;
          const size_t oidx = (size_t)row * PREV + t * CG + c;
          out[oidx]  = y;
          outb[oidx] = __float2bfloat16(y);
        }
    }
    // no barrier: next iteration's H1 writes are by the same wave that read
  }
}

// ---------------------------------------------------------------------------
// Head: logits = Y @ Wfc + bfc ; per-row NLL into rowloss (one wave per row)
// ---------------------------------------------------------------------------
__global__ __launch_bounds__(64)
void head_kernel(const float* __restrict__ Y, const float* __restrict__ Wfc,
                 const float* __restrict__ bfc, const int* __restrict__ labels,
                 float* __restrict__ logits, float* __restrict__ rowloss) {
  const int b = blockIdx.x;
  const int lane = threadIdx.x;
  const float* yr = Y + (size_t)b * PREV;
  float acc[NCLS] = {};
  for (int k = lane; k < PREV; k += 64) {
    const float yv = yr[k];
    #pragma unroll
    for (int cI = 0; cI < NCLS; ++cI) acc[cI] = fmaf(yv, Wfc[k * NCLS + cI], acc[cI]);
  }
  #pragma unroll
  for (int cI = 0; cI < NCLS; ++cI) {
    #pragma unroll
    for (int off = 32; off; off >>= 1) acc[cI] += __shfl_down(acc[cI], off);
  }
  if (lane == 0) {
    float l[NCLS];
    float m = -1e30f;
    #pragma unroll
    for (int cI = 0; cI < NCLS; ++cI) { l[cI] = acc[cI] + bfc[cI]; m = fmaxf(m, l[cI]); }
    float se = 0.f;
    #pragma unroll
    for (int cI = 0; cI < NCLS; ++cI) se += __expf(l[cI] - m);
    const float lse = m + __logf(se);
    #pragma unroll
    for (int cI = 0; cI < NCLS; ++cI) logits[(size_t)b * NCLS + cI] = l[cI];
    const int lab = labels[b];
    float picked = 0.f;
    #pragma unroll
    for (int cI = 0; cI < NCLS; ++cI) picked += (cI == lab) ? l[cI] : 0.f;
    rowloss[b] = lse - picked;
  }
}

// ---------------------------------------------------------------------------
// Deterministic loss reduction (single block)
// ---------------------------------------------------------------------------
__global__ __launch_bounds__(256)
void loss_reduce_kernel(const float* __restrict__ rowloss, float* __restrict__ loss_out) {
  float s = 0.f;
  for (int i = threadIdx.x; i < BATCH; i += 256) s += rowloss[i];
  #pragma unroll
  for (int off = 32; off; off >>= 1) s += __shfl_down(s, off);
  __shared__ float sb[4];
  if ((threadIdx.x & 63) == 0) sb[threadIdx.x >> 6] = s;
  __syncthreads();
  if (threadIdx.x == 0) loss_out[0] = (sb[0] + sb[1] + sb[2] + sb[3]) * (1.f / BATCH);
}

// ---------------------------------------------------------------------------
extern "C" void kernel_launch(void* const* d_in, const int* in_sizes, int n_in,
                              void* d_out, int out_size, void* d_ws, size_t ws_size,
                              hipStream_t stream) {
  const float* x      = (const float*)d_in[0];
  const int*   labels = (const int*)  d_in[1];
  const float* Wout0  = (const float*)d_in[2];
  const float* bout0  = (const float*)d_in[3];
  const float* Wout1  = (const float*)d_in[4];
  const float* bout1  = (const float*)d_in[5];
  const float* Wout2  = (const float*)d_in[6];
  const float* bout2  = (const float*)d_in[7];
  const float* W1     = (const float*)d_in[8];
  const float* b1     = (const float*)d_in[9];
  const float* W2     = (const float*)d_in[10];
  const float* b2     = (const float*)d_in[11];
  const float* W3     = (const float*)d_in[12];
  const float* b3     = (const float*)d_in[13];
  const float* Wfc    = (const float*)d_in[14];
  const float* bfc    = (const float*)d_in[15];

  char* ws = (char*)d_ws;
  float*          Abuf    = (float*)(ws);                               // 64 MB fp32 4096x4096
  float*          Ybuf    = (float*)(ws + ((size_t)64 << 20));          //  8 MB fp32 4096x512
  __hip_bfloat16* Ybf     = (__hip_bfloat16*)(ws + ((size_t)72 << 20)); //  4 MB bf16 4096x512
  __hip_bfloat16* xbf     = (__hip_bfloat16*)(ws + ((size_t)76 << 20)); //  8 MB bf16 4096x1024
  __hip_bfloat16* WT0     = (__hip_bfloat16*)(ws + ((size_t)84 << 20)); //  8 MB bf16 4096x1024
  __hip_bfloat16* WT1     = (__hip_bfloat16*)(ws + ((size_t)92 << 20)); //  4 MB bf16 4096x512
  __hip_bfloat16* WT2     = (__hip_bfloat16*)(ws + ((size_t)96 << 20)); //  4 MB bf16 4096x512
  __hip_bfloat16* W2Tb    = (__hip_bfloat16*)(ws + ((size_t)100 << 20));// 128 KB bf16 16x64x64
  float*          rowloss = (float*)(ws + ((size_t)101 << 20));         // 16 KB
  float2*         stats   = (float2*)(ws + ((size_t)101 << 20) + (256 << 10)); // 32 KB

  float* logits = (float*)d_out;
  float* loss   = logits + (size_t)BATCH * NCLS;

  // per-launch weight/input conversions (deterministic, cheap)
  cvt_bf16_kernel<<<dim3(BATCH * 1024 / 4 / 256), dim3(256), 0, stream>>>(x, xbf, BATCH * 1024);
  transpose_cvt_kernel<<<dim3(NHID / 64, 1024 / 64), dim3(256), 0, stream>>>(Wout0, WT0, 1024, NHID);
  transpose_cvt_kernel<<<dim3(NHID / 64, PREV / 64), dim3(256), 0, stream>>>(Wout1, WT1, PREV, NHID);
  transpose_cvt_kernel<<<dim3(NHID / 64, PREV / 64), dim3(256), 0, stream>>>(Wout2, WT2, PREV, NHID);
  transpose_w2_bf16_kernel<<<dim3(NTYPES), dim3(256), 0, stream>>>(W2, W2Tb);

  const dim3 ggrid(NHID / 128, BATCH / 128), gblk(256);
  const dim3 sgrid(BATCH / 4), sblk(256);
  const dim3 igrid(BATCH / 64, NTYPES), iblk(256);

  // layer 0
  gemm_mfma_kernel<<<ggrid, gblk, 0, stream>>>(xbf, WT0, bout0, Abuf, NHID, 1024);
  ln_stats_kernel<<<sgrid, sblk, 0, stream>>>(Abuf, stats);
  inner_type_kernel<<<igrid, iblk, 0, stream>>>(Abuf, stats, Ybuf, Ybf, W2Tb, W1, b1, b2, W3, b3);
  // layer 1
  gemm_mfma_kernel<<<ggrid, gblk, 0, stream>>>(Ybf, WT1, bout1, Abuf, NHID, PREV);
  ln_stats_kernel<<<sgrid, sblk, 0, stream>>>(Abuf, stats);
  inner_type_kernel<<<igrid, iblk, 0, stream>>>(Abuf, stats, Ybuf, Ybf, W2Tb, W1, b1, b2, W3, b3);
  // layer 2
  gemm_mfma_kernel<<<ggrid, gblk, 0, stream>>>(Ybf, WT2, bout2, Abuf, NHID, PREV);
  ln_stats_kernel<<<sgrid, sblk, 0, stream>>>(Abuf, stats);
  inner_type_kernel<<<igrid, iblk, 0, stream>>>(Abuf, stats, Ybuf, Ybf, W2Tb, W1, b1, b2, W3, b3);

  // head + loss
  head_kernel<<<dim3(BATCH), dim3(64), 0, stream>>>(Ybuf, Wfc, bfc, labels, logits, rowloss);
  loss_reduce_kernel<<<dim3(1), dim3(256), 0, stream>>>(rowloss, loss);
}

// Round 7
// 414.488 us; speedup vs baseline: 4.4375x; 1.1426x over previous
//
#include <hip/hip_runtime.h>
#include <hip/hip_bf16.h>
#include <math.h>

// Problem constants
constexpr int BATCH   = 4096;
constexpr int NCLS    = 10;
constexpr int NHID    = 4096;   // OUT_HIDDEN
constexpr int PREV    = 512;    // NHID / ARG_IN
constexpr int NTYPES  = 16;
constexpr int CG      = 32;     // cells per type per row: 4096/(16*8)
constexpr float LN_EPS = 1e-5f;

typedef __attribute__((ext_vector_type(8))) short short8;   // 8 bf16 (4 VGPRs)
typedef __attribute__((ext_vector_type(4))) float f32x4;    // MFMA accumulator

// ---------------------------------------------------------------------------
// bf16 MFMA GEMM (m97 structure): C[M,N] = A[M,K] @ BT[N,K]^T + bias
// ---------------------------------------------------------------------------
__global__ __launch_bounds__(256)
void gemm_mfma_kernel(const __hip_bfloat16* __restrict__ A,   // M x K
                      const __hip_bfloat16* __restrict__ BT,  // N x K
                      const float* __restrict__ bias,
                      float* __restrict__ C,                  // M x N
                      int N, int K) {
  __shared__ __hip_bfloat16 As[128 * 32];
  __shared__ __hip_bfloat16 Bs[128 * 32];
  const int tid  = threadIdx.x;
  const int wid  = tid >> 6;
  const int lane = tid & 63;
  const int row0 = blockIdx.y * 128;
  const int col0 = blockIdx.x * 128;
  const int wrow = (wid >> 1) * 64;
  const int wcol = (wid & 1) * 64;

  f32x4 acc[4][4] = {};

  const int sr = wid * 32;
  const int lr = lane >> 2;
  const int lc = (lane & 3) * 8;

  const int fr = lane & 15;
  const int fo = (lane >> 4) * 8;

  for (int k0 = 0; k0 < K; k0 += 32) {
    const __hip_bfloat16* ga0 = A  + (size_t)(row0 + sr +      lr) * K + k0 + lc;
    const __hip_bfloat16* ga1 = A  + (size_t)(row0 + sr + 16 + lr) * K + k0 + lc;
    const __hip_bfloat16* gb0 = BT + (size_t)(col0 + sr +      lr) * K + k0 + lc;
    const __hip_bfloat16* gb1 = BT + (size_t)(col0 + sr + 16 + lr) * K + k0 + lc;
    __builtin_amdgcn_global_load_lds((const __attribute__((address_space(1))) void*)ga0,
                                     (__attribute__((address_space(3))) void*)&As[(sr     ) * 32], 16, 0, 0);
    __builtin_amdgcn_global_load_lds((const __attribute__((address_space(1))) void*)ga1,
                                     (__attribute__((address_space(3))) void*)&As[(sr + 16) * 32], 16, 0, 0);
    __builtin_amdgcn_global_load_lds((const __attribute__((address_space(1))) void*)gb0,
                                     (__attribute__((address_space(3))) void*)&Bs[(sr     ) * 32], 16, 0, 0);
    __builtin_amdgcn_global_load_lds((const __attribute__((address_space(1))) void*)gb1,
                                     (__attribute__((address_space(3))) void*)&Bs[(sr + 16) * 32], 16, 0, 0);
    __syncthreads();

    short8 af[4], bfr[4];
    #pragma unroll
    for (int i = 0; i < 4; ++i)
      af[i] = *reinterpret_cast<const short8*>(&As[(wrow + i * 16 + fr) * 32 + fo]);
    #pragma unroll
    for (int j = 0; j < 4; ++j)
      bfr[j] = *reinterpret_cast<const short8*>(&Bs[(wcol + j * 16 + fr) * 32 + fo]);

    #pragma unroll
    for (int i = 0; i < 4; ++i)
      #pragma unroll
      for (int j = 0; j < 4; ++j)
        acc[i][j] = __builtin_amdgcn_mfma_f32_16x16x32_bf16(af[i], bfr[j], acc[i][j], 0, 0, 0);
    __syncthreads();
  }

  #pragma unroll
  for (int j = 0; j < 4; ++j) {
    const int cc = col0 + wcol + j * 16 + (lane & 15);
    const float bv = bias[cc];
    #pragma unroll
    for (int i = 0; i < 4; ++i) {
      const int rr = row0 + wrow + i * 16 + (lane >> 4) * 4;
      #pragma unroll
      for (int r = 0; r < 4; ++r)
        C[(size_t)(rr + r) * N + cc] = acc[i][j][r] + bv;
    }
  }
}

// ---------------------------------------------------------------------------
// fp32 -> bf16 conversion (vectorized)
// ---------------------------------------------------------------------------
__global__ __launch_bounds__(256)
void cvt_bf16_kernel(const float* __restrict__ in, __hip_bfloat16* __restrict__ out, int n) {
  const int i = (blockIdx.x * 256 + threadIdx.x) * 4;
  if (i >= n) return;
  const float4 v = *reinterpret_cast<const float4*>(&in[i]);
  __hip_bfloat16 t[4];
  t[0] = __float2bfloat16(v.x); t[1] = __float2bfloat16(v.y);
  t[2] = __float2bfloat16(v.z); t[3] = __float2bfloat16(v.w);
  *reinterpret_cast<ushort4*>(&out[i]) = *reinterpret_cast<const ushort4*>(t);
}

// ---------------------------------------------------------------------------
// W (K x N fp32) -> WT (N x K bf16) transpose+convert, 64x64 LDS tiles
// ---------------------------------------------------------------------------
__global__ __launch_bounds__(256)
void transpose_cvt_kernel(const float* __restrict__ W, __hip_bfloat16* __restrict__ WT,
                          int K, int N) {
  __shared__ __hip_bfloat16 tile[64][65];
  const int tid = threadIdx.x;
  const int kt = blockIdx.y * 64, nt = blockIdx.x * 64;
  const int cn = tid & 63;
  for (int r = tid >> 6; r < 64; r += 4)
    tile[cn][r] = __float2bfloat16(W[(size_t)(kt + r) * N + nt + cn]);
  __syncthreads();
  for (int r = tid >> 6; r < 64; r += 4)
    WT[(size_t)(nt + r) * K + kt + cn] = tile[r][cn];
}

// ---------------------------------------------------------------------------
// W2 (T,h,n) fp32 -> W2Tb (T,n,h) bf16
// ---------------------------------------------------------------------------
__global__ __launch_bounds__(256)
void transpose_w2_bf16_kernel(const float* __restrict__ W2, __hip_bfloat16* __restrict__ W2Tb) {
  const int t = blockIdx.x;
  for (int idx = threadIdx.x; idx < 64 * 64; idx += 256) {
    const int n = idx >> 6, h = idx & 63;
    W2Tb[t * 4096 + n * 64 + h] = __float2bfloat16(W2[t * 4096 + h * 64 + n]);
  }
}

// ---------------------------------------------------------------------------
// LN stats: one wave per row. stats[row] = (mu, rsqrt(var+eps))
// ---------------------------------------------------------------------------
__global__ __launch_bounds__(256)
void ln_stats_kernel(const float* __restrict__ X, float2* __restrict__ stats) {
  const int lane = threadIdx.x & 63;
  const int row  = blockIdx.x * 4 + (threadIdx.x >> 6);
  const float* p = X + (size_t)row * NHID;
  float s = 0.f, ss = 0.f;
  #pragma unroll
  for (int i = 0; i < 16; ++i) {
    const float4 v = *reinterpret_cast<const float4*>(&p[i * 256 + lane * 4]);
    s  += v.x + v.y + v.z + v.w;
    ss += v.x * v.x + v.y * v.y + v.z * v.z + v.w * v.w;
  }
  #pragma unroll
  for (int off = 32; off; off >>= 1) { s += __shfl_xor(s, off); ss += __shfl_xor(ss, off); }
  if (lane == 0) {
    const float mu = s * (1.f / 4096.f);
    float2 st;
    st.x = mu;
    st.y = rsqrtf(ss * (1.f / 4096.f) - mu * mu + LN_EPS);
    stats[row] = st;
  }
}

// ---------------------------------------------------------------------------
// Inner grouped MLPs, one TYPE per block, weights hoisted, z PING-PONG
// PREFETCHED one iteration ahead (T14: global->reg issue early, consume one
// body later; all reg arrays constant-indexed).
// LN folded into L1 algebra: h = rs*dot(x_raw, w) + (b1 - mu*rs*sum_q w).
// ---------------------------------------------------------------------------
__global__ __launch_bounds__(256, 2)
void inner_type_kernel(const float* __restrict__ X,          // (B, 4096) pre-LN
                       const float2* __restrict__ stats,     // (B,) mu, rs
                       float* __restrict__ out,              // (B, 512) or null
                       __hip_bfloat16* __restrict__ outb,
                       const __hip_bfloat16* __restrict__ W2Tb,
                       const float* __restrict__ W1, const float* __restrict__ b1,
                       const float* __restrict__ b2,
                       const float* __restrict__ W3, const float* __restrict__ b3) {
  __shared__ __hip_bfloat16 H1s[128 * 64];   // 16 KB, elem ^= (row&7)<<3 swizzle
  __shared__ float W1s[512];                 // 2 KB: W1[t] (8 x 64)
  const int tid  = threadIdx.x;
  const int lane = tid & 63;
  const int wvid = tid >> 6;
  const int t    = blockIdx.y;
  const int r0   = blockIdx.x * 64;

  const int fc = lane & 15;      // fragment col / row index
  const int fq = lane >> 4;      // fragment quad
  const int rg = tid >> 3;       // cell group (x4 cells); rg>>3 == wvid
  const int cg = tid & 7;        // neuron group (x8 neurons)

  const float* zcol = X + t * 256 + (rg & 7) * 32;   // + row*NHID per iter

#define LOAD_Z(zr, itv)                                                        \
  {                                                                            \
    const float* zb_ = zcol + (size_t)(r0 + (itv) * 4 + wvid) * NHID;          \
    _Pragma("unroll")                                                          \
    for (int c_ = 0; c_ < 4; ++c_) {                                           \
      *reinterpret_cast<float4*>(&zr[c_ * 8])     =                            \
          *reinterpret_cast<const float4*>(&zb_[c_ * 8]);                      \
      *reinterpret_cast<float4*>(&zr[c_ * 8 + 4]) =                            \
          *reinterpret_cast<const float4*>(&zb_[c_ * 8 + 4]);                  \
    }                                                                          \
  }

  // ---- issue first z + stats prefetch BEFORE weight loads ----
  float zA[32], zB[32];
  float2 stA, stB;
  LOAD_Z(zA, 0);
  stA = stats[r0 + wvid];

  // ---- startup: all weight state loaded ONCE ----
  W1s[tid]       = W1[t * 512 + tid];
  W1s[256 + tid] = W1[t * 512 + 256 + tid];

  short8 bfrag[4][2];
  #pragma unroll
  for (int cf = 0; cf < 4; ++cf)
    #pragma unroll
    for (int ks = 0; ks < 2; ++ks)
      bfrag[cf][ks] = *reinterpret_cast<const short8*>(
          &W2Tb[(size_t)t * 4096 + (cf * 16 + fc) * 64 + ks * 32 + fq * 8]);

  float b2v[4], w3v[4];
  #pragma unroll
  for (int cf = 0; cf < 4; ++cf) {
    b2v[cf] = b2[t * 64 + cf * 16 + fc];
    w3v[cf] = W3[t * 64 + cf * 16 + fc];
  }
  const float yb = b3[t];

  float b1v[8];
  {
    const float4 bv0 = *reinterpret_cast<const float4*>(&b1[t * 64 + cg * 8]);
    const float4 bv1 = *reinterpret_cast<const float4*>(&b1[t * 64 + cg * 8 + 4]);
    b1v[0] = bv0.x; b1v[1] = bv0.y; b1v[2] = bv0.z; b1v[3] = bv0.w;
    b1v[4] = bv1.x; b1v[5] = bv1.y; b1v[6] = bv1.z; b1v[7] = bv1.w;
  }

  __syncthreads();   // W1s visible; the ONLY barrier

  // column sums of W1 for the LN fold: sw[j] = sum_q W1[q][j]
  float swv[8];
  #pragma unroll
  for (int jj = 0; jj < 8; ++jj) {
    float s = 0.f;
    #pragma unroll
    for (int q = 0; q < 8; ++q) s += W1s[q * 64 + cg * 8 + jj];
    swv[jj] = s;
  }

#define BODY(zr, stv, itv)                                                     \
  {                                                                            \
    const int row_ = r0 + (itv) * 4 + wvid;                                    \
    const float rs_ = stv.y;                                                   \
    const float c1_ = -stv.x * rs_;                                            \
    float bias2[8];                                                            \
    _Pragma("unroll")                                                          \
    for (int jj = 0; jj < 8; ++jj) bias2[jj] = fmaf(c1_, swv[jj], b1v[jj]);    \
    float dot[4][8];                                                           \
    _Pragma("unroll")                                                          \
    for (int rr = 0; rr < 4; ++rr)                                             \
      _Pragma("unroll")                                                        \
      for (int jj = 0; jj < 8; ++jj) dot[rr][jj] = 0.f;                        \
    _Pragma("unroll")                                                          \
    for (int q = 0; q < 8; ++q) {                                              \
      const float4 wa_ = *reinterpret_cast<const float4*>(&W1s[q * 64 + cg * 8]);     \
      const float4 wb_ = *reinterpret_cast<const float4*>(&W1s[q * 64 + cg * 8 + 4]); \
      _Pragma("unroll")                                                        \
      for (int rr = 0; rr < 4; ++rr) {                                         \
        const float zq_ = zr[rr * 8 + q];                                      \
        dot[rr][0] = fmaf(zq_, wa_.x, dot[rr][0]);                             \
        dot[rr][1] = fmaf(zq_, wa_.y, dot[rr][1]);                             \
        dot[rr][2] = fmaf(zq_, wa_.z, dot[rr][2]);                             \
        dot[rr][3] = fmaf(zq_, wa_.w, dot[rr][3]);                             \
        dot[rr][4] = fmaf(zq_, wb_.x, dot[rr][4]);                             \
        dot[rr][5] = fmaf(zq_, wb_.y, dot[rr][5]);                             \
        dot[rr][6] = fmaf(zq_, wb_.z, dot[rr][6]);                             \
        dot[rr][7] = fmaf(zq_, wb_.w, dot[rr][7]);                             \
      }                                                                        \
    }                                                                          \
    _Pragma("unroll")                                                          \
    for (int rr = 0; rr < 4; ++rr) {                                           \
      const int hrow_ = rg * 4 + rr;                                           \
      union { short8 v; __hip_bfloat16 e[8]; } pk_;                            \
      _Pragma("unroll")                                                        \
      for (int jj = 0; jj < 8; ++jj)                                           \
        pk_.e[jj] = __float2bfloat16(                                          \
            fmaxf(fmaf(rs_, dot[rr][jj], bias2[jj]), 0.f));                    \
      const int eo_ = hrow_ * 64 + ((cg * 8) ^ ((hrow_ & 7) << 3));            \
      *reinterpret_cast<short8*>(&H1s[eo_]) = pk_.v;                           \
    }                                                                          \
    f32x4 acc[2][4] = {};                                                      \
    _Pragma("unroll")                                                          \
    for (int ks = 0; ks < 2; ++ks) {                                           \
      short8 a0_, a1_;                                                         \
      {                                                                        \
        const int hrow_ = wvid * 32 + fc;                                      \
        a0_ = *reinterpret_cast<const short8*>(                                \
            &H1s[hrow_ * 64 + ((ks * 32 + fq * 8) ^ ((hrow_ & 7) << 3))]);     \
      }                                                                        \
      {                                                                        \
        const int hrow_ = wvid * 32 + 16 + fc;                                 \
        a1_ = *reinterpret_cast<const short8*>(                                \
            &H1s[hrow_ * 64 + ((ks * 32 + fq * 8) ^ ((hrow_ & 7) << 3))]);     \
      }                                                                        \
      _Pragma("unroll")                                                        \
      for (int cf = 0; cf < 4; ++cf) {                                         \
        acc[0][cf] = __builtin_amdgcn_mfma_f32_16x16x32_bf16(a0_, bfrag[cf][ks], acc[0][cf], 0, 0, 0); \
        acc[1][cf] = __builtin_amdgcn_mfma_f32_16x16x32_bf16(a1_, bfrag[cf][ks], acc[1][cf], 0, 0, 0); \
      }                                                                        \
    }                                                                          \
    float p[2][4];                                                             \
    _Pragma("unroll")                                                          \
    for (int rf = 0; rf < 2; ++rf)                                             \
      _Pragma("unroll")                                                        \
      for (int r = 0; r < 4; ++r) {                                            \
        float s_ = 0.f;                                                        \
        _Pragma("unroll")                                                      \
        for (int cf = 0; cf < 4; ++cf)                                         \
          s_ = fmaf(fmaxf(acc[rf][cf][r] + b2v[cf], 0.f), w3v[cf], s_);        \
        s_ += __shfl_xor(s_, 1);                                               \
        s_ += __shfl_xor(s_, 2);                                               \
        s_ += __shfl_xor(s_, 4);                                               \
        s_ += __shfl_xor(s_, 8);                                               \
        p[rf][r] = s_;                                                         \
      }                                                                        \
    if (fc == 0) {                                                             \
      _Pragma("unroll")                                                        \
      for (int rf = 0; rf < 2; ++rf)                                           \
        _Pragma("unroll")                                                      \
        for (int r = 0; r < 4; ++r) {                                          \
          const int c_ = rf * 16 + fq * 4 + r;                                 \
          const float y_ = p[rf][r] + yb;                                      \
          const size_t oidx_ = (size_t)row_ * PREV + t * CG + c_;              \
          if (out) out[oidx_] = y_;                                            \
          outb[oidx_] = __float2bfloat16(y_);                                  \
        }                                                                      \
    }                                                                          \
  }

  #pragma unroll 1
  for (int it2 = 0; it2 < 8; ++it2) {
    const int itA = it2 * 2;
    // prefetch odd iteration while computing even
    LOAD_Z(zB, itA + 1);
    stB = stats[r0 + (itA + 1) * 4 + wvid];
    BODY(zA, stA, itA);
    // prefetch next even iteration while computing odd
    if (it2 < 7) {
      LOAD_Z(zA, itA + 2);
      stA = stats[r0 + (itA + 2) * 4 + wvid];
    }
    BODY(zB, stB, itA + 1);
  }
#undef LOAD_Z
#undef BODY
}

// ---------------------------------------------------------------------------
// Head: logits = Y @ Wfc + bfc ; per-row NLL into rowloss (one wave per row)
// ---------------------------------------------------------------------------
__global__ __launch_bounds__(64)
void head_kernel(const float* __restrict__ Y, const float* __restrict__ Wfc,
                 const float* __restrict__ bfc, const int* __restrict__ labels,
                 float* __restrict__ logits, float* __restrict__ rowloss) {
  const int b = blockIdx.x;
  const int lane = threadIdx.x;
  const float* yr = Y + (size_t)b * PREV;
  float acc[NCLS] = {};
  for (int k = lane; k < PREV; k += 64) {
    const float yv = yr[k];
    #pragma unroll
    for (int cI = 0; cI < NCLS; ++cI) acc[cI] = fmaf(yv, Wfc[k * NCLS + cI], acc[cI]);
  }
  #pragma unroll
  for (int cI = 0; cI < NCLS; ++cI) {
    #pragma unroll
    for (int off = 32; off; off >>= 1) acc[cI] += __shfl_down(acc[cI], off);
  }
  if (lane == 0) {
    float l[NCLS];
    float m = -1e30f;
    #pragma unroll
    for (int cI = 0; cI < NCLS; ++cI) { l[cI] = acc[cI] + bfc[cI]; m = fmaxf(m, l[cI]); }
    float se = 0.f;
    #pragma unroll
    for (int cI = 0; cI < NCLS; ++cI) se += __expf(l[cI] - m);
    const float lse = m + __logf(se);
    #pragma unroll
    for (int cI = 0; cI < NCLS; ++cI) logits[(size_t)b * NCLS + cI] = l[cI];
    const int lab = labels[b];
    float picked = 0.f;
    #pragma unroll
    for (int cI = 0; cI < NCLS; ++cI) picked += (cI == lab) ? l[cI] : 0.f;
    rowloss[b] = lse - picked;
  }
}

// ---------------------------------------------------------------------------
// Deterministic loss reduction (single block)
// ---------------------------------------------------------------------------
__global__ __launch_bounds__(256)
void loss_reduce_kernel(const float* __restrict__ rowloss, float* __restrict__ loss_out) {
  float s = 0.f;
  for (int i = threadIdx.x; i < BATCH; i += 256) s += rowloss[i];
  #pragma unroll
  for (int off = 32; off; off >>= 1) s += __shfl_down(s, off);
  __shared__ float sb[4];
  if ((threadIdx.x & 63) == 0) sb[threadIdx.x >> 6] = s;
  __syncthreads();
  if (threadIdx.x == 0) loss_out[0] = (sb[0] + sb[1] + sb[2] + sb[3]) * (1.f / BATCH);
}

// ---------------------------------------------------------------------------
extern "C" void kernel_launch(void* const* d_in, const int* in_sizes, int n_in,
                              void* d_out, int out_size, void* d_ws, size_t ws_size,
                              hipStream_t stream) {
  const float* x      = (const float*)d_in[0];
  const int*   labels = (const int*)  d_in[1];
  const float* Wout0  = (const float*)d_in[2];
  const float* bout0  = (const float*)d_in[3];
  const float* Wout1  = (const float*)d_in[4];
  const float* bout1  = (const float*)d_in[5];
  const float* Wout2  = (const float*)d_in[6];
  const float* bout2  = (const float*)d_in[7];
  const float* W1     = (const float*)d_in[8];
  const float* b1     = (const float*)d_in[9];
  const float* W2     = (const float*)d_in[10];
  const float* b2     = (const float*)d_in[11];
  const float* W3     = (const float*)d_in[12];
  const float* b3     = (const float*)d_in[13];
  const float* Wfc    = (const float*)d_in[14];
  const float* bfc    = (const float*)d_in[15];

  char* ws = (char*)d_ws;
  float*          Abuf    = (float*)(ws);                               // 64 MB fp32 4096x4096
  float*          Ybuf    = (float*)(ws + ((size_t)64 << 20));          //  8 MB fp32 4096x512
  __hip_bfloat16* Ybf     = (__hip_bfloat16*)(ws + ((size_t)72 << 20)); //  4 MB bf16 4096x512
  __hip_bfloat16* xbf     = (__hip_bfloat16*)(ws + ((size_t)76 << 20)); //  8 MB bf16 4096x1024
  __hip_bfloat16* WT0     = (__hip_bfloat16*)(ws + ((size_t)84 << 20)); //  8 MB bf16 4096x1024
  __hip_bfloat16* WT1     = (__hip_bfloat16*)(ws + ((size_t)92 << 20)); //  4 MB bf16 4096x512
  __hip_bfloat16* WT2     = (__hip_bfloat16*)(ws + ((size_t)96 << 20)); //  4 MB bf16 4096x512
  __hip_bfloat16* W2Tb    = (__hip_bfloat16*)(ws + ((size_t)100 << 20));// 128 KB bf16 16x64x64
  float*          rowloss = (float*)(ws + ((size_t)101 << 20));         // 16 KB
  float2*         stats   = (float2*)(ws + ((size_t)101 << 20) + (256 << 10)); // 32 KB

  float* logits = (float*)d_out;
  float* loss   = logits + (size_t)BATCH * NCLS;

  // per-launch weight/input conversions (deterministic, cheap)
  cvt_bf16_kernel<<<dim3(BATCH * 1024 / 4 / 256), dim3(256), 0, stream>>>(x, xbf, BATCH * 1024);
  transpose_cvt_kernel<<<dim3(NHID / 64, 1024 / 64), dim3(256), 0, stream>>>(Wout0, WT0, 1024, NHID);
  transpose_cvt_kernel<<<dim3(NHID / 64, PREV / 64), dim3(256), 0, stream>>>(Wout1, WT1, PREV, NHID);
  transpose_cvt_kernel<<<dim3(NHID / 64, PREV / 64), dim3(256), 0, stream>>>(Wout2, WT2, PREV, NHID);
  transpose_w2_bf16_kernel<<<dim3(NTYPES), dim3(256), 0, stream>>>(W2, W2Tb);

  const dim3 ggrid(NHID / 128, BATCH / 128), gblk(256);
  const dim3 sgrid(BATCH / 4), sblk(256);
  const dim3 igrid(BATCH / 64, NTYPES), iblk(256);

  // layer 0
  gemm_mfma_kernel<<<ggrid, gblk, 0, stream>>>(xbf, WT0, bout0, Abuf, NHID, 1024);
  ln_stats_kernel<<<sgrid, sblk, 0, stream>>>(Abuf, stats);
  inner_type_kernel<<<igrid, iblk, 0, stream>>>(Abuf, stats, nullptr, Ybf, W2Tb, W1, b1, b2, W3, b3);
  // layer 1
  gemm_mfma_kernel<<<ggrid, gblk, 0, stream>>>(Ybf, WT1, bout1, Abuf, NHID, PREV);
  ln_stats_kernel<<<sgrid, sblk, 0, stream>>>(Abuf, stats);
  inner_type_kernel<<<igrid, iblk, 0, stream>>>(Abuf, stats, nullptr, Ybf, W2Tb, W1, b1, b2, W3, b3);
  // layer 2
  gemm_mfma_kernel<<<ggrid, gblk, 0, stream>>>(Ybf, WT2, bout2, Abuf, NHID, PREV);
  ln_stats_kernel<<<sgrid, sblk, 0, stream>>>(Abuf, stats);
  inner_type_kernel<<<igrid, iblk, 0, stream>>>(Abuf, stats, Ybuf, Ybf, W2Tb, W1, b1, b2, W3, b3);

  // head + loss
  head_kernel<<<dim3(BATCH), dim3(64), 0, stream>>>(Ybuf, Wfc, bfc, labels, logits, rowloss);
  loss_reduce_kernel<<<dim3(1), dim3(256), 0, stream>>>(rowloss, loss);
}

// Round 8
// 380.438 us; speedup vs baseline: 4.8347x; 1.0895x over previous
//
#include <hip/hip_runtime.h>
#include <hip/hip_bf16.h>
#include <math.h>

// Problem constants
constexpr int BATCH   = 4096;
constexpr int NCLS    = 10;
constexpr int NHID    = 4096;   // OUT_HIDDEN
constexpr int PREV    = 512;    // NHID / ARG_IN
constexpr int NTYPES  = 16;
constexpr int CG      = 32;     // cells per type per row: 4096/(16*8)
constexpr float LN_EPS = 1e-5f;

typedef __attribute__((ext_vector_type(8))) short short8;   // 8 bf16 (4 VGPRs)
typedef __attribute__((ext_vector_type(4))) float f32x4;    // MFMA accumulator

// ---------------------------------------------------------------------------
// bf16 MFMA GEMM (m97 structure): C[M,N] = A[M,K] @ BT[N,K]^T + bias
// ---------------------------------------------------------------------------
__global__ __launch_bounds__(256)
void gemm_mfma_kernel(const __hip_bfloat16* __restrict__ A,   // M x K
                      const __hip_bfloat16* __restrict__ BT,  // N x K
                      const float* __restrict__ bias,
                      float* __restrict__ C,                  // M x N
                      int N, int K) {
  __shared__ __hip_bfloat16 As[128 * 32];
  __shared__ __hip_bfloat16 Bs[128 * 32];
  const int tid  = threadIdx.x;
  const int wid  = tid >> 6;
  const int lane = tid & 63;
  const int row0 = blockIdx.y * 128;
  const int col0 = blockIdx.x * 128;
  const int wrow = (wid >> 1) * 64;
  const int wcol = (wid & 1) * 64;

  f32x4 acc[4][4] = {};

  const int sr = wid * 32;
  const int lr = lane >> 2;
  const int lc = (lane & 3) * 8;

  const int fr = lane & 15;
  const int fo = (lane >> 4) * 8;

  for (int k0 = 0; k0 < K; k0 += 32) {
    const __hip_bfloat16* ga0 = A  + (size_t)(row0 + sr +      lr) * K + k0 + lc;
    const __hip_bfloat16* ga1 = A  + (size_t)(row0 + sr + 16 + lr) * K + k0 + lc;
    const __hip_bfloat16* gb0 = BT + (size_t)(col0 + sr +      lr) * K + k0 + lc;
    const __hip_bfloat16* gb1 = BT + (size_t)(col0 + sr + 16 + lr) * K + k0 + lc;
    __builtin_amdgcn_global_load_lds((const __attribute__((address_space(1))) void*)ga0,
                                     (__attribute__((address_space(3))) void*)&As[(sr     ) * 32], 16, 0, 0);
    __builtin_amdgcn_global_load_lds((const __attribute__((address_space(1))) void*)ga1,
                                     (__attribute__((address_space(3))) void*)&As[(sr + 16) * 32], 16, 0, 0);
    __builtin_amdgcn_global_load_lds((const __attribute__((address_space(1))) void*)gb0,
                                     (__attribute__((address_space(3))) void*)&Bs[(sr     ) * 32], 16, 0, 0);
    __builtin_amdgcn_global_load_lds((const __attribute__((address_space(1))) void*)gb1,
                                     (__attribute__((address_space(3))) void*)&Bs[(sr + 16) * 32], 16, 0, 0);
    __syncthreads();

    short8 af[4], bfr[4];
    #pragma unroll
    for (int i = 0; i < 4; ++i)
      af[i] = *reinterpret_cast<const short8*>(&As[(wrow + i * 16 + fr) * 32 + fo]);
    #pragma unroll
    for (int j = 0; j < 4; ++j)
      bfr[j] = *reinterpret_cast<const short8*>(&Bs[(wcol + j * 16 + fr) * 32 + fo]);

    #pragma unroll
    for (int i = 0; i < 4; ++i)
      #pragma unroll
      for (int j = 0; j < 4; ++j)
        acc[i][j] = __builtin_amdgcn_mfma_f32_16x16x32_bf16(af[i], bfr[j], acc[i][j], 0, 0, 0);
    __syncthreads();
  }

  #pragma unroll
  for (int j = 0; j < 4; ++j) {
    const int cc = col0 + wcol + j * 16 + (lane & 15);
    const float bv = bias[cc];
    #pragma unroll
    for (int i = 0; i < 4; ++i) {
      const int rr = row0 + wrow + i * 16 + (lane >> 4) * 4;
      #pragma unroll
      for (int r = 0; r < 4; ++r)
        C[(size_t)(rr + r) * N + cc] = acc[i][j][r] + bv;
    }
  }
}

// ---------------------------------------------------------------------------
// fp32 -> bf16 conversion (vectorized)
// ---------------------------------------------------------------------------
__global__ __launch_bounds__(256)
void cvt_bf16_kernel(const float* __restrict__ in, __hip_bfloat16* __restrict__ out, int n) {
  const int i = (blockIdx.x * 256 + threadIdx.x) * 4;
  if (i >= n) return;
  const float4 v = *reinterpret_cast<const float4*>(&in[i]);
  __hip_bfloat16 t[4];
  t[0] = __float2bfloat16(v.x); t[1] = __float2bfloat16(v.y);
  t[2] = __float2bfloat16(v.z); t[3] = __float2bfloat16(v.w);
  *reinterpret_cast<ushort4*>(&out[i]) = *reinterpret_cast<const ushort4*>(t);
}

// ---------------------------------------------------------------------------
// W (K x N fp32) -> WT (N x K bf16) transpose+convert, 64x64 LDS tiles
// ---------------------------------------------------------------------------
__global__ __launch_bounds__(256)
void transpose_cvt_kernel(const float* __restrict__ W, __hip_bfloat16* __restrict__ WT,
                          int K, int N) {
  __shared__ __hip_bfloat16 tile[64][65];
  const int tid = threadIdx.x;
  const int kt = blockIdx.y * 64, nt = blockIdx.x * 64;
  const int cn = tid & 63;
  for (int r = tid >> 6; r < 64; r += 4)
    tile[cn][r] = __float2bfloat16(W[(size_t)(kt + r) * N + nt + cn]);
  __syncthreads();
  for (int r = tid >> 6; r < 64; r += 4)
    WT[(size_t)(nt + r) * K + kt + cn] = tile[r][cn];
}

// ---------------------------------------------------------------------------
// Weight prep for inner MLP (per type t = blockIdx.x):
//  W2Tb[t][n][h] bf16  (transpose of W2)
//  W1b [t][n][k] bf16  (transpose of W1; k=0..7)   -> L1 MFMA A-fragments
//  swsum[t][n] fp32    (sum_k W1[t][k][n])          -> LN fold
// ---------------------------------------------------------------------------
__global__ __launch_bounds__(256)
void prep_weights_kernel(const float* __restrict__ W2, const float* __restrict__ W1,
                         __hip_bfloat16* __restrict__ W2Tb,
                         __hip_bfloat16* __restrict__ W1b,
                         float* __restrict__ swsum) {
  const int t = blockIdx.x;
  for (int idx = threadIdx.x; idx < 64 * 64; idx += 256) {
    const int n = idx >> 6, h = idx & 63;
    W2Tb[t * 4096 + n * 64 + h] = __float2bfloat16(W2[t * 4096 + h * 64 + n]);
  }
  for (int idx = threadIdx.x; idx < 512; idx += 256) {
    const int n = idx >> 3, k = idx & 7;
    W1b[t * 512 + idx] = __float2bfloat16(W1[t * 512 + k * 64 + n]);
  }
  if (threadIdx.x < 64) {
    float s = 0.f;
    #pragma unroll
    for (int k = 0; k < 8; ++k) s += W1[t * 512 + k * 64 + threadIdx.x];
    swsum[t * 64 + threadIdx.x] = s;
  }
}

// ---------------------------------------------------------------------------
// LN stats: one wave per row. stats[row] = (mu, rsqrt(var+eps))
// ---------------------------------------------------------------------------
__global__ __launch_bounds__(256)
void ln_stats_kernel(const float* __restrict__ X, float2* __restrict__ stats) {
  const int lane = threadIdx.x & 63;
  const int row  = blockIdx.x * 4 + (threadIdx.x >> 6);
  const float* p = X + (size_t)row * NHID;
  float s = 0.f, ss = 0.f;
  #pragma unroll
  for (int i = 0; i < 16; ++i) {
    const float4 v = *reinterpret_cast<const float4*>(&p[i * 256 + lane * 4]);
    s  += v.x + v.y + v.z + v.w;
    ss += v.x * v.x + v.y * v.y + v.z * v.z + v.w * v.w;
  }
  #pragma unroll
  for (int off = 32; off; off >>= 1) { s += __shfl_xor(s, off); ss += __shfl_xor(ss, off); }
  if (lane == 0) {
    const float mu = s * (1.f / 4096.f);
    float2 st;
    st.x = mu;
    st.y = rsqrtf(ss * (1.f / 4096.f) - mu * mu + LN_EPS);
    stats[row] = st;
  }
}

// ---------------------------------------------------------------------------
// Inner grouped MLPs. One TYPE per block, 64 batch rows, BARRIER-FREE.
// L1 is now MFMA (swapped operands): pC[n][cell] = W1^T(n,k) x z(k,cell),
// K=8 zero-padded to 32 (w1frag lanes fq>0 are hard zeros -> unused z lanes
// cannot poison the dot). Epilogue applies LN fold h = relu(rs*pC + bias2)
// and writes 4-contiguous-n b64 chunks into the SAME swizzled H1s layout the
// verified L2 path reads (byte ^= (cell&7)<<4 granule involution).
// z: lanes fq==0 load 2 cells x 8 fp32, ping-pong prefetched (T14).
// ---------------------------------------------------------------------------
__global__ __launch_bounds__(256, 2)
void inner_type_kernel(const float* __restrict__ X,          // (B, 4096) pre-LN
                       const float2* __restrict__ stats,     // (B,) mu, rs
                       float* __restrict__ out,              // (B, 512) or null
                       __hip_bfloat16* __restrict__ outb,
                       const __hip_bfloat16* __restrict__ W2Tb,
                       const __hip_bfloat16* __restrict__ W1b,
                       const float* __restrict__ swsum,
                       const float* __restrict__ b1,
                       const float* __restrict__ b2,
                       const float* __restrict__ W3, const float* __restrict__ b3) {
  __shared__ __hip_bfloat16 H1s[128 * 64];   // 16 KB; byte ^= (cell&7)<<4 swizzle
  const int tid  = threadIdx.x;
  const int lane = tid & 63;
  const int wvid = tid >> 6;
  const int t    = blockIdx.y;
  const int r0   = blockIdx.x * 64;

  const int fc  = lane & 15;     // fragment row/col index
  const int fq  = lane >> 4;     // fragment quad
  const bool ld = (fq == 0);     // z-loading lanes

  // z for cells fc and fc+16 of the wave's current batch row (lanes fq==0)
  const float* zcol = X + t * 256 + fc * 8;

#define LOAD_Z(zr, itv)                                                        \
  if (ld) {                                                                    \
    const float* zb_ = zcol + (size_t)(r0 + (itv) * 4 + wvid) * NHID;          \
    *reinterpret_cast<float4*>(&zr[0])  = *reinterpret_cast<const float4*>(zb_);          \
    *reinterpret_cast<float4*>(&zr[4])  = *reinterpret_cast<const float4*>(zb_ + 4);      \
    *reinterpret_cast<float4*>(&zr[8])  = *reinterpret_cast<const float4*>(zb_ + 128);    \
    *reinterpret_cast<float4*>(&zr[12]) = *reinterpret_cast<const float4*>(zb_ + 132);    \
  }

  float zA[16], zB[16];
  #pragma unroll
  for (int i = 0; i < 16; ++i) { zA[i] = 0.f; zB[i] = 0.f; }
  float2 stA, stB;
  LOAD_Z(zA, 0);
  stA = stats[r0 + wvid];

  // ---- startup: all weight state loaded ONCE ----
  // L1 A-fragments: W1^T, lane fc = n-row, fq==0 holds k=0..7, else zero
  short8 w1frag[4];
  #pragma unroll
  for (int nf = 0; nf < 4; ++nf) {
    short8 v = {};
    if (ld) v = *reinterpret_cast<const short8*>(&W1b[(size_t)t * 512 + (nf * 16 + fc) * 8]);
    w1frag[nf] = v;
  }

  // L2 B-fragments: W2^T
  short8 bfrag[4][2];
  #pragma unroll
  for (int cf = 0; cf < 4; ++cf)
    #pragma unroll
    for (int ks = 0; ks < 2; ++ks)
      bfrag[cf][ks] = *reinterpret_cast<const short8*>(
          &W2Tb[(size_t)t * 4096 + (cf * 16 + fc) * 64 + ks * 32 + fq * 8]);

  // LN-fold constants: per lane, n = nf*16 + fq*4 + r
  float4 b1q[4], swq[4];
  #pragma unroll
  for (int nf = 0; nf < 4; ++nf) {
    b1q[nf] = *reinterpret_cast<const float4*>(&b1[t * 64 + nf * 16 + fq * 4]);
    swq[nf] = *reinterpret_cast<const float4*>(&swsum[t * 64 + nf * 16 + fq * 4]);
  }

  float b2v[4], w3v[4];
  #pragma unroll
  for (int cf = 0; cf < 4; ++cf) {
    b2v[cf] = b2[t * 64 + cf * 16 + fc];
    w3v[cf] = W3[t * 64 + cf * 16 + fc];
  }
  const float yb = b3[t];

#define BODY(zr, stv, itv)                                                     \
  {                                                                            \
    const int row_ = r0 + (itv) * 4 + wvid;                                    \
    const float rs_ = stv.y;                                                   \
    const float c1_ = -stv.x * rs_;                                            \
    /* z -> bf16 B-fragments (lanes fq>0 hold zeros by construction) */        \
    short8 zf[2];                                                              \
    {                                                                          \
      union { short8 v; __hip_bfloat16 e[8]; } p0, p1;                         \
      _Pragma("unroll")                                                        \
      for (int q = 0; q < 8; ++q) {                                            \
        p0.e[q] = __float2bfloat16(zr[q]);                                     \
        p1.e[q] = __float2bfloat16(zr[8 + q]);                                 \
      }                                                                        \
      zf[0] = p0.v; zf[1] = p1.v;                                              \
    }                                                                          \
    /* L1: 8 MFMA, pC[nf][ci] = W1^T x z  (n rows, cells cols) */              \
    f32x4 pC[4][2] = {};                                                       \
    _Pragma("unroll")                                                          \
    for (int nf = 0; nf < 4; ++nf) {                                           \
      pC[nf][0] = __builtin_amdgcn_mfma_f32_16x16x32_bf16(w1frag[nf], zf[0], pC[nf][0], 0, 0, 0); \
      pC[nf][1] = __builtin_amdgcn_mfma_f32_16x16x32_bf16(w1frag[nf], zf[1], pC[nf][1], 0, 0, 0); \
    }                                                                          \
    /* epilogue-L1: h = relu(rs*pC + b1 + c1*sw), write b64 (4 contig n) */    \
    _Pragma("unroll")                                                          \
    for (int nf = 0; nf < 4; ++nf) {                                           \
      const float bx = fmaf(c1_, swq[nf].x, b1q[nf].x);                        \
      const float by = fmaf(c1_, swq[nf].y, b1q[nf].y);                        \
      const float bz = fmaf(c1_, swq[nf].z, b1q[nf].z);                        \
      const float bw = fmaf(c1_, swq[nf].w, b1q[nf].w);                        \
      _Pragma("unroll")                                                        \
      for (int ci = 0; ci < 2; ++ci) {                                         \
        union { uint2 u; __hip_bfloat16 e[4]; } pk_;                           \
        pk_.e[0] = __float2bfloat16(fmaxf(fmaf(rs_, pC[nf][ci][0], bx), 0.f)); \
        pk_.e[1] = __float2bfloat16(fmaxf(fmaf(rs_, pC[nf][ci][1], by), 0.f)); \
        pk_.e[2] = __float2bfloat16(fmaxf(fmaf(rs_, pC[nf][ci][2], bz), 0.f)); \
        pk_.e[3] = __float2bfloat16(fmaxf(fmaf(rs_, pC[nf][ci][3], bw), 0.f)); \
        const int cell_ = wvid * 32 + ci * 16 + fc;                            \
        const int boff_ = cell_ * 128 + ((nf * 32 + fq * 8) ^ ((cell_ & 7) << 4)); \
        *reinterpret_cast<uint2*>((char*)H1s + boff_) = pk_.u;                 \
      }                                                                        \
    }                                                                          \
    /* L2 MFMA: wave-private rows of H1s (unchanged, verified) */              \
    f32x4 acc[2][4] = {};                                                      \
    _Pragma("unroll")                                                          \
    for (int ks = 0; ks < 2; ++ks) {                                           \
      short8 a0_, a1_;                                                         \
      {                                                                        \
        const int hrow_ = wvid * 32 + fc;                                      \
        a0_ = *reinterpret_cast<const short8*>(                                \
            &H1s[hrow_ * 64 + ((ks * 32 + fq * 8) ^ ((hrow_ & 7) << 3))]);     \
      }                                                                        \
      {                                                                        \
        const int hrow_ = wvid * 32 + 16 + fc;                                 \
        a1_ = *reinterpret_cast<const short8*>(                                \
            &H1s[hrow_ * 64 + ((ks * 32 + fq * 8) ^ ((hrow_ & 7) << 3))]);     \
      }                                                                        \
      _Pragma("unroll")                                                        \
      for (int cf = 0; cf < 4; ++cf) {                                         \
        acc[0][cf] = __builtin_amdgcn_mfma_f32_16x16x32_bf16(a0_, bfrag[cf][ks], acc[0][cf], 0, 0, 0); \
        acc[1][cf] = __builtin_amdgcn_mfma_f32_16x16x32_bf16(a1_, bfrag[cf][ks], acc[1][cf], 0, 0, 0); \
      }                                                                        \
    }                                                                          \
    /* L3 epilogue */                                                          \
    float p[2][4];                                                             \
    _Pragma("unroll")                                                          \
    for (int rf = 0; rf < 2; ++rf)                                             \
      _Pragma("unroll")                                                        \
      for (int r = 0; r < 4; ++r) {                                            \
        float s_ = 0.f;                                                        \
        _Pragma("unroll")                                                      \
        for (int cf = 0; cf < 4; ++cf)                                         \
          s_ = fmaf(fmaxf(acc[rf][cf][r] + b2v[cf], 0.f), w3v[cf], s_);        \
        s_ += __shfl_xor(s_, 1);                                               \
        s_ += __shfl_xor(s_, 2);                                               \
        s_ += __shfl_xor(s_, 4);                                               \
        s_ += __shfl_xor(s_, 8);                                               \
        p[rf][r] = s_;                                                         \
      }                                                                        \
    if (fc == 0) {                                                             \
      _Pragma("unroll")                                                        \
      for (int rf = 0; rf < 2; ++rf)                                           \
        _Pragma("unroll")                                                      \
        for (int r = 0; r < 4; ++r) {                                          \
          const int c_ = rf * 16 + fq * 4 + r;                                 \
          const float y_ = p[rf][r] + yb;                                      \
          const size_t oidx_ = (size_t)row_ * PREV + t * CG + c_;              \
          if (out) out[oidx_] = y_;                                            \
          outb[oidx_] = __float2bfloat16(y_);                                  \
        }                                                                      \
    }                                                                          \
  }

  #pragma unroll 1
  for (int it2 = 0; it2 < 8; ++it2) {
    const int itA = it2 * 2;
    LOAD_Z(zB, itA + 1);
    stB = stats[r0 + (itA + 1) * 4 + wvid];
    BODY(zA, stA, itA);
    if (it2 < 7) {
      LOAD_Z(zA, itA + 2);
      stA = stats[r0 + (itA + 2) * 4 + wvid];
    }
    BODY(zB, stB, itA + 1);
  }
#undef LOAD_Z
#undef BODY
}

// ---------------------------------------------------------------------------
// Head: logits = Y @ Wfc + bfc ; per-row NLL into rowloss (one wave per row)
// ---------------------------------------------------------------------------
__global__ __launch_bounds__(64)
void head_kernel(const float* __restrict__ Y, const float* __restrict__ Wfc,
                 const float* __restrict__ bfc, const int* __restrict__ labels,
                 float* __restrict__ logits, float* __restrict__ rowloss) {
  const int b = blockIdx.x;
  const int lane = threadIdx.x;
  const float* yr = Y + (size_t)b * PREV;
  float acc[NCLS] = {};
  for (int k = lane; k < PREV; k += 64) {
    const float yv = yr[k];
    #pragma unroll
    for (int cI = 0; cI < NCLS; ++cI) acc[cI] = fmaf(yv, Wfc[k * NCLS + cI], acc[cI]);
  }
  #pragma unroll
  for (int cI = 0; cI < NCLS; ++cI) {
    #pragma unroll
    for (int off = 32; off; off >>= 1) acc[cI] += __shfl_down(acc[cI], off);
  }
  if (lane == 0) {
    float l[NCLS];
    float m = -1e30f;
    #pragma unroll
    for (int cI = 0; cI < NCLS; ++cI) { l[cI] = acc[cI] + bfc[cI]; m = fmaxf(m, l[cI]); }
    float se = 0.f;
    #pragma unroll
    for (int cI = 0; cI < NCLS; ++cI) se += __expf(l[cI] - m);
    const float lse = m + __logf(se);
    #pragma unroll
    for (int cI = 0; cI < NCLS; ++cI) logits[(size_t)b * NCLS + cI] = l[cI];
    const int lab = labels[b];
    float picked = 0.f;
    #pragma unroll
    for (int cI = 0; cI < NCLS; ++cI) picked += (cI == lab) ? l[cI] : 0.f;
    rowloss[b] = lse - picked;
  }
}

// ---------------------------------------------------------------------------
// Deterministic loss reduction (single block)
// ---------------------------------------------------------------------------
__global__ __launch_bounds__(256)
void loss_reduce_kernel(const float* __restrict__ rowloss, float* __restrict__ loss_out) {
  float s = 0.f;
  for (int i = threadIdx.x; i < BATCH; i += 256) s += rowloss[i];
  #pragma unroll
  for (int off = 32; off; off >>= 1) s += __shfl_down(s, off);
  __shared__ float sb[4];
  if ((threadIdx.x & 63) == 0) sb[threadIdx.x >> 6] = s;
  __syncthreads();
  if (threadIdx.x == 0) loss_out[0] = (sb[0] + sb[1] + sb[2] + sb[3]) * (1.f / BATCH);
}

// ---------------------------------------------------------------------------
extern "C" void kernel_launch(void* const* d_in, const int* in_sizes, int n_in,
                              void* d_out, int out_size, void* d_ws, size_t ws_size,
                              hipStream_t stream) {
  const float* x      = (const float*)d_in[0];
  const int*   labels = (const int*)  d_in[1];
  const float* Wout0  = (const float*)d_in[2];
  const float* bout0  = (const float*)d_in[3];
  const float* Wout1  = (const float*)d_in[4];
  const float* bout1  = (const float*)d_in[5];
  const float* Wout2  = (const float*)d_in[6];
  const float* bout2  = (const float*)d_in[7];
  const float* W1     = (const float*)d_in[8];
  const float* b1     = (const float*)d_in[9];
  const float* W2     = (const float*)d_in[10];
  const float* b2     = (const float*)d_in[11];
  const float* W3     = (const float*)d_in[12];
  const float* b3     = (const float*)d_in[13];
  const float* Wfc    = (const float*)d_in[14];
  const float* bfc    = (const float*)d_in[15];

  char* ws = (char*)d_ws;
  float*          Abuf    = (float*)(ws);                               // 64 MB fp32 4096x4096
  float*          Ybuf    = (float*)(ws + ((size_t)64 << 20));          //  8 MB fp32 4096x512
  __hip_bfloat16* Ybf     = (__hip_bfloat16*)(ws + ((size_t)72 << 20)); //  4 MB bf16 4096x512
  __hip_bfloat16* xbf     = (__hip_bfloat16*)(ws + ((size_t)76 << 20)); //  8 MB bf16 4096x1024
  __hip_bfloat16* WT0     = (__hip_bfloat16*)(ws + ((size_t)84 << 20)); //  8 MB bf16 4096x1024
  __hip_bfloat16* WT1     = (__hip_bfloat16*)(ws + ((size_t)92 << 20)); //  4 MB bf16 4096x512
  __hip_bfloat16* WT2     = (__hip_bfloat16*)(ws + ((size_t)96 << 20)); //  4 MB bf16 4096x512
  __hip_bfloat16* W2Tb    = (__hip_bfloat16*)(ws + ((size_t)100 << 20));// 128 KB bf16 16x64x64
  __hip_bfloat16* W1b     = (__hip_bfloat16*)(ws + ((size_t)100 << 20) + (128 << 10)); // 16 KB
  float*          swsum   = (float*)(ws + ((size_t)100 << 20) + (192 << 10));          //  4 KB
  float*          rowloss = (float*)(ws + ((size_t)101 << 20));         // 16 KB
  float2*         stats   = (float2*)(ws + ((size_t)101 << 20) + (256 << 10)); // 32 KB

  float* logits = (float*)d_out;
  float* loss   = logits + (size_t)BATCH * NCLS;

  // per-launch weight/input conversions (deterministic, cheap)
  cvt_bf16_kernel<<<dim3(BATCH * 1024 / 4 / 256), dim3(256), 0, stream>>>(x, xbf, BATCH * 1024);
  transpose_cvt_kernel<<<dim3(NHID / 64, 1024 / 64), dim3(256), 0, stream>>>(Wout0, WT0, 1024, NHID);
  transpose_cvt_kernel<<<dim3(NHID / 64, PREV / 64), dim3(256), 0, stream>>>(Wout1, WT1, PREV, NHID);
  transpose_cvt_kernel<<<dim3(NHID / 64, PREV / 64), dim3(256), 0, stream>>>(Wout2, WT2, PREV, NHID);
  prep_weights_kernel<<<dim3(NTYPES), dim3(256), 0, stream>>>(W2, W1, W2Tb, W1b, swsum);

  const dim3 ggrid(NHID / 128, BATCH / 128), gblk(256);
  const dim3 sgrid(BATCH / 4), sblk(256);
  const dim3 igrid(BATCH / 64, NTYPES), iblk(256);

  // layer 0
  gemm_mfma_kernel<<<ggrid, gblk, 0, stream>>>(xbf, WT0, bout0, Abuf, NHID, 1024);
  ln_stats_kernel<<<sgrid, sblk, 0, stream>>>(Abuf, stats);
  inner_type_kernel<<<igrid, iblk, 0, stream>>>(Abuf, stats, nullptr, Ybf, W2Tb, W1b, swsum, b1, b2, W3, b3);
  // layer 1
  gemm_mfma_kernel<<<ggrid, gblk, 0, stream>>>(Ybf, WT1, bout1, Abuf, NHID, PREV);
  ln_stats_kernel<<<sgrid, sblk, 0, stream>>>(Abuf, stats);
  inner_type_kernel<<<igrid, iblk, 0, stream>>>(Abuf, stats, nullptr, Ybf, W2Tb, W1b, swsum, b1, b2, W3, b3);
  // layer 2
  gemm_mfma_kernel<<<ggrid, gblk, 0, stream>>>(Ybf, WT2, bout2, Abuf, NHID, PREV);
  ln_stats_kernel<<<sgrid, sblk, 0, stream>>>(Abuf, stats);
  inner_type_kernel<<<igrid, iblk, 0, stream>>>(Abuf, stats, Ybuf, Ybf, W2Tb, W1b, swsum, b1, b2, W3, b3);

  // head + loss
  head_kernel<<<dim3(BATCH), dim3(64), 0, stream>>>(Ybuf, Wfc, bfc, labels, logits, rowloss);
  loss_reduce_kernel<<<dim3(1), dim3(256), 0, stream>>>(rowloss, loss);
}

// Round 9
// 358.162 us; speedup vs baseline: 5.1354x; 1.0622x over previous
//
#include <hip/hip_runtime.h>
#include <hip/hip_bf16.h>
#include <math.h>

// Problem constants
constexpr int BATCH   = 4096;
constexpr int NCLS    = 10;
constexpr int NHID    = 4096;   // OUT_HIDDEN
constexpr int PREV    = 512;    // NHID / ARG_IN
constexpr int NTYPES  = 16;
constexpr int CG      = 32;     // cells per type per row
constexpr int NCB     = NHID / 128;   // 32 col-blocks per GEMM row
constexpr float LN_EPS = 1e-5f;

typedef __attribute__((ext_vector_type(8))) short short8;   // 8 bf16 (4 VGPRs)
typedef __attribute__((ext_vector_type(4))) float f32x4;    // MFMA accumulator

// ---------------------------------------------------------------------------
// bf16 MFMA GEMM + fused LN partials:
//   Cb[M,4096] (bf16) = A[M,K] @ BT[4096,K]^T + bias
//   partials[row][colblk] = (sum, sumsq) of this block's 128-col slice (fp32)
// ---------------------------------------------------------------------------
__global__ __launch_bounds__(256)
void gemm_ln_kernel(const __hip_bfloat16* __restrict__ A,   // M x K
                    const __hip_bfloat16* __restrict__ BT,  // 4096 x K
                    const float* __restrict__ bias,
                    __hip_bfloat16* __restrict__ Cb,        // M x 4096 bf16
                    float2* __restrict__ partials,          // M x 32
                    int K) {
  __shared__ __hip_bfloat16 As[128 * 32];
  __shared__ __hip_bfloat16 Bs[128 * 32];
  __shared__ float2 sbuf[2][128];
  const int tid  = threadIdx.x;
  const int wid  = tid >> 6;
  const int lane = tid & 63;
  const int row0 = blockIdx.y * 128;
  const int col0 = blockIdx.x * 128;
  const int wrow = (wid >> 1) * 64;
  const int wcol = (wid & 1) * 64;

  f32x4 acc[4][4] = {};

  const int sr = wid * 32;
  const int lr = lane >> 2;
  const int lc = (lane & 3) * 8;

  const int fr = lane & 15;
  const int lq = lane >> 4;
  const int fo = lq * 8;

  for (int k0 = 0; k0 < K; k0 += 32) {
    const __hip_bfloat16* ga0 = A  + (size_t)(row0 + sr +      lr) * K + k0 + lc;
    const __hip_bfloat16* ga1 = A  + (size_t)(row0 + sr + 16 + lr) * K + k0 + lc;
    const __hip_bfloat16* gb0 = BT + (size_t)(col0 + sr +      lr) * K + k0 + lc;
    const __hip_bfloat16* gb1 = BT + (size_t)(col0 + sr + 16 + lr) * K + k0 + lc;
    __builtin_amdgcn_global_load_lds((const __attribute__((address_space(1))) void*)ga0,
                                     (__attribute__((address_space(3))) void*)&As[(sr     ) * 32], 16, 0, 0);
    __builtin_amdgcn_global_load_lds((const __attribute__((address_space(1))) void*)ga1,
                                     (__attribute__((address_space(3))) void*)&As[(sr + 16) * 32], 16, 0, 0);
    __builtin_amdgcn_global_load_lds((const __attribute__((address_space(1))) void*)gb0,
                                     (__attribute__((address_space(3))) void*)&Bs[(sr     ) * 32], 16, 0, 0);
    __builtin_amdgcn_global_load_lds((const __attribute__((address_space(1))) void*)gb1,
                                     (__attribute__((address_space(3))) void*)&Bs[(sr + 16) * 32], 16, 0, 0);
    __syncthreads();

    short8 af[4], bfr[4];
    #pragma unroll
    for (int i = 0; i < 4; ++i)
      af[i] = *reinterpret_cast<const short8*>(&As[(wrow + i * 16 + fr) * 32 + fo]);
    #pragma unroll
    for (int j = 0; j < 4; ++j)
      bfr[j] = *reinterpret_cast<const short8*>(&Bs[(wcol + j * 16 + fr) * 32 + fo]);

    #pragma unroll
    for (int i = 0; i < 4; ++i)
      #pragma unroll
      for (int j = 0; j < 4; ++j)
        acc[i][j] = __builtin_amdgcn_mfma_f32_16x16x32_bf16(af[i], bfr[j], acc[i][j], 0, 0, 0);
    __syncthreads();
  }

  // epilogue: bf16 store + per-row (sum, sumsq) over this block's 128 cols
  float sA[4][4] = {}, sQ[4][4] = {};
  #pragma unroll
  for (int j = 0; j < 4; ++j) {
    const int cc = col0 + wcol + j * 16 + fr;
    const float bv = bias[cc];
    #pragma unroll
    for (int i = 0; i < 4; ++i) {
      const int rr = row0 + wrow + i * 16 + lq * 4;
      #pragma unroll
      for (int r = 0; r < 4; ++r) {
        const float v = acc[i][j][r] + bv;
        Cb[(size_t)(rr + r) * NHID + cc] = __float2bfloat16(v);
        sA[i][r] += v;
        sQ[i][r] = fmaf(v, v, sQ[i][r]);
      }
    }
  }
  #pragma unroll
  for (int i = 0; i < 4; ++i)
    #pragma unroll
    for (int r = 0; r < 4; ++r) {
      float sv = sA[i][r], sq = sQ[i][r];
      sv += __shfl_xor(sv, 1); sq += __shfl_xor(sq, 1);
      sv += __shfl_xor(sv, 2); sq += __shfl_xor(sq, 2);
      sv += __shfl_xor(sv, 4); sq += __shfl_xor(sq, 4);
      sv += __shfl_xor(sv, 8); sq += __shfl_xor(sq, 8);
      if (fr == 0) sbuf[wid & 1][wrow + i * 16 + lq * 4 + r] = make_float2(sv, sq);
    }
  __syncthreads();
  for (int idx = tid; idx < 128; idx += 256) {
    const float2 a = sbuf[0][idx], b = sbuf[1][idx];
    partials[(size_t)(row0 + idx) * NCB + blockIdx.x] = make_float2(a.x + b.x, a.y + b.y);
  }
}

// ---------------------------------------------------------------------------
// stats[row] = (mu, rsqrt(var+eps)) from 32 per-colblock partials
// ---------------------------------------------------------------------------
__global__ __launch_bounds__(256)
void stats_reduce_kernel(const float2* __restrict__ partials, float2* __restrict__ stats) {
  const int row = blockIdx.x * 256 + threadIdx.x;
  const float2* p = partials + (size_t)row * NCB;
  float s = 0.f, ss = 0.f;
  #pragma unroll
  for (int cb = 0; cb < NCB; ++cb) { const float2 v = p[cb]; s += v.x; ss += v.y; }
  const float mu = s * (1.f / 4096.f);
  float2 st;
  st.x = mu;
  st.y = rsqrtf(ss * (1.f / 4096.f) - mu * mu + LN_EPS);
  stats[row] = st;
}

// ---------------------------------------------------------------------------
// fp32 -> bf16 conversion (vectorized)
// ---------------------------------------------------------------------------
__global__ __launch_bounds__(256)
void cvt_bf16_kernel(const float* __restrict__ in, __hip_bfloat16* __restrict__ out, int n) {
  const int i = (blockIdx.x * 256 + threadIdx.x) * 4;
  if (i >= n) return;
  const float4 v = *reinterpret_cast<const float4*>(&in[i]);
  __hip_bfloat16 t[4];
  t[0] = __float2bfloat16(v.x); t[1] = __float2bfloat16(v.y);
  t[2] = __float2bfloat16(v.z); t[3] = __float2bfloat16(v.w);
  *reinterpret_cast<ushort4*>(&out[i]) = *reinterpret_cast<const ushort4*>(t);
}

// ---------------------------------------------------------------------------
// W (K x N fp32) -> WT (N x K bf16) transpose+convert, 64x64 LDS tiles
// ---------------------------------------------------------------------------
__global__ __launch_bounds__(256)
void transpose_cvt_kernel(const float* __restrict__ W, __hip_bfloat16* __restrict__ WT,
                          int K, int N) {
  __shared__ __hip_bfloat16 tile[64][65];
  const int tid = threadIdx.x;
  const int kt = blockIdx.y * 64, nt = blockIdx.x * 64;
  const int cn = tid & 63;
  for (int r = tid >> 6; r < 64; r += 4)
    tile[cn][r] = __float2bfloat16(W[(size_t)(kt + r) * N + nt + cn]);
  __syncthreads();
  for (int r = tid >> 6; r < 64; r += 4)
    WT[(size_t)(nt + r) * K + kt + cn] = tile[r][cn];
}

// ---------------------------------------------------------------------------
// Weight prep for inner MLP (per type t = blockIdx.x)
// ---------------------------------------------------------------------------
__global__ __launch_bounds__(256)
void prep_weights_kernel(const float* __restrict__ W2, const float* __restrict__ W1,
                         __hip_bfloat16* __restrict__ W2Tb,
                         __hip_bfloat16* __restrict__ W1b,
                         float* __restrict__ swsum) {
  const int t = blockIdx.x;
  for (int idx = threadIdx.x; idx < 64 * 64; idx += 256) {
    const int n = idx >> 6, h = idx & 63;
    W2Tb[t * 4096 + n * 64 + h] = __float2bfloat16(W2[t * 4096 + h * 64 + n]);
  }
  for (int idx = threadIdx.x; idx < 512; idx += 256) {
    const int n = idx >> 3, k = idx & 7;
    W1b[t * 512 + idx] = __float2bfloat16(W1[t * 512 + k * 64 + n]);
  }
  if (threadIdx.x < 64) {
    float s = 0.f;
    #pragma unroll
    for (int k = 0; k < 8; ++k) s += W1[t * 512 + k * 64 + threadIdx.x];
    swsum[t * 64 + threadIdx.x] = s;
  }
}

// ---------------------------------------------------------------------------
// Inner grouped MLPs. One TYPE per block, 32 batch rows (8 iters), barrier-
// free. X is bf16: the two 16B short8 loads ARE the L1 MFMA B-fragments
// (lanes fq>0 hold zeros; w1frag also zero there). LN folded algebraically.
// Ping-pong prefetch of zf + stats (T14).
// ---------------------------------------------------------------------------
__global__ __launch_bounds__(256, 3)
void inner_type_kernel(const __hip_bfloat16* __restrict__ Xb,  // (B,4096) bf16 pre-LN
                       const float2* __restrict__ stats,       // (B,) mu, rs
                       float* __restrict__ out,                // (B,512) or null
                       __hip_bfloat16* __restrict__ outb,
                       const __hip_bfloat16* __restrict__ W2Tb,
                       const __hip_bfloat16* __restrict__ W1b,
                       const float* __restrict__ swsum,
                       const float* __restrict__ b1,
                       const float* __restrict__ b2,
                       const float* __restrict__ W3, const float* __restrict__ b3) {
  __shared__ __hip_bfloat16 H1s[128 * 64];   // 16 KB; byte ^= (cell&7)<<4 swizzle
  const int tid  = threadIdx.x;
  const int lane = tid & 63;
  const int wvid = tid >> 6;
  const int t    = blockIdx.y;
  const int r0   = blockIdx.x * 32;

  const int fc  = lane & 15;
  const int fq  = lane >> 4;
  const bool ld = (fq == 0);

  const __hip_bfloat16* zcol = Xb + t * 256 + fc * 8;

#define LOAD_Z(zf0, zf1, itv)                                                  \
  if (ld) {                                                                    \
    const __hip_bfloat16* zb_ = zcol + (size_t)(r0 + (itv) * 4 + wvid) * NHID; \
    zf0 = *reinterpret_cast<const short8*>(zb_);                               \
    zf1 = *reinterpret_cast<const short8*>(zb_ + 128);                         \
  }

  short8 zfA0 = {}, zfA1 = {}, zfB0 = {}, zfB1 = {};
  float2 stA, stB;
  LOAD_Z(zfA0, zfA1, 0);
  stA = stats[r0 + wvid];

  // ---- startup: weights loaded ONCE ----
  short8 w1frag[4];
  #pragma unroll
  for (int nf = 0; nf < 4; ++nf) {
    short8 v = {};
    if (ld) v = *reinterpret_cast<const short8*>(&W1b[(size_t)t * 512 + (nf * 16 + fc) * 8]);
    w1frag[nf] = v;
  }

  short8 bfrag[4][2];
  #pragma unroll
  for (int cf = 0; cf < 4; ++cf)
    #pragma unroll
    for (int ks = 0; ks < 2; ++ks)
      bfrag[cf][ks] = *reinterpret_cast<const short8*>(
          &W2Tb[(size_t)t * 4096 + (cf * 16 + fc) * 64 + ks * 32 + fq * 8]);

  float4 b1q[4], swq[4];
  #pragma unroll
  for (int nf = 0; nf < 4; ++nf) {
    b1q[nf] = *reinterpret_cast<const float4*>(&b1[t * 64 + nf * 16 + fq * 4]);
    swq[nf] = *reinterpret_cast<const float4*>(&swsum[t * 64 + nf * 16 + fq * 4]);
  }

  float b2v[4], w3v[4];
  #pragma unroll
  for (int cf = 0; cf < 4; ++cf) {
    b2v[cf] = b2[t * 64 + cf * 16 + fc];
    w3v[cf] = W3[t * 64 + cf * 16 + fc];
  }
  const float yb = b3[t];

#define BODY(zf0, zf1, stv, itv)                                               \
  {                                                                            \
    const int row_ = r0 + (itv) * 4 + wvid;                                    \
    const float rs_ = stv.y;                                                   \
    const float c1_ = -stv.x * rs_;                                            \
    /* L1: 8 MFMA, pC[nf][ci] = W1^T x z (n rows, cells cols) */               \
    f32x4 pC[4][2] = {};                                                       \
    _Pragma("unroll")                                                          \
    for (int nf = 0; nf < 4; ++nf) {                                           \
      pC[nf][0] = __builtin_amdgcn_mfma_f32_16x16x32_bf16(w1frag[nf], zf0, pC[nf][0], 0, 0, 0); \
      pC[nf][1] = __builtin_amdgcn_mfma_f32_16x16x32_bf16(w1frag[nf], zf1, pC[nf][1], 0, 0, 0); \
    }                                                                          \
    /* epilogue-L1: h = relu(rs*pC + b1 + c1*sw), b64 writes (4 contig n) */   \
    _Pragma("unroll")                                                          \
    for (int nf = 0; nf < 4; ++nf) {                                           \
      const float bx = fmaf(c1_, swq[nf].x, b1q[nf].x);                        \
      const float by = fmaf(c1_, swq[nf].y, b1q[nf].y);                        \
      const float bz = fmaf(c1_, swq[nf].z, b1q[nf].z);                        \
      const float bw = fmaf(c1_, swq[nf].w, b1q[nf].w);                        \
      _Pragma("unroll")                                                        \
      for (int ci = 0; ci < 2; ++ci) {                                         \
        union { uint2 u; __hip_bfloat16 e[4]; } pk_;                           \
        pk_.e[0] = __float2bfloat16(fmaxf(fmaf(rs_, pC[nf][ci][0], bx), 0.f)); \
        pk_.e[1] = __float2bfloat16(fmaxf(fmaf(rs_, pC[nf][ci][1], by), 0.f)); \
        pk_.e[2] = __float2bfloat16(fmaxf(fmaf(rs_, pC[nf][ci][2], bz), 0.f)); \
        pk_.e[3] = __float2bfloat16(fmaxf(fmaf(rs_, pC[nf][ci][3], bw), 0.f)); \
        const int cell_ = wvid * 32 + ci * 16 + fc;                            \
        const int boff_ = cell_ * 128 + ((nf * 32 + fq * 8) ^ ((cell_ & 7) << 4)); \
        *reinterpret_cast<uint2*>((char*)H1s + boff_) = pk_.u;                 \
      }                                                                        \
    }                                                                          \
    /* L2 MFMA: wave-private rows of H1s */                                    \
    f32x4 acc[2][4] = {};                                                      \
    _Pragma("unroll")                                                          \
    for (int ks = 0; ks < 2; ++ks) {                                           \
      short8 a0_, a1_;                                                         \
      {                                                                        \
        const int hrow_ = wvid * 32 + fc;                                      \
        a0_ = *reinterpret_cast<const short8*>(                                \
            &H1s[hrow_ * 64 + ((ks * 32 + fq * 8) ^ ((hrow_ & 7) << 3))]);     \
      }                                                                        \
      {                                                                        \
        const int hrow_ = wvid * 32 + 16 + fc;                                 \
        a1_ = *reinterpret_cast<const short8*>(                                \
            &H1s[hrow_ * 64 + ((ks * 32 + fq * 8) ^ ((hrow_ & 7) << 3))]);     \
      }                                                                        \
      _Pragma("unroll")                                                        \
      for (int cf = 0; cf < 4; ++cf) {                                         \
        acc[0][cf] = __builtin_amdgcn_mfma_f32_16x16x32_bf16(a0_, bfrag[cf][ks], acc[0][cf], 0, 0, 0); \
        acc[1][cf] = __builtin_amdgcn_mfma_f32_16x16x32_bf16(a1_, bfrag[cf][ks], acc[1][cf], 0, 0, 0); \
      }                                                                        \
    }                                                                          \
    /* L3 epilogue */                                                          \
    float p[2][4];                                                             \
    _Pragma("unroll")                                                          \
    for (int rf = 0; rf < 2; ++rf)                                             \
      _Pragma("unroll")                                                        \
      for (int r = 0; r < 4; ++r) {                                            \
        float s_ = 0.f;                                                        \
        _Pragma("unroll")                                                      \
        for (int cf = 0; cf < 4; ++cf)                                         \
          s_ = fmaf(fmaxf(acc[rf][cf][r] + b2v[cf], 0.f), w3v[cf], s_);        \
        s_ += __shfl_xor(s_, 1);                                               \
        s_ += __shfl_xor(s_, 2);                                               \
        s_ += __shfl_xor(s_, 4);                                               \
        s_ += __shfl_xor(s_, 8);                                               \
        p[rf][r] = s_;                                                         \
      }                                                                        \
    if (fc == 0) {                                                             \
      _Pragma("unroll")                                                        \
      for (int rf = 0; rf < 2; ++rf)                                           \
        _Pragma("unroll")                                                      \
        for (int r = 0; r < 4; ++r) {                                          \
          const int c_ = rf * 16 + fq * 4 + r;                                 \
          const float y_ = p[rf][r] + yb;                                      \
          const size_t oidx_ = (size_t)row_ * PREV + t * CG + c_;              \
          if (out) out[oidx_] = y_;                                            \
          outb[oidx_] = __float2bfloat16(y_);                                  \
        }                                                                      \
    }                                                                          \
  }

  #pragma unroll 1
  for (int it2 = 0; it2 < 4; ++it2) {
    const int itA = it2 * 2;
    LOAD_Z(zfB0, zfB1, itA + 1);
    stB = stats[r0 + (itA + 1) * 4 + wvid];
    BODY(zfA0, zfA1, stA, itA);
    if (it2 < 3) {
      LOAD_Z(zfA0, zfA1, itA + 2);
      stA = stats[r0 + (itA + 2) * 4 + wvid];
    }
    BODY(zfB0, zfB1, stB, itA + 1);
  }
#undef LOAD_Z
#undef BODY
}

// ---------------------------------------------------------------------------
// Head: logits = Y @ Wfc + bfc ; per-row NLL into rowloss (one wave per row)
// ---------------------------------------------------------------------------
__global__ __launch_bounds__(64)
void head_kernel(const float* __restrict__ Y, const float* __restrict__ Wfc,
                 const float* __restrict__ bfc, const int* __restrict__ labels,
                 float* __restrict__ logits, float* __restrict__ rowloss) {
  const int b = blockIdx.x;
  const int lane = threadIdx.x;
  const float* yr = Y + (size_t)b * PREV;
  float acc[NCLS] = {};
  for (int k = lane; k < PREV; k += 64) {
    const float yv = yr[k];
    #pragma unroll
    for (int cI = 0; cI < NCLS; ++cI) acc[cI] = fmaf(yv, Wfc[k * NCLS + cI], acc[cI]);
  }
  #pragma unroll
  for (int cI = 0; cI < NCLS; ++cI) {
    #pragma unroll
    for (int off = 32; off; off >>= 1) acc[cI] += __shfl_down(acc[cI], off);
  }
  if (lane == 0) {
    float l[NCLS];
    float m = -1e30f;
    #pragma unroll
    for (int cI = 0; cI < NCLS; ++cI) { l[cI] = acc[cI] + bfc[cI]; m = fmaxf(m, l[cI]); }
    float se = 0.f;
    #pragma unroll
    for (int cI = 0; cI < NCLS; ++cI) se += __expf(l[cI] - m);
    const float lse = m + __logf(se);
    #pragma unroll
    for (int cI = 0; cI < NCLS; ++cI) logits[(size_t)b * NCLS + cI] = l[cI];
    const int lab = labels[b];
    float picked = 0.f;
    #pragma unroll
    for (int cI = 0; cI < NCLS; ++cI) picked += (cI == lab) ? l[cI] : 0.f;
    rowloss[b] = lse - picked;
  }
}

// ---------------------------------------------------------------------------
// Deterministic loss reduction (single block)
// ---------------------------------------------------------------------------
__global__ __launch_bounds__(256)
void loss_reduce_kernel(const float* __restrict__ rowloss, float* __restrict__ loss_out) {
  float s = 0.f;
  for (int i = threadIdx.x; i < BATCH; i += 256) s += rowloss[i];
  #pragma unroll
  for (int off = 32; off; off >>= 1) s += __shfl_down(s, off);
  __shared__ float sb[4];
  if ((threadIdx.x & 63) == 0) sb[threadIdx.x >> 6] = s;
  __syncthreads();
  if (threadIdx.x == 0) loss_out[0] = (sb[0] + sb[1] + sb[2] + sb[3]) * (1.f / BATCH);
}

// ---------------------------------------------------------------------------
extern "C" void kernel_launch(void* const* d_in, const int* in_sizes, int n_in,
                              void* d_out, int out_size, void* d_ws, size_t ws_size,
                              hipStream_t stream) {
  const float* x      = (const float*)d_in[0];
  const int*   labels = (const int*)  d_in[1];
  const float* Wout0  = (const float*)d_in[2];
  const float* bout0  = (const float*)d_in[3];
  const float* Wout1  = (const float*)d_in[4];
  const float* bout1  = (const float*)d_in[5];
  const float* Wout2  = (const float*)d_in[6];
  const float* bout2  = (const float*)d_in[7];
  const float* W1     = (const float*)d_in[8];
  const float* b1     = (const float*)d_in[9];
  const float* W2     = (const float*)d_in[10];
  const float* b2     = (const float*)d_in[11];
  const float* W3     = (const float*)d_in[12];
  const float* b3     = (const float*)d_in[13];
  const float* Wfc    = (const float*)d_in[14];
  const float* bfc    = (const float*)d_in[15];

  char* ws = (char*)d_ws;
  __hip_bfloat16* Abf     = (__hip_bfloat16*)(ws);                      // 32 MB bf16 4096x4096
  float*          Ybuf    = (float*)(ws + ((size_t)32 << 20));          //  8 MB fp32 4096x512
  __hip_bfloat16* Ybf     = (__hip_bfloat16*)(ws + ((size_t)40 << 20)); //  4 MB bf16 4096x512
  __hip_bfloat16* xbf     = (__hip_bfloat16*)(ws + ((size_t)44 << 20)); //  8 MB bf16 4096x1024
  __hip_bfloat16* WT0     = (__hip_bfloat16*)(ws + ((size_t)52 << 20)); //  8 MB bf16 4096x1024
  __hip_bfloat16* WT1     = (__hip_bfloat16*)(ws + ((size_t)60 << 20)); //  4 MB bf16 4096x512
  __hip_bfloat16* WT2     = (__hip_bfloat16*)(ws + ((size_t)64 << 20)); //  4 MB bf16 4096x512
  __hip_bfloat16* W2Tb    = (__hip_bfloat16*)(ws + ((size_t)68 << 20)); // 128 KB
  __hip_bfloat16* W1b     = (__hip_bfloat16*)(ws + ((size_t)68 << 20) + (128 << 10)); // 16 KB
  float*          swsum   = (float*)(ws + ((size_t)68 << 20) + (192 << 10));          //  4 KB
  float2*         partials= (float2*)(ws + ((size_t)69 << 20));         //  1 MB 4096x32 float2
  float2*         stats   = (float2*)(ws + ((size_t)70 << 20));         // 32 KB
  float*          rowloss = (float*)(ws + ((size_t)71 << 20));          // 16 KB

  float* logits = (float*)d_out;
  float* loss   = logits + (size_t)BATCH * NCLS;

  // per-launch weight/input conversions (deterministic, cheap)
  cvt_bf16_kernel<<<dim3(BATCH * 1024 / 4 / 256), dim3(256), 0, stream>>>(x, xbf, BATCH * 1024);
  transpose_cvt_kernel<<<dim3(NHID / 64, 1024 / 64), dim3(256), 0, stream>>>(Wout0, WT0, 1024, NHID);
  transpose_cvt_kernel<<<dim3(NHID / 64, PREV / 64), dim3(256), 0, stream>>>(Wout1, WT1, PREV, NHID);
  transpose_cvt_kernel<<<dim3(NHID / 64, PREV / 64), dim3(256), 0, stream>>>(Wout2, WT2, PREV, NHID);
  prep_weights_kernel<<<dim3(NTYPES), dim3(256), 0, stream>>>(W2, W1, W2Tb, W1b, swsum);

  const dim3 ggrid(NHID / 128, BATCH / 128), gblk(256);
  const dim3 rgrid(BATCH / 256), rblk(256);
  const dim3 igrid(BATCH / 32, NTYPES), iblk(256);

  // layer 0
  gemm_ln_kernel<<<ggrid, gblk, 0, stream>>>(xbf, WT0, bout0, Abf, partials, 1024);
  stats_reduce_kernel<<<rgrid, rblk, 0, stream>>>(partials, stats);
  inner_type_kernel<<<igrid, iblk, 0, stream>>>(Abf, stats, nullptr, Ybf, W2Tb, W1b, swsum, b1, b2, W3, b3);
  // layer 1
  gemm_ln_kernel<<<ggrid, gblk, 0, stream>>>(Ybf, WT1, bout1, Abf, partials, PREV);
  stats_reduce_kernel<<<rgrid, rblk, 0, stream>>>(partials, stats);
  inner_type_kernel<<<igrid, iblk, 0, stream>>>(Abf, stats, nullptr, Ybf, W2Tb, W1b, swsum, b1, b2, W3, b3);
  // layer 2
  gemm_ln_kernel<<<ggrid, gblk, 0, stream>>>(Ybf, WT2, bout2, Abf, partials, PREV);
  stats_reduce_kernel<<<rgrid, rblk, 0, stream>>>(partials, stats);
  inner_type_kernel<<<igrid, iblk, 0, stream>>>(Abf, stats, Ybuf, Ybf, W2Tb, W1b, swsum, b1, b2, W3, b3);

  // head + loss
  head_kernel<<<dim3(BATCH), dim3(64), 0, stream>>>(Ybuf, Wfc, bfc, labels, logits, rowloss);
  loss_reduce_kernel<<<dim3(1), dim3(256), 0, stream>>>(rowloss, loss);
}

// Round 10
// 343.185 us; speedup vs baseline: 5.3595x; 1.0436x over previous
//
#include <hip/hip_runtime.h>
#include <hip/hip_bf16.h>
#include <math.h>

// Problem constants
constexpr int BATCH   = 4096;
constexpr int NCLS    = 10;
constexpr int NHID    = 4096;   // OUT_HIDDEN
constexpr int PREV    = 512;    // NHID / ARG_IN
constexpr int NTYPES  = 16;
constexpr int CG      = 32;     // cells per type per row
constexpr float LN_EPS = 1e-5f;

typedef __attribute__((ext_vector_type(8))) short short8;   // 8 bf16 (4 VGPRs)
typedef __attribute__((ext_vector_type(4))) float f32x4;    // MFMA accumulator

// ---------------------------------------------------------------------------
// bf16 MFMA GEMM (m97 structure): Cb[M,4096] (bf16) = A @ BT^T + bias
// Plain epilogue (no fused reductions — round-9 fused-LN epilogue cost 2x).
// ---------------------------------------------------------------------------
__global__ __launch_bounds__(256)
void gemm_bf16_kernel(const __hip_bfloat16* __restrict__ A,   // M x K
                      const __hip_bfloat16* __restrict__ BT,  // 4096 x K
                      const float* __restrict__ bias,
                      __hip_bfloat16* __restrict__ Cb,        // M x 4096 bf16
                      int K) {
  __shared__ __hip_bfloat16 As[128 * 32];
  __shared__ __hip_bfloat16 Bs[128 * 32];
  const int tid  = threadIdx.x;
  const int wid  = tid >> 6;
  const int lane = tid & 63;
  const int row0 = blockIdx.y * 128;
  const int col0 = blockIdx.x * 128;
  const int wrow = (wid >> 1) * 64;
  const int wcol = (wid & 1) * 64;

  f32x4 acc[4][4] = {};

  const int sr = wid * 32;
  const int lr = lane >> 2;
  const int lc = (lane & 3) * 8;

  const int fr = lane & 15;
  const int lq = lane >> 4;
  const int fo = lq * 8;

  for (int k0 = 0; k0 < K; k0 += 32) {
    const __hip_bfloat16* ga0 = A  + (size_t)(row0 + sr +      lr) * K + k0 + lc;
    const __hip_bfloat16* ga1 = A  + (size_t)(row0 + sr + 16 + lr) * K + k0 + lc;
    const __hip_bfloat16* gb0 = BT + (size_t)(col0 + sr +      lr) * K + k0 + lc;
    const __hip_bfloat16* gb1 = BT + (size_t)(col0 + sr + 16 + lr) * K + k0 + lc;
    __builtin_amdgcn_global_load_lds((const __attribute__((address_space(1))) void*)ga0,
                                     (__attribute__((address_space(3))) void*)&As[(sr     ) * 32], 16, 0, 0);
    __builtin_amdgcn_global_load_lds((const __attribute__((address_space(1))) void*)ga1,
                                     (__attribute__((address_space(3))) void*)&As[(sr + 16) * 32], 16, 0, 0);
    __builtin_amdgcn_global_load_lds((const __attribute__((address_space(1))) void*)gb0,
                                     (__attribute__((address_space(3))) void*)&Bs[(sr     ) * 32], 16, 0, 0);
    __builtin_amdgcn_global_load_lds((const __attribute__((address_space(1))) void*)gb1,
                                     (__attribute__((address_space(3))) void*)&Bs[(sr + 16) * 32], 16, 0, 0);
    __syncthreads();

    short8 af[4], bfr[4];
    #pragma unroll
    for (int i = 0; i < 4; ++i)
      af[i] = *reinterpret_cast<const short8*>(&As[(wrow + i * 16 + fr) * 32 + fo]);
    #pragma unroll
    for (int j = 0; j < 4; ++j)
      bfr[j] = *reinterpret_cast<const short8*>(&Bs[(wcol + j * 16 + fr) * 32 + fo]);

    #pragma unroll
    for (int i = 0; i < 4; ++i)
      #pragma unroll
      for (int j = 0; j < 4; ++j)
        acc[i][j] = __builtin_amdgcn_mfma_f32_16x16x32_bf16(af[i], bfr[j], acc[i][j], 0, 0, 0);
    __syncthreads();
  }

  #pragma unroll
  for (int j = 0; j < 4; ++j) {
    const int cc = col0 + wcol + j * 16 + fr;
    const float bv = bias[cc];
    #pragma unroll
    for (int i = 0; i < 4; ++i) {
      const int rr = row0 + wrow + i * 16 + lq * 4;
      #pragma unroll
      for (int r = 0; r < 4; ++r)
        Cb[(size_t)(rr + r) * NHID + cc] = __float2bfloat16(acc[i][j][r] + bv);
    }
  }
}

// ---------------------------------------------------------------------------
// LN stats over bf16 activations: one wave per row. stats[row] = (mu, rs)
// ---------------------------------------------------------------------------
__global__ __launch_bounds__(256)
void ln_stats_bf16_kernel(const __hip_bfloat16* __restrict__ Xb, float2* __restrict__ stats) {
  const int lane = threadIdx.x & 63;
  const int row  = blockIdx.x * 4 + (threadIdx.x >> 6);
  const __hip_bfloat16* p = Xb + (size_t)row * NHID;
  float s = 0.f, ss = 0.f;
  #pragma unroll
  for (int i = 0; i < 8; ++i) {
    union { short8 v; unsigned short u[8]; } b;
    b.v = *reinterpret_cast<const short8*>(&p[i * 512 + lane * 8]);
    #pragma unroll
    for (int j = 0; j < 8; ++j) {
      const float f = __uint_as_float(((unsigned)b.u[j]) << 16);
      s += f;
      ss = fmaf(f, f, ss);
    }
  }
  #pragma unroll
  for (int off = 32; off; off >>= 1) { s += __shfl_xor(s, off); ss += __shfl_xor(ss, off); }
  if (lane == 0) {
    const float mu = s * (1.f / 4096.f);
    float2 st;
    st.x = mu;
    st.y = rsqrtf(ss * (1.f / 4096.f) - mu * mu + LN_EPS);
    stats[row] = st;
  }
}

// ---------------------------------------------------------------------------
// fp32 -> bf16 conversion (vectorized)
// ---------------------------------------------------------------------------
__global__ __launch_bounds__(256)
void cvt_bf16_kernel(const float* __restrict__ in, __hip_bfloat16* __restrict__ out, int n) {
  const int i = (blockIdx.x * 256 + threadIdx.x) * 4;
  if (i >= n) return;
  const float4 v = *reinterpret_cast<const float4*>(&in[i]);
  __hip_bfloat16 t[4];
  t[0] = __float2bfloat16(v.x); t[1] = __float2bfloat16(v.y);
  t[2] = __float2bfloat16(v.z); t[3] = __float2bfloat16(v.w);
  *reinterpret_cast<ushort4*>(&out[i]) = *reinterpret_cast<const ushort4*>(t);
}

// ---------------------------------------------------------------------------
// W (K x N fp32) -> WT (N x K bf16) transpose+convert, 64x64 LDS tiles
// ---------------------------------------------------------------------------
__global__ __launch_bounds__(256)
void transpose_cvt_kernel(const float* __restrict__ W, __hip_bfloat16* __restrict__ WT,
                          int K, int N) {
  __shared__ __hip_bfloat16 tile[64][65];
  const int tid = threadIdx.x;
  const int kt = blockIdx.y * 64, nt = blockIdx.x * 64;
  const int cn = tid & 63;
  for (int r = tid >> 6; r < 64; r += 4)
    tile[cn][r] = __float2bfloat16(W[(size_t)(kt + r) * N + nt + cn]);
  __syncthreads();
  for (int r = tid >> 6; r < 64; r += 4)
    WT[(size_t)(nt + r) * K + kt + cn] = tile[r][cn];
}

// ---------------------------------------------------------------------------
// Weight prep for inner MLP (per type t = blockIdx.x)
// ---------------------------------------------------------------------------
__global__ __launch_bounds__(256)
void prep_weights_kernel(const float* __restrict__ W2, const float* __restrict__ W1,
                         __hip_bfloat16* __restrict__ W2Tb,
                         __hip_bfloat16* __restrict__ W1b,
                         float* __restrict__ swsum) {
  const int t = blockIdx.x;
  for (int idx = threadIdx.x; idx < 64 * 64; idx += 256) {
    const int n = idx >> 6, h = idx & 63;
    W2Tb[t * 4096 + n * 64 + h] = __float2bfloat16(W2[t * 4096 + h * 64 + n]);
  }
  for (int idx = threadIdx.x; idx < 512; idx += 256) {
    const int n = idx >> 3, k = idx & 7;
    W1b[t * 512 + idx] = __float2bfloat16(W1[t * 512 + k * 64 + n]);
  }
  if (threadIdx.x < 64) {
    float s = 0.f;
    #pragma unroll
    for (int k = 0; k < 8; ++k) s += W1[t * 512 + k * 64 + threadIdx.x];
    swsum[t * 64 + threadIdx.x] = s;
  }
}

// ---------------------------------------------------------------------------
// Inner grouped MLPs. One TYPE per block, 32 batch rows (8 iters), barrier-
// free. X is bf16: the two 16B short8 loads ARE the L1 MFMA B-fragments
// (lanes fq>0 hold zeros; w1frag also zero there). LN folded algebraically.
// Ping-pong prefetch of zf + stats (T14).
// ---------------------------------------------------------------------------
__global__ __launch_bounds__(256, 3)
void inner_type_kernel(const __hip_bfloat16* __restrict__ Xb,  // (B,4096) bf16 pre-LN
                       const float2* __restrict__ stats,       // (B,) mu, rs
                       float* __restrict__ out,                // (B,512) or null
                       __hip_bfloat16* __restrict__ outb,
                       const __hip_bfloat16* __restrict__ W2Tb,
                       const __hip_bfloat16* __restrict__ W1b,
                       const float* __restrict__ swsum,
                       const float* __restrict__ b1,
                       const float* __restrict__ b2,
                       const float* __restrict__ W3, const float* __restrict__ b3) {
  __shared__ __hip_bfloat16 H1s[128 * 64];   // 16 KB; byte ^= (cell&7)<<4 swizzle
  const int tid  = threadIdx.x;
  const int lane = tid & 63;
  const int wvid = tid >> 6;
  const int t    = blockIdx.y;
  const int r0   = blockIdx.x * 32;

  const int fc  = lane & 15;
  const int fq  = lane >> 4;
  const bool ld = (fq == 0);

  const __hip_bfloat16* zcol = Xb + t * 256 + fc * 8;

#define LOAD_Z(zf0, zf1, itv)                                                  \
  if (ld) {                                                                    \
    const __hip_bfloat16* zb_ = zcol + (size_t)(r0 + (itv) * 4 + wvid) * NHID; \
    zf0 = *reinterpret_cast<const short8*>(zb_);                               \
    zf1 = *reinterpret_cast<const short8*>(zb_ + 128);                         \
  }

  short8 zfA0 = {}, zfA1 = {}, zfB0 = {}, zfB1 = {};
  float2 stA, stB;
  LOAD_Z(zfA0, zfA1, 0);
  stA = stats[r0 + wvid];

  // ---- startup: weights loaded ONCE ----
  short8 w1frag[4];
  #pragma unroll
  for (int nf = 0; nf < 4; ++nf) {
    short8 v = {};
    if (ld) v = *reinterpret_cast<const short8*>(&W1b[(size_t)t * 512 + (nf * 16 + fc) * 8]);
    w1frag[nf] = v;
  }

  short8 bfrag[4][2];
  #pragma unroll
  for (int cf = 0; cf < 4; ++cf)
    #pragma unroll
    for (int ks = 0; ks < 2; ++ks)
      bfrag[cf][ks] = *reinterpret_cast<const short8*>(
          &W2Tb[(size_t)t * 4096 + (cf * 16 + fc) * 64 + ks * 32 + fq * 8]);

  float4 b1q[4], swq[4];
  #pragma unroll
  for (int nf = 0; nf < 4; ++nf) {
    b1q[nf] = *reinterpret_cast<const float4*>(&b1[t * 64 + nf * 16 + fq * 4]);
    swq[nf] = *reinterpret_cast<const float4*>(&swsum[t * 64 + nf * 16 + fq * 4]);
  }

  float b2v[4], w3v[4];
  #pragma unroll
  for (int cf = 0; cf < 4; ++cf) {
    b2v[cf] = b2[t * 64 + cf * 16 + fc];
    w3v[cf] = W3[t * 64 + cf * 16 + fc];
  }
  const float yb = b3[t];

#define BODY(zf0, zf1, stv, itv)                                               \
  {                                                                            \
    const int row_ = r0 + (itv) * 4 + wvid;                                    \
    const float rs_ = stv.y;                                                   \
    const float c1_ = -stv.x * rs_;                                            \
    /* L1: 8 MFMA, pC[nf][ci] = W1^T x z (n rows, cells cols) */               \
    f32x4 pC[4][2] = {};                                                       \
    _Pragma("unroll")                                                          \
    for (int nf = 0; nf < 4; ++nf) {                                           \
      pC[nf][0] = __builtin_amdgcn_mfma_f32_16x16x32_bf16(w1frag[nf], zf0, pC[nf][0], 0, 0, 0); \
      pC[nf][1] = __builtin_amdgcn_mfma_f32_16x16x32_bf16(w1frag[nf], zf1, pC[nf][1], 0, 0, 0); \
    }                                                                          \
    /* epilogue-L1: h = relu(rs*pC + b1 + c1*sw), b64 writes (4 contig n) */   \
    _Pragma("unroll")                                                          \
    for (int nf = 0; nf < 4; ++nf) {                                           \
      const float bx = fmaf(c1_, swq[nf].x, b1q[nf].x);                        \
      const float by = fmaf(c1_, swq[nf].y, b1q[nf].y);                        \
      const float bz = fmaf(c1_, swq[nf].z, b1q[nf].z);                        \
      const float bw = fmaf(c1_, swq[nf].w, b1q[nf].w);                        \
      _Pragma("unroll")                                                        \
      for (int ci = 0; ci < 2; ++ci) {                                         \
        union { uint2 u; __hip_bfloat16 e[4]; } pk_;                           \
        pk_.e[0] = __float2bfloat16(fmaxf(fmaf(rs_, pC[nf][ci][0], bx), 0.f)); \
        pk_.e[1] = __float2bfloat16(fmaxf(fmaf(rs_, pC[nf][ci][1], by), 0.f)); \
        pk_.e[2] = __float2bfloat16(fmaxf(fmaf(rs_, pC[nf][ci][2], bz), 0.f)); \
        pk_.e[3] = __float2bfloat16(fmaxf(fmaf(rs_, pC[nf][ci][3], bw), 0.f)); \
        const int cell_ = wvid * 32 + ci * 16 + fc;                            \
        const int boff_ = cell_ * 128 + ((nf * 32 + fq * 8) ^ ((cell_ & 7) << 4)); \
        *reinterpret_cast<uint2*>((char*)H1s + boff_) = pk_.u;                 \
      }                                                                        \
    }                                                                          \
    /* L2 MFMA: wave-private rows of H1s */                                    \
    f32x4 acc[2][4] = {};                                                      \
    _Pragma("unroll")                                                          \
    for (int ks = 0; ks < 2; ++ks) {                                           \
      short8 a0_, a1_;                                                         \
      {                                                                        \
        const int hrow_ = wvid * 32 + fc;                                      \
        a0_ = *reinterpret_cast<const short8*>(                                \
            &H1s[hrow_ * 64 + ((ks * 32 + fq * 8) ^ ((hrow_ & 7) << 3))]);     \
      }                                                                        \
      {                                                                        \
        const int hrow_ = wvid * 32 + 16 + fc;                                 \
        a1_ = *reinterpret_cast<const short8*>(                                \
            &H1s[hrow_ * 64 + ((ks * 32 + fq * 8) ^ ((hrow_ & 7) << 3))]);     \
      }                                                                        \
      _Pragma("unroll")                                                        \
      for (int cf = 0; cf < 4; ++cf) {                                         \
        acc[0][cf] = __builtin_amdgcn_mfma_f32_16x16x32_bf16(a0_, bfrag[cf][ks], acc[0][cf], 0, 0, 0); \
        acc[1][cf] = __builtin_amdgcn_mfma_f32_16x16x32_bf16(a1_, bfrag[cf][ks], acc[1][cf], 0, 0, 0); \
      }                                                                        \
    }                                                                          \
    /* L3 epilogue */                                                          \
    float p[2][4];                                                             \
    _Pragma("unroll")                                                          \
    for (int rf = 0; rf < 2; ++rf)                                             \
      _Pragma("unroll")                                                        \
      for (int r = 0; r < 4; ++r) {                                            \
        float s_ = 0.f;                                                        \
        _Pragma("unroll")                                                      \
        for (int cf = 0; cf < 4; ++cf)                                         \
          s_ = fmaf(fmaxf(acc[rf][cf][r] + b2v[cf], 0.f), w3v[cf], s_);        \
        s_ += __shfl_xor(s_, 1);                                               \
        s_ += __shfl_xor(s_, 2);                                               \
        s_ += __shfl_xor(s_, 4);                                               \
        s_ += __shfl_xor(s_, 8);                                               \
        p[rf][r] = s_;                                                         \
      }                                                                        \
    if (fc == 0) {                                                             \
      _Pragma("unroll")                                                        \
      for (int rf = 0; rf < 2; ++rf)                                           \
        _Pragma("unroll")                                                      \
        for (int r = 0; r < 4; ++r) {                                          \
          const int c_ = rf * 16 + fq * 4 + r;                                 \
          const float y_ = p[rf][r] + yb;                                      \
          const size_t oidx_ = (size_t)row_ * PREV + t * CG + c_;              \
          if (out) out[oidx_] = y_;                                            \
          outb[oidx_] = __float2bfloat16(y_);                                  \
        }                                                                      \
    }                                                                          \
  }

  #pragma unroll 1
  for (int it2 = 0; it2 < 4; ++it2) {
    const int itA = it2 * 2;
    LOAD_Z(zfB0, zfB1, itA + 1);
    stB = stats[r0 + (itA + 1) * 4 + wvid];
    BODY(zfA0, zfA1, stA, itA);
    if (it2 < 3) {
      LOAD_Z(zfA0, zfA1, itA + 2);
      stA = stats[r0 + (itA + 2) * 4 + wvid];
    }
    BODY(zfB0, zfB1, stB, itA + 1);
  }
#undef LOAD_Z
#undef BODY
}

// ---------------------------------------------------------------------------
// Head: logits = Y @ Wfc + bfc ; per-row NLL into rowloss (one wave per row)
// ---------------------------------------------------------------------------
__global__ __launch_bounds__(64)
void head_kernel(const float* __restrict__ Y, const float* __restrict__ Wfc,
                 const float* __restrict__ bfc, const int* __restrict__ labels,
                 float* __restrict__ logits, float* __restrict__ rowloss) {
  const int b = blockIdx.x;
  const int lane = threadIdx.x;
  const float* yr = Y + (size_t)b * PREV;
  float acc[NCLS] = {};
  for (int k = lane; k < PREV; k += 64) {
    const float yv = yr[k];
    #pragma unroll
    for (int cI = 0; cI < NCLS; ++cI) acc[cI] = fmaf(yv, Wfc[k * NCLS + cI], acc[cI]);
  }
  #pragma unroll
  for (int cI = 0; cI < NCLS; ++cI) {
    #pragma unroll
    for (int off = 32; off; off >>= 1) acc[cI] += __shfl_down(acc[cI], off);
  }
  if (lane == 0) {
    float l[NCLS];
    float m = -1e30f;
    #pragma unroll
    for (int cI = 0; cI < NCLS; ++cI) { l[cI] = acc[cI] + bfc[cI]; m = fmaxf(m, l[cI]); }
    float se = 0.f;
    #pragma unroll
    for (int cI = 0; cI < NCLS; ++cI) se += __expf(l[cI] - m);
    const float lse = m + __logf(se);
    #pragma unroll
    for (int cI = 0; cI < NCLS; ++cI) logits[(size_t)b * NCLS + cI] = l[cI];
    const int lab = labels[b];
    float picked = 0.f;
    #pragma unroll
    for (int cI = 0; cI < NCLS; ++cI) picked += (cI == lab) ? l[cI] : 0.f;
    rowloss[b] = lse - picked;
  }
}

// ---------------------------------------------------------------------------
// Deterministic loss reduction (single block)
// ---------------------------------------------------------------------------
__global__ __launch_bounds__(256)
void loss_reduce_kernel(const float* __restrict__ rowloss, float* __restrict__ loss_out) {
  float s = 0.f;
  for (int i = threadIdx.x; i < BATCH; i += 256) s += rowloss[i];
  #pragma unroll
  for (int off = 32; off; off >>= 1) s += __shfl_down(s, off);
  __shared__ float sb[4];
  if ((threadIdx.x & 63) == 0) sb[threadIdx.x >> 6] = s;
  __syncthreads();
  if (threadIdx.x == 0) loss_out[0] = (sb[0] + sb[1] + sb[2] + sb[3]) * (1.f / BATCH);
}

// ---------------------------------------------------------------------------
extern "C" void kernel_launch(void* const* d_in, const int* in_sizes, int n_in,
                              void* d_out, int out_size, void* d_ws, size_t ws_size,
                              hipStream_t stream) {
  const float* x      = (const float*)d_in[0];
  const int*   labels = (const int*)  d_in[1];
  const float* Wout0  = (const float*)d_in[2];
  const float* bout0  = (const float*)d_in[3];
  const float* Wout1  = (const float*)d_in[4];
  const float* bout1  = (const float*)d_in[5];
  const float* Wout2  = (const float*)d_in[6];
  const float* bout2  = (const float*)d_in[7];
  const float* W1     = (const float*)d_in[8];
  const float* b1     = (const float*)d_in[9];
  const float* W2     = (const float*)d_in[10];
  const float* b2     = (const float*)d_in[11];
  const float* W3     = (const float*)d_in[12];
  const float* b3     = (const float*)d_in[13];
  const float* Wfc    = (const float*)d_in[14];
  const float* bfc    = (const float*)d_in[15];

  char* ws = (char*)d_ws;
  __hip_bfloat16* Abf     = (__hip_bfloat16*)(ws);                      // 32 MB bf16 4096x4096
  float*          Ybuf    = (float*)(ws + ((size_t)32 << 20));          //  8 MB fp32 4096x512
  __hip_bfloat16* Ybf     = (__hip_bfloat16*)(ws + ((size_t)40 << 20)); //  4 MB bf16 4096x512
  __hip_bfloat16* xbf     = (__hip_bfloat16*)(ws + ((size_t)44 << 20)); //  8 MB bf16 4096x1024
  __hip_bfloat16* WT0     = (__hip_bfloat16*)(ws + ((size_t)52 << 20)); //  8 MB bf16 4096x1024
  __hip_bfloat16* WT1     = (__hip_bfloat16*)(ws + ((size_t)60 << 20)); //  4 MB bf16 4096x512
  __hip_bfloat16* WT2     = (__hip_bfloat16*)(ws + ((size_t)64 << 20)); //  4 MB bf16 4096x512
  __hip_bfloat16* W2Tb    = (__hip_bfloat16*)(ws + ((size_t)68 << 20)); // 128 KB
  __hip_bfloat16* W1b     = (__hip_bfloat16*)(ws + ((size_t)68 << 20) + (128 << 10)); // 16 KB
  float*          swsum   = (float*)(ws + ((size_t)68 << 20) + (192 << 10));          //  4 KB
  float2*         stats   = (float2*)(ws + ((size_t)70 << 20));         // 32 KB
  float*          rowloss = (float*)(ws + ((size_t)71 << 20));          // 16 KB

  float* logits = (float*)d_out;
  float* loss   = logits + (size_t)BATCH * NCLS;

  // per-launch weight/input conversions (deterministic, cheap)
  cvt_bf16_kernel<<<dim3(BATCH * 1024 / 4 / 256), dim3(256), 0, stream>>>(x, xbf, BATCH * 1024);
  transpose_cvt_kernel<<<dim3(NHID / 64, 1024 / 64), dim3(256), 0, stream>>>(Wout0, WT0, 1024, NHID);
  transpose_cvt_kernel<<<dim3(NHID / 64, PREV / 64), dim3(256), 0, stream>>>(Wout1, WT1, PREV, NHID);
  transpose_cvt_kernel<<<dim3(NHID / 64, PREV / 64), dim3(256), 0, stream>>>(Wout2, WT2, PREV, NHID);
  prep_weights_kernel<<<dim3(NTYPES), dim3(256), 0, stream>>>(W2, W1, W2Tb, W1b, swsum);

  const dim3 ggrid(NHID / 128, BATCH / 128), gblk(256);
  const dim3 sgrid(BATCH / 4), sblk(256);
  const dim3 igrid(BATCH / 32, NTYPES), iblk(256);

  // layer 0
  gemm_bf16_kernel<<<ggrid, gblk, 0, stream>>>(xbf, WT0, bout0, Abf, 1024);
  ln_stats_bf16_kernel<<<sgrid, sblk, 0, stream>>>(Abf, stats);
  inner_type_kernel<<<igrid, iblk, 0, stream>>>(Abf, stats, nullptr, Ybf, W2Tb, W1b, swsum, b1, b2, W3, b3);
  // layer 1
  gemm_bf16_kernel<<<ggrid, gblk, 0, stream>>>(Ybf, WT1, bout1, Abf, PREV);
  ln_stats_bf16_kernel<<<sgrid, sblk, 0, stream>>>(Abf, stats);
  inner_type_kernel<<<igrid, iblk, 0, stream>>>(Abf, stats, nullptr, Ybf, W2Tb, W1b, swsum, b1, b2, W3, b3);
  // layer 2
  gemm_bf16_kernel<<<ggrid, gblk, 0, stream>>>(Ybf, WT2, bout2, Abf, PREV);
  ln_stats_bf16_kernel<<<sgrid, sblk, 0, stream>>>(Abf, stats);
  inner_type_kernel<<<igrid, iblk, 0, stream>>>(Abf, stats, Ybuf, Ybf, W2Tb, W1b, swsum, b1, b2, W3, b3);

  // head + loss
  head_kernel<<<dim3(BATCH), dim3(64), 0, stream>>>(Ybuf, Wfc, bfc, labels, logits, rowloss);
  loss_reduce_kernel<<<dim3(1), dim3(256), 0, stream>>>(rowloss, loss);
}